// Round 1
// baseline (3492.101 us; speedup 1.0000x reference)
//
#include <hip/hip_runtime.h>
#include <math.h>

#define B_ 32
#define N_ 512
#define F_ 101
#define E_ 128
#define H_ 4
#define EH_ 512
#define L_ 3
#define M_ (B_*N_)   // 16384

// ---------- fold inproj into wq/wk: Wq_eff = wq[l] @ inproj_w[l][:, :EH] ----------
__global__ __launch_bounds__(256) void eff_w_kernel(
    const float* __restrict__ wq, const float* __restrict__ wk,
    const float* __restrict__ inproj_w,
    float* __restrict__ Wq_eff, float* __restrict__ Wk_eff) {
  int idx = blockIdx.x*256 + threadIdx.x;       // 3*2*128*512 = 393216
  int c = idx & 511;
  int r = (idx >> 9) & 127;
  int lq = idx >> 16;                            // 0..5
  int l = lq >> 1, qk = lq & 1;
  const float* wrow = (qk ? wk : wq) + ((size_t)l*E_ + r)*EH_;
  const float* ip = inproj_w + (size_t)l*EH_*3*EH_ + (qk ? EH_ + c : c);
  float acc = 0.f;
  for (int kk = 0; kk < EH_; ++kk) acc += wrow[kk]*ip[(size_t)kk*3*EH_];
  (qk ? Wk_eff : Wq_eff)[((size_t)l*E_ + r)*EH_ + c] = acc;
}

__global__ __launch_bounds__(256) void eff_b_kernel(
    const float* __restrict__ bq, const float* __restrict__ bk,
    const float* __restrict__ inproj_w, const float* __restrict__ inproj_b,
    float* __restrict__ bq_eff, float* __restrict__ bk_eff) {
  int idx = blockIdx.x*256 + threadIdx.x;       // 3*2*512 = 3072
  if (idx >= 3072) return;
  int c = idx & 511;
  int lq = idx >> 9; int l = lq >> 1, qk = lq & 1;
  const float* bv = (qk ? bk : bq) + (size_t)l*EH_;
  int cc = qk ? EH_ + c : c;
  const float* ip = inproj_w + (size_t)l*EH_*3*EH_ + cc;
  float acc = inproj_b[(size_t)l*3*EH_ + cc];
  for (int kk = 0; kk < EH_; ++kk) acc += bv[kk]*ip[(size_t)kk*3*EH_];
  (qk ? bk_eff : bq_eff)[(size_t)l*EH_ + c] = acc;
}

// ---------- embedding: x = af_table[comp] @ comp_w + de @ emb_w + biases ----------
__global__ __launch_bounds__(128) void embed_kernel(
    const float* __restrict__ str_fea, const int* __restrict__ comp_fea,
    const float* __restrict__ af_table, const float* __restrict__ comp_w,
    const float* __restrict__ comp_b, const float* __restrict__ emb_w,
    const float* __restrict__ emb_b,
    float* __restrict__ x, float* __restrict__ x_init, float* __restrict__ w_row) {
  __shared__ float de_s[8][1000];
  __shared__ float af_s[8][92];
  const int row0 = blockIdx.x * 8;
  const int tid = threadIdx.x;
  for (int idx = tid; idx < 8*1000; idx += 128) {
    int r = idx / 1000, j = idx - r*1000;
    int f = j / 10, s = j - f*10;
    float dv = str_fea[(size_t)(row0+r)*F_ + 1 + f];
    float v = 1.0f - (dv - (float)s*0.1f);
    de_s[r][j] = v*v;
  }
  for (int idx = tid; idx < 8*92; idx += 128) {
    int r = idx / 92, j = idx - r*92;
    af_s[r][j] = af_table[(size_t)comp_fea[row0+r]*92 + j];
  }
  if (tid < 8) w_row[row0+tid] = str_fea[(size_t)(row0+tid)*F_];
  __syncthreads();
  float acc[8];
  float base = comp_b[tid] + emb_b[tid];
  #pragma unroll
  for (int r = 0; r < 8; ++r) acc[r] = base;
  for (int kk = 0; kk < 92; ++kk) {
    float w = comp_w[(size_t)kk*E_ + tid];
    #pragma unroll
    for (int r = 0; r < 8; ++r) acc[r] += af_s[r][kk]*w;
  }
  for (int j = 0; j < 1000; ++j) {
    float w = emb_w[(size_t)j*E_ + tid];
    #pragma unroll
    for (int r = 0; r < 8; ++r) acc[r] += de_s[r][j]*w;
  }
  #pragma unroll
  for (int r = 0; r < 8; ++r) {
    size_t o = (size_t)(row0+r)*E_ + tid;
    x[o] = acc[r]; x_init[o] = acc[r];
  }
}

// ---------- row LayerNorm over E=128 (one wave per row) ----------
__global__ __launch_bounds__(256) void ln_rows_kernel(const float* __restrict__ in,
    const float* __restrict__ g, const float* __restrict__ bt, float* __restrict__ out) {
  int row = blockIdx.x*4 + (threadIdx.x >> 6);
  int lane = threadIdx.x & 63;
  const float2 v = *(const float2*)(in + (size_t)row*E_ + lane*2);
  float s = v.x + v.y, sq = v.x*v.x + v.y*v.y;
  #pragma unroll
  for (int m = 1; m < 64; m <<= 1) { s += __shfl_xor(s, m, 64); sq += __shfl_xor(sq, m, 64); }
  float mean = s*(1.f/E_);
  float var = sq*(1.f/E_) - mean*mean;
  float rstd = rsqrtf(var + 1e-5f);
  const float2 gv = *(const float2*)(g + lane*2);
  const float2 bv = *(const float2*)(bt + lane*2);
  float2 o;
  o.x = (v.x-mean)*rstd*gv.x + bv.x;
  o.y = (v.y-mean)*rstd*gv.y + bv.y;
  *(float2*)(out + (size_t)row*E_ + lane*2) = o;
}

__global__ __launch_bounds__(256) void ln_add_kernel(const float* __restrict__ in1,
    const float* __restrict__ in2,
    const float* __restrict__ g, const float* __restrict__ bt, float* __restrict__ out) {
  int row = blockIdx.x*4 + (threadIdx.x >> 6);
  int lane = threadIdx.x & 63;
  const float2 a = *(const float2*)(in1 + (size_t)row*E_ + lane*2);
  const float2 b = *(const float2*)(in2 + (size_t)row*E_ + lane*2);
  float2 v; v.x = a.x + b.x; v.y = a.y + b.y;
  float s = v.x + v.y, sq = v.x*v.x + v.y*v.y;
  #pragma unroll
  for (int m = 1; m < 64; m <<= 1) { s += __shfl_xor(s, m, 64); sq += __shfl_xor(sq, m, 64); }
  float mean = s*(1.f/E_);
  float var = sq*(1.f/E_) - mean*mean;
  float rstd = rsqrtf(var + 1e-5f);
  const float2 gv = *(const float2*)(g + lane*2);
  const float2 bv = *(const float2*)(bt + lane*2);
  float2 o;
  o.x = (v.x-mean)*rstd*gv.x + bv.x;
  o.y = (v.y-mean)*rstd*gv.y + bv.y;
  *(float2*)(out + (size_t)row*E_ + lane*2) = o;
}

// ---------- tiled f32 GEMM: C = A(MxK) @ B(KxNc) + bias [+res | softplus] ----------
__device__ __forceinline__ float softplus_f(float v) {
  return fmaxf(v, 0.f) + log1pf(expf(-fabsf(v)));
}

template<int EPI>   // 0: bias  1: bias+res  2: softplus(bias+acc)
__global__ __launch_bounds__(256) void gemm_kernel(
    const float* __restrict__ A, const float* __restrict__ Bm,
    const float* __restrict__ bias, const float* __restrict__ res,
    float* __restrict__ C, int M, int K, int Nc) {
  __shared__ float As[32][68];   // transposed: As[k][m]
  __shared__ float Bs[32][68];
  const int bm = blockIdx.x * 64;
  const int bn = blockIdx.y * 64;
  const int t = threadIdx.x;
  const int tx = t & 15, ty = t >> 4;
  float acc[4][4] = {};
  const int arow = t >> 2, ac0 = (t & 3)*8;
  const int brow = t >> 3, bc0 = (t & 7)*8;
  for (int k0 = 0; k0 < K; k0 += 32) {
    float4 a0 = *(const float4*)(A + (size_t)(bm+arow)*K + k0 + ac0);
    float4 a1 = *(const float4*)(A + (size_t)(bm+arow)*K + k0 + ac0 + 4);
    As[ac0+0][arow]=a0.x; As[ac0+1][arow]=a0.y; As[ac0+2][arow]=a0.z; As[ac0+3][arow]=a0.w;
    As[ac0+4][arow]=a1.x; As[ac0+5][arow]=a1.y; As[ac0+6][arow]=a1.z; As[ac0+7][arow]=a1.w;
    float4 b0 = *(const float4*)(Bm + (size_t)(k0+brow)*Nc + bn + bc0);
    float4 b1 = *(const float4*)(Bm + (size_t)(k0+brow)*Nc + bn + bc0 + 4);
    *(float4*)(&Bs[brow][bc0]) = b0;
    *(float4*)(&Bs[brow][bc0+4]) = b1;
    __syncthreads();
    #pragma unroll
    for (int kk = 0; kk < 32; ++kk) {
      float4 av = *(const float4*)(&As[kk][ty*4]);
      float4 bv = *(const float4*)(&Bs[kk][tx*4]);
      acc[0][0] += av.x*bv.x; acc[0][1] += av.x*bv.y; acc[0][2] += av.x*bv.z; acc[0][3] += av.x*bv.w;
      acc[1][0] += av.y*bv.x; acc[1][1] += av.y*bv.y; acc[1][2] += av.y*bv.z; acc[1][3] += av.y*bv.w;
      acc[2][0] += av.z*bv.x; acc[2][1] += av.z*bv.y; acc[2][2] += av.z*bv.z; acc[2][3] += av.z*bv.w;
      acc[3][0] += av.w*bv.x; acc[3][1] += av.w*bv.y; acc[3][2] += av.w*bv.z; acc[3][3] += av.w*bv.w;
    }
    __syncthreads();
  }
  const float4 bia = *(const float4*)(bias + bn + tx*4);
  #pragma unroll
  for (int r = 0; r < 4; ++r) {
    int i = bm + ty*4 + r;
    float4 o;
    o.x = acc[r][0] + bia.x; o.y = acc[r][1] + bia.y;
    o.z = acc[r][2] + bia.z; o.w = acc[r][3] + bia.w;
    if (EPI == 1) {
      const float4 rv = *(const float4*)(res + (size_t)i*Nc + bn + tx*4);
      o.x += rv.x; o.y += rv.y; o.z += rv.z; o.w += rv.w;
    }
    if (EPI == 2) {
      o.x = softplus_f(o.x); o.y = softplus_f(o.y);
      o.z = softplus_f(o.z); o.w = softplus_f(o.w);
    }
    *(float4*)(C + (size_t)i*Nc + bn + tx*4) = o;
  }
}

// ---------- attention: mean-over-heads softmax, w_row-reweighted, @ vin ----------
__device__ __forceinline__ void qk_dot(const float* qr0, const float* qr1,
                                       const float* kr0, const float* kr1,
                                       float& a00, float& a01, float& a10, float& a11) {
  float s00=0.f,s01=0.f,s10=0.f,s11=0.f;
  #pragma unroll
  for (int d = 0; d < 128; d += 4) {
    float4 x0 = *(const float4*)(qr0+d);
    float4 x1 = *(const float4*)(qr1+d);
    float4 y0 = *(const float4*)(kr0+d);
    float4 y1 = *(const float4*)(kr1+d);
    s00 += x0.x*y0.x + x0.y*y0.y + x0.z*y0.z + x0.w*y0.w;
    s01 += x0.x*y1.x + x0.y*y1.y + x0.z*y1.z + x0.w*y1.w;
    s10 += x1.x*y0.x + x1.y*y0.y + x1.z*y0.z + x1.w*y0.w;
    s11 += x1.x*y1.x + x1.y*y1.y + x1.z*y1.z + x1.w*y1.w;
  }
  a00=s00; a01=s01; a10=s10; a11=s11;
}

__global__ __launch_bounds__(256) void attn_kernel(
    const float* __restrict__ q, const float* __restrict__ k,
    const float* __restrict__ vin, const float* __restrict__ w_row,
    float* __restrict__ att) {
  __shared__ float q_s[16][516];
  __shared__ float k_s[64][132];
  __shared__ float c_s[16][64];
  __shared__ float w_s[N_];
  __shared__ float Sinv_s[H_][16];
  const int b = blockIdx.y;
  const int i0 = blockIdx.x * 16;
  const int t = threadIdx.x;
  const float SC = 0.088388347648318447f;  // 1/sqrt(128)

  {
    const float* qb = q + ((size_t)b*N_ + i0)*EH_;
    int ii = t >> 4, m = t & 15;
    #pragma unroll
    for (int u = 0; u < 8; ++u) {
      int c = m*4 + u*64;
      *(float4*)(&q_s[ii][c]) = *(const float4*)(qb + (size_t)ii*EH_ + c);
    }
  }
  for (int j = t; j < N_; j += 256) w_s[j] = w_row[(size_t)b*N_ + j];
  __syncthreads();

  const int pi = t >> 5;   // i rows {2pi, 2pi+1}
  const int pj = t & 31;   // j cols {pj, pj+32}
  const float* kb = k + (size_t)b*N_*EH_;
  const int sjj = t >> 2, sc0 = (t & 3)*4;

  // pass 1: per-head softmax denominators (mask j where w==0; logits small -> no max needed)
  for (int h = 0; h < H_; ++h) {
    float s0 = 0.f, s1 = 0.f;
    for (int j0 = 0; j0 < N_; j0 += 64) {
      #pragma unroll
      for (int u = 0; u < 8; ++u) {
        int cc = sc0 + u*16;
        *(float4*)(&k_s[sjj][cc]) = *(const float4*)(kb + (size_t)(j0+sjj)*EH_ + h*128 + cc);
      }
      __syncthreads();
      float a00,a01,a10,a11;
      qk_dot(&q_s[2*pi][h*128], &q_s[2*pi+1][h*128], &k_s[pj][0], &k_s[pj+32][0],
             a00,a01,a10,a11);
      float m0 = (w_s[j0+pj]    != 0.f) ? 1.f : 0.f;
      float m1 = (w_s[j0+pj+32] != 0.f) ? 1.f : 0.f;
      s0 += expf(a00*SC)*m0 + expf(a01*SC)*m1;
      s1 += expf(a10*SC)*m0 + expf(a11*SC)*m1;
      __syncthreads();
    }
    #pragma unroll
    for (int m = 1; m < 32; m <<= 1) { s0 += __shfl_xor(s0, m, 64); s1 += __shfl_xor(s1, m, 64); }
    if (pj == 0) { Sinv_s[h][2*pi] = 1.f/s0; Sinv_s[h][2*pi+1] = 1.f/s1; }
  }
  __syncthreads();

  // pass 2: combined coefficients c_j = sum_h softmax_h, then PV with w_row weighting
  float acc[32];
  #pragma unroll
  for (int u = 0; u < 32; ++u) acc[u] = 0.f;
  float zacc = 0.f;
  const int iy = t >> 4, dc = t & 15;
  const float* vb = vin + (size_t)b*N_*EH_;

  for (int j0 = 0; j0 < N_; j0 += 64) {
    for (int idx = t; idx < 16*64; idx += 256) ((float*)c_s)[idx] = 0.f;
    __syncthreads();
    for (int h = 0; h < H_; ++h) {
      #pragma unroll
      for (int u = 0; u < 8; ++u) {
        int cc = sc0 + u*16;
        *(float4*)(&k_s[sjj][cc]) = *(const float4*)(kb + (size_t)(j0+sjj)*EH_ + h*128 + cc);
      }
      __syncthreads();
      float a00,a01,a10,a11;
      qk_dot(&q_s[2*pi][h*128], &q_s[2*pi+1][h*128], &k_s[pj][0], &k_s[pj+32][0],
             a00,a01,a10,a11);
      float si0 = Sinv_s[h][2*pi], si1 = Sinv_s[h][2*pi+1];
      c_s[2*pi][pj]      += expf(a00*SC)*si0;
      c_s[2*pi][pj+32]   += expf(a01*SC)*si0;
      c_s[2*pi+1][pj]    += expf(a10*SC)*si1;
      c_s[2*pi+1][pj+32] += expf(a11*SC)*si1;
      __syncthreads();
    }
    for (int j = 0; j < 64; ++j) {
      float coef = c_s[iy][j] * w_s[j0+j];
      zacc += coef;
      const float* vp = vb + (size_t)(j0+j)*EH_ + dc*4;
      #pragma unroll
      for (int u = 0; u < 8; ++u) {
        float4 vv = *(const float4*)(vp + u*64);
        acc[u*4+0] += coef*vv.x;
        acc[u*4+1] += coef*vv.y;
        acc[u*4+2] += coef*vv.z;
        acc[u*4+3] += coef*vv.w;
      }
    }
    __syncthreads();
  }
  float zinv = 1.f/zacc;
  float* ap = att + ((size_t)b*N_ + i0 + iy)*EH_ + dc*4;
  #pragma unroll
  for (int u = 0; u < 8; ++u) {
    float4 o;
    o.x = acc[u*4+0]*zinv; o.y = acc[u*4+1]*zinv;
    o.z = acc[u*4+2]*zinv; o.w = acc[u*4+3]*zinv;
    *(float4*)(ap + u*64) = o;
  }
}

// ---------- final pooling + LN + projection ----------
__global__ __launch_bounds__(128) void pool_kernel(const float* __restrict__ x,
    const float* __restrict__ x_init,
    const float* __restrict__ w_row, float* __restrict__ pooled) {
  int b = blockIdx.x, e = threadIdx.x;
  float acc = 0.f;
  for (int n = 0; n < N_; ++n) {
    float w = w_row[(size_t)b*N_ + n];
    size_t o = ((size_t)b*N_ + n)*E_ + e;
    acc += w * (x[o] + x_init[o]);
  }
  pooled[(size_t)b*E_ + e] = acc;
}

__global__ __launch_bounds__(128) void final_kernel(const float* __restrict__ pooled,
    const float* __restrict__ g, const float* __restrict__ bt,
    const float* __restrict__ fw, const float* __restrict__ fb, float* __restrict__ out) {
  int b = blockIdx.x, t = threadIdx.x;
  float v = pooled[(size_t)b*E_ + t];
  float s = v, sq = v*v;
  #pragma unroll
  for (int m = 1; m < 64; m <<= 1) { s += __shfl_xor(s, m, 64); sq += __shfl_xor(sq, m, 64); }
  __shared__ float red[4];
  int wv = t >> 6, ln = t & 63;
  if (ln == 0) { red[wv*2] = s; red[wv*2+1] = sq; }
  __syncthreads();
  s = red[0] + red[2]; sq = red[1] + red[3];
  float mean = s*(1.f/E_), var = sq*(1.f/E_) - mean*mean;
  float rstd = rsqrtf(var + 1e-5f);
  float xl = (v - mean)*rstd*g[t] + bt[t];
  float p = xl * fw[t];
  #pragma unroll
  for (int m = 1; m < 64; m <<= 1) p += __shfl_xor(p, m, 64);
  __shared__ float red2[2];
  if (ln == 0) red2[wv] = p;
  __syncthreads();
  if (t == 0) out[b] = red2[0] + red2[1] + fb[0];
}

extern "C" void kernel_launch(void* const* d_in, const int* in_sizes, int n_in,
                              void* d_out, int out_size, void* d_ws, size_t ws_size,
                              hipStream_t stream) {
  (void)in_sizes; (void)n_in; (void)out_size; (void)ws_size;
  const float* str_fea  = (const float*)d_in[0];
  const int*   comp_fea = (const int*)  d_in[1];
  // d_in[2] cell_fea unused by reference
  const float* af_table = (const float*)d_in[3];
  const float* comp_w   = (const float*)d_in[4];
  const float* comp_b   = (const float*)d_in[5];
  const float* emb_w    = (const float*)d_in[6];
  const float* emb_b    = (const float*)d_in[7];
  const float* ln_g     = (const float*)d_in[8];
  const float* ln_b     = (const float*)d_in[9];
  const float* wq       = (const float*)d_in[10];
  const float* bq       = (const float*)d_in[11];
  const float* wk       = (const float*)d_in[12];
  const float* bk       = (const float*)d_in[13];
  const float* wv       = (const float*)d_in[14];
  const float* bv       = (const float*)d_in[15];
  const float* inproj_w = (const float*)d_in[16];
  const float* inproj_b = (const float*)d_in[17];
  const float* out_w    = (const float*)d_in[18];
  const float* out_b    = (const float*)d_in[19];
  const float* ffn_w    = (const float*)d_in[20];
  const float* ffn_b    = (const float*)d_in[21];
  const float* ln2_g    = (const float*)d_in[22];
  const float* ln2_b    = (const float*)d_in[23];
  const float* final_w  = (const float*)d_in[24];
  const float* final_b  = (const float*)d_in[25];
  float* out = (float*)d_out;

  // workspace layout (~178 MB f32)
  float* ws = (float*)d_ws;
  const size_t XN = (size_t)M_*E_;      // 2,097,152
  const size_t QN = (size_t)M_*EH_;     // 8,388,608
  float* x      = ws;
  float* x_init = x + XN;
  float* xn     = x_init + XN;
  float* o1     = xn + XN;
  float* o2     = o1 + XN;
  float* qb     = o2 + XN;
  float* kb     = qb + QN;
  float* vinb   = kb + QN;
  float* attb   = vinb + QN;
  float* w_row  = attb + QN;
  float* Wq_eff = w_row + M_;
  float* Wk_eff = Wq_eff + (size_t)L_*E_*EH_;
  float* bq_eff = Wk_eff + (size_t)L_*E_*EH_;
  float* bk_eff = bq_eff + (size_t)L_*EH_;
  float* pooled = bk_eff + (size_t)L_*EH_;

  eff_w_kernel<<<1536, 256, 0, stream>>>(wq, wk, inproj_w, Wq_eff, Wk_eff);
  eff_b_kernel<<<12, 256, 0, stream>>>(bq, bk, inproj_w, inproj_b, bq_eff, bk_eff);
  embed_kernel<<<M_/8, 128, 0, stream>>>(str_fea, comp_fea, af_table, comp_w, comp_b,
                                         emb_w, emb_b, x, x_init, w_row);

  for (int l = 0; l < L_; ++l) {
    ln_rows_kernel<<<M_/4, 256, 0, stream>>>(x, ln_g + l*E_, ln_b + l*E_, xn);
    gemm_kernel<0><<<dim3(M_/64, EH_/64), 256, 0, stream>>>(
        xn, Wq_eff + (size_t)l*E_*EH_, bq_eff + l*EH_, nullptr, qb, M_, E_, EH_);
    gemm_kernel<0><<<dim3(M_/64, EH_/64), 256, 0, stream>>>(
        xn, Wk_eff + (size_t)l*E_*EH_, bk_eff + l*EH_, nullptr, kb, M_, E_, EH_);
    gemm_kernel<0><<<dim3(M_/64, EH_/64), 256, 0, stream>>>(
        xn, wv + (size_t)l*E_*EH_, bv + l*EH_, nullptr, vinb, M_, E_, EH_);
    attn_kernel<<<dim3(N_/16, B_), 256, 0, stream>>>(qb, kb, vinb, w_row, attb);
    gemm_kernel<1><<<dim3(M_/64, E_/64), 256, 0, stream>>>(
        attb, out_w + (size_t)l*EH_*E_, out_b + l*E_, x, o1, M_, EH_, E_);
    ln_rows_kernel<<<M_/4, 256, 0, stream>>>(o1, ln_g + l*E_, ln_b + l*E_, xn);
    gemm_kernel<2><<<dim3(M_/64, E_/64), 256, 0, stream>>>(
        xn, ffn_w + (size_t)l*E_*E_, ffn_b + l*E_, nullptr, o2, M_, E_, E_);
    ln_add_kernel<<<M_/4, 256, 0, stream>>>(o1, o2, ln_g + l*E_, ln_b + l*E_, x);
  }

  pool_kernel<<<B_, 128, 0, stream>>>(x, x_init, w_row, pooled);
  final_kernel<<<B_, 128, 0, stream>>>(pooled, ln2_g, ln2_b, final_w, final_b, out);
}

// Round 2
// 663.737 us; speedup vs baseline: 5.2613x; 5.2613x over previous
//
#include <hip/hip_runtime.h>
#include <math.h>

#define B_ 32
#define N_ 512
#define F_ 101
#define E_ 128
#define H_ 4
#define EH_ 512
#define L_ 3
#define M_ (B_*N_)   // 16384

typedef __attribute__((ext_vector_type(8))) short s8v;
typedef __attribute__((ext_vector_type(8))) unsigned short us8v;
typedef __attribute__((ext_vector_type(4))) float f4v;
typedef __attribute__((ext_vector_type(4))) unsigned int u4v;

__device__ __forceinline__ unsigned short f2bf(float f){
  unsigned int u = __builtin_bit_cast(unsigned int, f);
  u += 0x7fffu + ((u>>16)&1u);
  return (unsigned short)(u>>16);
}
__device__ __forceinline__ float bf2f(unsigned int h){
  unsigned int u = h<<16; return __builtin_bit_cast(float, u);
}

#define GLOAD16(gp, lp) __builtin_amdgcn_global_load_lds( \
    (__attribute__((address_space(1))) unsigned int*)(gp), \
    (__attribute__((address_space(3))) unsigned int*)(lp), 16, 0, 0)

#define MFMA16(a,b,c) __builtin_amdgcn_mfma_f32_16x16x32_bf16(a,b,c,0,0,0)

// ---------- fold inproj into wq/wk (f32): Wq_eff = wq[l] @ inproj_w[l][:, :EH] ----------
__global__ __launch_bounds__(256) void eff_w_kernel(
    const float* __restrict__ wq, const float* __restrict__ wk,
    const float* __restrict__ inproj_w,
    float* __restrict__ Wq_eff, float* __restrict__ Wk_eff) {
  int idx = blockIdx.x*256 + threadIdx.x;       // 3*2*128*512 = 393216
  int c = idx & 511;
  int r = (idx >> 9) & 127;
  int lq = idx >> 16;                            // 0..5
  int l = lq >> 1, qk = lq & 1;
  const float* wrow = (qk ? wk : wq) + ((size_t)l*E_ + r)*EH_;
  const float* ip = inproj_w + (size_t)l*EH_*3*EH_ + (qk ? EH_ + c : c);
  float acc = 0.f;
  for (int kk = 0; kk < EH_; ++kk) acc += wrow[kk]*ip[(size_t)kk*3*EH_];
  (qk ? Wk_eff : Wq_eff)[((size_t)l*E_ + r)*EH_ + c] = acc;
}

__global__ __launch_bounds__(256) void eff_b_kernel(
    const float* __restrict__ bq, const float* __restrict__ bk,
    const float* __restrict__ inproj_w, const float* __restrict__ inproj_b,
    float* __restrict__ bq_eff, float* __restrict__ bk_eff) {
  int idx = blockIdx.x*256 + threadIdx.x;       // 3*2*512 = 3072
  if (idx >= 3072) return;
  int c = idx & 511;
  int lq = idx >> 9; int l = lq >> 1, qk = lq & 1;
  const float* bv = (qk ? bk : bq) + (size_t)l*EH_;
  int cc = qk ? EH_ + c : c;
  const float* ip = inproj_w + (size_t)l*EH_*3*EH_ + cc;
  float acc = inproj_b[(size_t)l*3*EH_ + cc];
  for (int kk = 0; kk < EH_; ++kk) acc += bv[kk]*ip[(size_t)kk*3*EH_];
  (qk ? bk_eff : bq_eff)[(size_t)l*EH_ + c] = acc;
}

// ---------- convert weights to bf16, transposed [N][K] for MFMA B-operand ----------
__global__ __launch_bounds__(256) void convw_kernel(
    const float* __restrict__ Wq_eff, const float* __restrict__ Wk_eff,
    const float* __restrict__ wv, const float* __restrict__ out_w,
    const float* __restrict__ ffn_w,
    const float* __restrict__ bq_eff, const float* __restrict__ bk_eff,
    const float* __restrict__ bvv,
    unsigned short* __restrict__ wqkvT, unsigned short* __restrict__ outT,
    unsigned short* __restrict__ ffnT, float* __restrict__ bqkv) {
  int idx = blockIdx.x*256 + threadIdx.x;
  if (idx < 3*1536*128) {            // wqkvT[l][n][k]
    int k = idx & 127; int nl = idx >> 7; int n = nl % 1536; int lay = nl / 1536;
    float v;
    if (n < 512)       v = Wq_eff[((size_t)lay*128 + k)*512 + n];
    else if (n < 1024) v = Wk_eff[((size_t)lay*128 + k)*512 + (n-512)];
    else               v = wv   [((size_t)lay*128 + k)*512 + (n-1024)];
    wqkvT[idx] = f2bf(v);
  }
  if (idx < 3*128*512) {             // outT[l][n][k] = out_w[l][k][n]
    int k = idx & 511; int nl = idx >> 9; int n = nl & 127; int lay = nl >> 7;
    outT[idx] = f2bf(out_w[((size_t)lay*512 + k)*128 + n]);
  }
  if (idx < 3*128*128) {             // ffnT[l][n][k]
    int k = idx & 127; int nl = idx >> 7; int n = nl & 127; int lay = nl >> 7;
    ffnT[idx] = f2bf(ffn_w[((size_t)lay*128 + k)*128 + n]);
  }
  if (idx < 3*1536) {
    int n = idx % 1536; int lay = idx / 1536;
    float v = (n < 512) ? bq_eff[lay*512 + n]
            : (n < 1024) ? bk_eff[lay*512 + n - 512]
            : bvv[lay*512 + n - 1024];
    bqkv[idx] = v;
  }
}

// ---------- embedding (f32) ----------
__global__ __launch_bounds__(128) void embed_kernel(
    const float* __restrict__ str_fea, const int* __restrict__ comp_fea,
    const float* __restrict__ af_table, const float* __restrict__ comp_w,
    const float* __restrict__ comp_b, const float* __restrict__ emb_w,
    const float* __restrict__ emb_b,
    float* __restrict__ x, float* __restrict__ x_init, float* __restrict__ w_row) {
  __shared__ float de_s[8][1000];
  __shared__ float af_s[8][92];
  const int row0 = blockIdx.x * 8;
  const int tid = threadIdx.x;
  for (int idx = tid; idx < 8*1000; idx += 128) {
    int r = idx / 1000, j = idx - r*1000;
    int f = j / 10, s = j - f*10;
    float dv = str_fea[(size_t)(row0+r)*F_ + 1 + f];
    float v = 1.0f - (dv - (float)s*0.1f);
    de_s[r][j] = v*v;
  }
  for (int idx = tid; idx < 8*92; idx += 128) {
    int r = idx / 92, j = idx - r*92;
    af_s[r][j] = af_table[(size_t)comp_fea[row0+r]*92 + j];
  }
  if (tid < 8) w_row[row0+tid] = str_fea[(size_t)(row0+tid)*F_];
  __syncthreads();
  float acc[8];
  float base = comp_b[tid] + emb_b[tid];
  #pragma unroll
  for (int r = 0; r < 8; ++r) acc[r] = base;
  for (int kk = 0; kk < 92; ++kk) {
    float w = comp_w[(size_t)kk*E_ + tid];
    #pragma unroll
    for (int r = 0; r < 8; ++r) acc[r] += af_s[r][kk]*w;
  }
  for (int j = 0; j < 1000; ++j) {
    float w = emb_w[(size_t)j*E_ + tid];
    #pragma unroll
    for (int r = 0; r < 8; ++r) acc[r] += de_s[r][j]*w;
  }
  #pragma unroll
  for (int r = 0; r < 8; ++r) {
    size_t o = (size_t)(row0+r)*E_ + tid;
    x[o] = acc[r]; x_init[o] = acc[r];
  }
}

// ---------- row LayerNorm over E=128 -> bf16 out ----------
__global__ __launch_bounds__(256) void ln_rows_bf16_kernel(const float* __restrict__ in,
    const float* __restrict__ g, const float* __restrict__ bt, unsigned short* __restrict__ out) {
  int row = blockIdx.x*4 + (threadIdx.x >> 6);
  int lane = threadIdx.x & 63;
  const float2 v = *(const float2*)(in + (size_t)row*E_ + lane*2);
  float s = v.x + v.y, sq = v.x*v.x + v.y*v.y;
  #pragma unroll
  for (int m = 1; m < 64; m <<= 1) { s += __shfl_xor(s, m, 64); sq += __shfl_xor(sq, m, 64); }
  float mean = s*(1.f/E_);
  float var = sq*(1.f/E_) - mean*mean;
  float rstd = rsqrtf(var + 1e-5f);
  const float2 gv = *(const float2*)(g + lane*2);
  const float2 bv = *(const float2*)(bt + lane*2);
  float ox = (v.x-mean)*rstd*gv.x + bv.x;
  float oy = (v.y-mean)*rstd*gv.y + bv.y;
  unsigned int pk = (unsigned int)f2bf(ox) | ((unsigned int)f2bf(oy)<<16);
  *(unsigned int*)(out + (size_t)row*E_ + lane*2) = pk;
}

// ---------- LN(in1+in2) -> f32 out ----------
__global__ __launch_bounds__(256) void ln_add_kernel(const float* __restrict__ in1,
    const float* __restrict__ in2,
    const float* __restrict__ g, const float* __restrict__ bt, float* __restrict__ out) {
  int row = blockIdx.x*4 + (threadIdx.x >> 6);
  int lane = threadIdx.x & 63;
  const float2 a = *(const float2*)(in1 + (size_t)row*E_ + lane*2);
  const float2 b = *(const float2*)(in2 + (size_t)row*E_ + lane*2);
  float2 v; v.x = a.x + b.x; v.y = a.y + b.y;
  float s = v.x + v.y, sq = v.x*v.x + v.y*v.y;
  #pragma unroll
  for (int m = 1; m < 64; m <<= 1) { s += __shfl_xor(s, m, 64); sq += __shfl_xor(sq, m, 64); }
  float mean = s*(1.f/E_);
  float var = sq*(1.f/E_) - mean*mean;
  float rstd = rsqrtf(var + 1e-5f);
  const float2 gv = *(const float2*)(g + lane*2);
  const float2 bv = *(const float2*)(bt + lane*2);
  float2 o;
  o.x = (v.x-mean)*rstd*gv.x + bv.x;
  o.y = (v.y-mean)*rstd*gv.y + bv.y;
  *(float2*)(out + (size_t)row*E_ + lane*2) = o;
}

// ---------- bf16 MFMA GEMM: C = A[M][K] @ Bt[N][K]^T + bias ----------
// EPI 0: bf16 out -> qkb (n<1024) or transposed vT (n>=1024)
// EPI 1: f32 out = acc + bias + res
// EPI 2: f32 out = softplus(acc + bias)
template<int RT, int EPI>
__global__ __launch_bounds__(256) void mgemm_kernel(
    const unsigned short* __restrict__ A,
    const unsigned short* __restrict__ Bt,
    const float* __restrict__ bias,
    const float* __restrict__ res,
    void* __restrict__ Cout,
    unsigned short* __restrict__ vT,
    int K) {
  constexpr int BM = RT*32;
  __shared__ unsigned short lds[(BM+128)*64];
  unsigned short* Al = lds;
  unsigned short* Bl = lds + BM*64;
  const int bm = blockIdx.x*BM;
  const int bn = blockIdx.y*128;
  const int t = threadIdx.x;
  const int w = t>>6, l = t&63;
  const int wr = w>>1, wc = w&1;
  f4v acc[RT][4];
  #pragma unroll
  for (int i=0;i<RT;++i)
    #pragma unroll
    for (int j=0;j<4;++j) acc[i][j] = (f4v){0.f,0.f,0.f,0.f};
  const int srow = t>>3, sseg = t&7;
  for (int k0 = 0; k0 < K; k0 += 64) {
    #pragma unroll
    for (int c=0;c<BM/32;++c){
      int row = c*32 + srow;
      GLOAD16(A + (size_t)(bm+row)*K + k0 + ((sseg ^ (row&7))<<3),
              (char*)Al + c*4096 + w*1024);
    }
    #pragma unroll
    for (int c=0;c<4;++c){
      int row = c*32 + srow;
      GLOAD16(Bt + (size_t)(bn+row)*K + k0 + ((sseg ^ (row&7))<<3),
              (char*)Bl + c*4096 + w*1024);
    }
    __syncthreads();
    #pragma unroll
    for (int ks=0;ks<2;++ks){
      s8v bf[4];
      #pragma unroll
      for (int ct=0;ct<4;++ct){
        int col = wc*64 + ct*16 + (l&15);
        bf[ct] = *(const s8v*)((const char*)Bl + col*128 + ((((l>>4)+ks*4) ^ (col&7))<<4));
      }
      #pragma unroll
      for (int rt=0;rt<RT;++rt){
        int arow = wr*(RT*16) + rt*16 + (l&15);
        s8v af = *(const s8v*)((const char*)Al + arow*128 + ((((l>>4)+ks*4) ^ (arow&7))<<4));
        #pragma unroll
        for (int ct=0;ct<4;++ct)
          acc[rt][ct] = MFMA16(af, bf[ct], acc[rt][ct]);
      }
    }
    __syncthreads();
  }
  float bia[4];
  #pragma unroll
  for (int ct=0;ct<4;++ct) bia[ct] = bias[bn + wc*64 + ct*16 + (l&15)];
  if (EPI == 0) {
    if (bn < 1024) {
      #pragma unroll
      for (int rt=0;rt<RT;++rt)
        #pragma unroll
        for (int ct=0;ct<4;++ct)
          #pragma unroll
          for (int r=0;r<4;++r){
            int rr = wr*(RT*16) + rt*16 + (l>>4)*4 + r;
            int cc = wc*64 + ct*16 + (l&15);
            lds[rr*128 + cc] = f2bf(acc[rt][ct][r] + bia[ct]);
          }
      __syncthreads();
      unsigned short* qkb = (unsigned short*)Cout;
      #pragma unroll
      for (int it=0; it<BM/16; ++it){
        int row = it*16 + (t>>4), seg = t&15;
        u4v v = *(const u4v*)(lds + row*128 + seg*8);
        *(u4v*)(qkb + (size_t)(bm+row)*1024 + bn + seg*8) = v;
      }
    } else {
      #pragma unroll
      for (int rt=0;rt<RT;++rt)
        #pragma unroll
        for (int ct=0;ct<4;++ct){
          int rbase = bm + wr*(RT*16) + rt*16 + (l>>4)*4;
          int bb = rbase >> 9, nn = rbase & 511;
          int d = bn - 1024 + wc*64 + ct*16 + (l&15);
          unsigned int lo = (unsigned int)f2bf(acc[rt][ct][0] + bia[ct])
                          | ((unsigned int)f2bf(acc[rt][ct][1] + bia[ct])<<16);
          unsigned int hi = (unsigned int)f2bf(acc[rt][ct][2] + bia[ct])
                          | ((unsigned int)f2bf(acc[rt][ct][3] + bia[ct])<<16);
          uint2 pk; pk.x = lo; pk.y = hi;
          *(uint2*)(vT + ((size_t)(bb*512 + d))*512 + nn) = pk;
        }
    }
  } else {
    float* C = (float*)Cout;
    #pragma unroll
    for (int rt=0;rt<RT;++rt)
      #pragma unroll
      for (int ct=0;ct<4;++ct)
        #pragma unroll
        for (int r=0;r<4;++r){
          int rr = bm + wr*(RT*16) + rt*16 + (l>>4)*4 + r;
          int cc = wc*64 + ct*16 + (l&15);
          float v = acc[rt][ct][r] + bia[ct];
          if (EPI == 1) v += res[(size_t)rr*128 + cc];
          if (EPI == 2) v = fmaxf(v,0.f) + log1pf(__expf(-fabsf(v)));
          C[(size_t)rr*128 + cc] = v;
        }
  }
}

// ---------- attention stage A: per (i-tile, h, b): P = exp(QK^T*sc), Sinv ----------
__global__ __launch_bounds__(256) void attnA_kernel(
    const unsigned short* __restrict__ qkb, const float* __restrict__ w_row,
    unsigned short* __restrict__ P, float* __restrict__ Sinv) {
  __shared__ unsigned short Qlds[64*128];
  __shared__ unsigned short Klds[64*128];
  __shared__ unsigned short Ptile[64*64];
  __shared__ float w_s[512];
  const int i0 = blockIdx.x*64;
  const int h = blockIdx.y, b = blockIdx.z;
  const int t = threadIdx.x, w = t>>6, l = t&63;
  const float SC = 0.088388347648318447f;   // 1/sqrt(128)
  for (int j=t;j<512;j+=256) w_s[j] = w_row[b*512+j];
  {
    int row = t>>4, seg = t&15;
    #pragma unroll
    for (int c=0;c<4;++c)
      GLOAD16(qkb + (size_t)(b*512 + i0 + c*16 + row)*1024 + h*128 + ((seg ^ (row&7))<<3),
              (char*)Qlds + c*4096 + w*1024);
  }
  __syncthreads();
  s8v qf[4];
  #pragma unroll
  for (int ks=0;ks<4;++ks){
    int arow = w*16 + (l&15);
    qf[ks] = *(const s8v*)((const char*)Qlds + arow*256 + ((((l>>4)+ks*4) ^ (arow&7))<<4));
  }
  float sp[4] = {0.f,0.f,0.f,0.f};
  for (int j0=0;j0<512;j0+=64){
    {
      int row = t>>4, seg = t&15;
      #pragma unroll
      for (int c=0;c<4;++c)
        GLOAD16(qkb + (size_t)(b*512 + j0 + c*16 + row)*1024 + 512 + h*128 + ((seg ^ (row&7))<<3),
                (char*)Klds + c*4096 + w*1024);
    }
    __syncthreads();
    #pragma unroll
    for (int jt=0;jt<4;++jt){
      f4v a = (f4v){0.f,0.f,0.f,0.f};
      #pragma unroll
      for (int ks=0;ks<4;++ks){
        int col = jt*16 + (l&15);
        s8v kf = *(const s8v*)((const char*)Klds + col*256 + ((((l>>4)+ks*4) ^ (col&7))<<4));
        a = MFMA16(qf[ks], kf, a);
      }
      int jl = jt*16 + (l&15);
      float mw = (w_s[j0+jl] != 0.f) ? 1.f : 0.f;
      #pragma unroll
      for (int r=0;r<4;++r){
        float e = __expf(a[r]*SC);
        sp[r] += e*mw;
        Ptile[(w*16 + (l>>4)*4 + r)*64 + jl] = f2bf(e);
      }
    }
    __syncthreads();
    #pragma unroll
    for (int it=0;it<2;++it){
      int row = it*32 + (t>>3), seg = t&7;
      u4v pv = *(const u4v*)(Ptile + row*64 + seg*8);
      *(u4v*)(P + ((size_t)((b*4+h)*512 + i0 + row))*512 + j0 + seg*8) = pv;
    }
  }
  #pragma unroll
  for (int r=0;r<4;++r){
    float s = sp[r];
    s += __shfl_xor(s,1,64); s += __shfl_xor(s,2,64);
    s += __shfl_xor(s,4,64); s += __shfl_xor(s,8,64);
    sp[r] = s;
  }
  if ((l&15)==0){
    #pragma unroll
    for (int r=0;r<4;++r)
      Sinv[(size_t)(b*4+h)*512 + i0 + w*16 + (l>>4)*4 + r] = 1.f/sp[r];
  }
}

// ---------- attention stage B: combine heads + w-weight + PV MFMA + renorm ----------
__global__ __launch_bounds__(256) void attnB_kernel(
    const unsigned short* __restrict__ P, const float* __restrict__ Sinv,
    const unsigned short* __restrict__ vT, const float* __restrict__ w_row,
    unsigned short* __restrict__ att) {
  __shared__ unsigned short Vlds[512*64];   // [d][j] chunk, swizzled
  __shared__ unsigned short cA[64*64];      // coefficient tile, swizzled
  __shared__ float w_s[512];
  __shared__ float sinv_s[4][64];
  __shared__ float zred[64][4];
  __shared__ float zinv_s[64];
  const int i0 = blockIdx.x*64, b = blockIdx.y;
  const int t = threadIdx.x, w = t>>6, l = t&63;
  for (int j=t;j<512;j+=256) w_s[j] = w_row[b*512+j];
  { int hh = t>>6, ii = t&63;
    sinv_s[hh][ii] = Sinv[(size_t)(b*4+hh)*512 + i0 + ii]; }
  __syncthreads();
  f4v acc[4][8];
  #pragma unroll
  for (int i=0;i<4;++i)
    #pragma unroll
    for (int j=0;j<8;++j) acc[i][j] = (f4v){0.f,0.f,0.f,0.f};
  const int ci = t>>2, cjq = t&3;
  float zacc = 0.f;
  for (int j0=0;j0<512;j0+=64){
    { int seg = t&7;
      #pragma unroll
      for (int c=0;c<16;++c){
        int d = c*32 + (t>>3);
        GLOAD16(vT + ((size_t)(b*512 + d))*512 + j0 + ((seg ^ (d&7))<<3),
                (char*)Vlds + c*4096 + w*1024);
      }
    }
    float cv[16];
    #pragma unroll
    for (int e=0;e<16;++e) cv[e]=0.f;
    #pragma unroll
    for (int hh=0;hh<4;++hh){
      const unsigned short* pp = P + ((size_t)((b*4+hh)*512 + i0 + ci))*512 + j0 + cjq*16;
      u4v p0 = *(const u4v*)pp;
      u4v p1 = *(const u4v*)(pp+8);
      float si = sinv_s[hh][ci];
      #pragma unroll
      for (int e=0;e<4;++e){
        cv[2*e]     += bf2f(p0[e]&0xffffu)*si;
        cv[2*e+1]   += bf2f(p0[e]>>16)*si;
        cv[8+2*e]   += bf2f(p1[e]&0xffffu)*si;
        cv[8+2*e+1] += bf2f(p1[e]>>16)*si;
      }
    }
    us8v pk0, pk1;
    #pragma unroll
    for (int e=0;e<8;++e){
      float v0 = cv[e]   * w_s[j0 + cjq*16 + e];
      float v1 = cv[8+e] * w_s[j0 + cjq*16 + 8 + e];
      zacc += v0 + v1;
      pk0[e] = f2bf(v0); pk1[e] = f2bf(v1);
    }
    *(us8v*)((char*)cA + ci*128 + (((cjq*2)   ^ (ci&7))<<4)) = pk0;
    *(us8v*)((char*)cA + ci*128 + (((cjq*2+1) ^ (ci&7))<<4)) = pk1;
    __syncthreads();
    #pragma unroll
    for (int ks=0;ks<2;++ks){
      s8v af[4];
      #pragma unroll
      for (int rt=0;rt<4;++rt){
        int arow = rt*16 + (l&15);
        af[rt] = *(const s8v*)((const char*)cA + arow*128 + ((((l>>4)+ks*4) ^ (arow&7))<<4));
      }
      #pragma unroll
      for (int ct=0;ct<8;++ct){
        int d = w*128 + ct*16 + (l&15);
        s8v vf = *(const s8v*)((const char*)Vlds + d*128 + ((((l>>4)+ks*4) ^ (d&7))<<4));
        #pragma unroll
        for (int rt=0;rt<4;++rt)
          acc[rt][ct] = MFMA16(af[rt], vf, acc[rt][ct]);
      }
    }
    __syncthreads();
  }
  zred[ci][cjq] = zacc;
  __syncthreads();
  if (t < 64) zinv_s[t] = 1.f/(zred[t][0]+zred[t][1]+zred[t][2]+zred[t][3]);
  __syncthreads();
  #pragma unroll
  for (int rt=0;rt<4;++rt)
    #pragma unroll
    for (int ct=0;ct<8;++ct)
      #pragma unroll
      for (int r=0;r<4;++r){
        int rr = rt*16 + (l>>4)*4 + r;
        int d = w*128 + ct*16 + (l&15);
        Vlds[rr*512 + d] = f2bf(acc[rt][ct][r]*zinv_s[rr]);
      }
  __syncthreads();
  #pragma unroll
  for (int it=0; it<16; ++it){
    int row = it*4 + w;
    u4v v = *(const u4v*)(Vlds + row*512 + l*8);
    *(u4v*)(att + ((size_t)(b*512 + i0 + row))*512 + l*8) = v;
  }
}

// ---------- final pooling + LN + projection ----------
__global__ __launch_bounds__(128) void pool_kernel(const float* __restrict__ x,
    const float* __restrict__ x_init,
    const float* __restrict__ w_row, float* __restrict__ pooled) {
  int b = blockIdx.x, e = threadIdx.x;
  float acc = 0.f;
  for (int n = 0; n < N_; ++n) {
    float w = w_row[(size_t)b*N_ + n];
    size_t o = ((size_t)b*N_ + n)*E_ + e;
    acc += w * (x[o] + x_init[o]);
  }
  pooled[(size_t)b*E_ + e] = acc;
}

__global__ __launch_bounds__(128) void final_kernel(const float* __restrict__ pooled,
    const float* __restrict__ g, const float* __restrict__ bt,
    const float* __restrict__ fw, const float* __restrict__ fb, float* __restrict__ out) {
  int b = blockIdx.x, t = threadIdx.x;
  float v = pooled[(size_t)b*E_ + t];
  float s = v, sq = v*v;
  #pragma unroll
  for (int m = 1; m < 64; m <<= 1) { s += __shfl_xor(s, m, 64); sq += __shfl_xor(sq, m, 64); }
  __shared__ float red[4];
  int wv = t >> 6, ln = t & 63;
  if (ln == 0) { red[wv*2] = s; red[wv*2+1] = sq; }
  __syncthreads();
  s = red[0] + red[2]; sq = red[1] + red[3];
  float mean = s*(1.f/E_), var = sq*(1.f/E_) - mean*mean;
  float rstd = rsqrtf(var + 1e-5f);
  float xl = (v - mean)*rstd*g[t] + bt[t];
  float p = xl * fw[t];
  #pragma unroll
  for (int m = 1; m < 64; m <<= 1) p += __shfl_xor(p, m, 64);
  __shared__ float red2[2];
  if (ln == 0) red2[wv] = p;
  __syncthreads();
  if (t == 0) out[b] = red2[0] + red2[1] + fb[0];
}

extern "C" void kernel_launch(void* const* d_in, const int* in_sizes, int n_in,
                              void* d_out, int out_size, void* d_ws, size_t ws_size,
                              hipStream_t stream) {
  (void)in_sizes; (void)n_in; (void)out_size; (void)ws_size;
  const float* str_fea  = (const float*)d_in[0];
  const int*   comp_fea = (const int*)  d_in[1];
  const float* af_table = (const float*)d_in[3];
  const float* comp_w   = (const float*)d_in[4];
  const float* comp_b   = (const float*)d_in[5];
  const float* emb_w    = (const float*)d_in[6];
  const float* emb_b    = (const float*)d_in[7];
  const float* ln_g     = (const float*)d_in[8];
  const float* ln_b     = (const float*)d_in[9];
  const float* wq       = (const float*)d_in[10];
  const float* bq       = (const float*)d_in[11];
  const float* wk       = (const float*)d_in[12];
  const float* bk       = (const float*)d_in[13];
  const float* wv       = (const float*)d_in[14];
  const float* bv       = (const float*)d_in[15];
  const float* inproj_w = (const float*)d_in[16];
  const float* inproj_b = (const float*)d_in[17];
  const float* out_w    = (const float*)d_in[18];
  const float* out_b    = (const float*)d_in[19];
  const float* ffn_w    = (const float*)d_in[20];
  const float* ffn_b    = (const float*)d_in[21];
  const float* ln2_g    = (const float*)d_in[22];
  const float* ln2_b    = (const float*)d_in[23];
  const float* final_w  = (const float*)d_in[24];
  const float* final_b  = (const float*)d_in[25];
  float* out = (float*)d_out;

  float* ws = (float*)d_ws;
  size_t off = 0;
  float* x      = ws + off; off += 2097152;
  float* x_init = ws + off; off += 2097152;
  float* o1     = ws + off; off += 2097152;
  float* o2     = ws + off; off += 2097152;
  float* w_row  = ws + off; off += 16384;
  unsigned short* xnb  = (unsigned short*)(ws + off); off += 1048576;   // [M][128]
  unsigned short* qkb  = (unsigned short*)(ws + off); off += 8388608;   // [M][1024]
  unsigned short* vTb  = (unsigned short*)(ws + off); off += 4194304;   // [B][512][512]
  unsigned short* attb = (unsigned short*)(ws + off); off += 4194304;   // [M][512]
  unsigned short* Pb   = (unsigned short*)(ws + off); off += 16777216;  // [B][H][512][512]
  float* Sinvb  = ws + off; off += 65536;
  float* Wq_eff = ws + off; off += 196608;
  float* Wk_eff = ws + off; off += 196608;
  float* bq_eff = ws + off; off += 1536;
  float* bk_eff = ws + off; off += 1536;
  float* bqkv   = ws + off; off += 4608;
  unsigned short* wqkvT = (unsigned short*)(ws + off); off += 294912;   // [3][1536][128]
  unsigned short* outT  = (unsigned short*)(ws + off); off += 98304;    // [3][128][512]
  unsigned short* ffnT  = (unsigned short*)(ws + off); off += 24576;    // [3][128][128]
  float* pooled = ws + off; off += 4096;

  eff_w_kernel<<<1536, 256, 0, stream>>>(wq, wk, inproj_w, Wq_eff, Wk_eff);
  eff_b_kernel<<<12, 256, 0, stream>>>(bq, bk, inproj_w, inproj_b, bq_eff, bk_eff);
  convw_kernel<<<2304, 256, 0, stream>>>(Wq_eff, Wk_eff, wv, out_w, ffn_w,
                                         bq_eff, bk_eff, bv, wqkvT, outT, ffnT, bqkv);
  embed_kernel<<<M_/8, 128, 0, stream>>>(str_fea, comp_fea, af_table, comp_w, comp_b,
                                         emb_w, emb_b, x, x_init, w_row);

  for (int l = 0; l < L_; ++l) {
    ln_rows_bf16_kernel<<<M_/4, 256, 0, stream>>>(x, ln_g + l*E_, ln_b + l*E_, xnb);
    mgemm_kernel<4,0><<<dim3(M_/128, 12), 256, 0, stream>>>(
        xnb, wqkvT + (size_t)l*1536*128, bqkv + l*1536, nullptr, qkb, vTb, 128);
    attnA_kernel<<<dim3(8, 4, 32), 256, 0, stream>>>(qkb, w_row, Pb, Sinvb);
    attnB_kernel<<<dim3(8, 32), 256, 0, stream>>>(Pb, Sinvb, vTb, w_row, attb);
    mgemm_kernel<2,1><<<dim3(M_/64, 1), 256, 0, stream>>>(
        attb, outT + (size_t)l*128*512, out_b + (size_t)l*E_, x, o1, nullptr, 512);
    ln_rows_bf16_kernel<<<M_/4, 256, 0, stream>>>(o1, ln_g + l*E_, ln_b + l*E_, xnb);
    mgemm_kernel<2,2><<<dim3(M_/64, 1), 256, 0, stream>>>(
        xnb, ffnT + (size_t)l*128*128, ffn_b + (size_t)l*E_, nullptr, o2, nullptr, 128);
    ln_add_kernel<<<M_/4, 256, 0, stream>>>(o1, o2, ln_g + l*E_, ln_b + l*E_, x);
  }

  pool_kernel<<<B_, 128, 0, stream>>>(x, x_init, w_row, pooled);
  final_kernel<<<B_, 128, 0, stream>>>(pooled, ln2_g, ln2_b, final_w, final_b, out);
}

// Round 3
// 565.842 us; speedup vs baseline: 6.1715x; 1.1730x over previous
//
#include <hip/hip_runtime.h>
#include <math.h>

#define B_ 32
#define N_ 512
#define F_ 101
#define E_ 128
#define H_ 4
#define EH_ 512
#define L_ 3
#define M_ (B_*N_)   // 16384

typedef __attribute__((ext_vector_type(8))) short s8v;
typedef __attribute__((ext_vector_type(8))) unsigned short us8v;
typedef __attribute__((ext_vector_type(4))) float f4v;
typedef __attribute__((ext_vector_type(4))) unsigned int u4v;

__device__ __forceinline__ unsigned short f2bf(float f){
  unsigned int u = __builtin_bit_cast(unsigned int, f);
  u += 0x7fffu + ((u>>16)&1u);
  return (unsigned short)(u>>16);
}
__device__ __forceinline__ float bf2f(unsigned int h){
  unsigned int u = h<<16; return __builtin_bit_cast(float, u);
}
__device__ __forceinline__ float softplus_f(float v) {
  return fmaxf(v, 0.f) + log1pf(__expf(-fabsf(v)));
}

#define GLOAD16(gp, lp) __builtin_amdgcn_global_load_lds( \
    (__attribute__((address_space(1))) unsigned int*)(gp), \
    (__attribute__((address_space(3))) unsigned int*)(lp), 16, 0, 0)

#define MFMA16(a,b,c) __builtin_amdgcn_mfma_f32_16x16x32_bf16(a,b,c,0,0,0)

// ---------- eff fold GEMM: wqkvT[l][qk*512+n][r] = bf16( sum_kk wqk[l][r][kk] * ip[kk][n] ) ----------
__global__ __launch_bounds__(256) void eff_gemm_kernel(
    const float* __restrict__ wq, const float* __restrict__ wk,
    const float* __restrict__ inproj_w, unsigned short* __restrict__ wqkvT) {
  __shared__ float As[64][132];   // [kk][r]
  __shared__ float Bs[64][68];    // [kk][c]
  const int blk = blockIdx.x;     // 48 = 6 lq * 8 ntiles
  const int lq = blk>>3, nt = blk&7;
  const int l = lq>>1, qk = lq&1;
  const int bn = nt*64;
  const float* A = (qk ? wk : wq) + (size_t)l*128*512;
  const float* IP = inproj_w + (size_t)l*512*1536 + qk*512 + bn;
  const int t = threadIdx.x;
  float acc[8][4];
  #pragma unroll
  for (int i=0;i<8;++i)
    #pragma unroll
    for (int j=0;j<4;++j) acc[i][j]=0.f;
  const int r0 = (t&15)*8, c0 = (t>>4)*4;
  for (int k0=0;k0<512;k0+=64){
    int r = t & 127, half = t>>7;
    #pragma unroll
    for (int u=0;u<8;++u){
      float4 a = *(const float4*)(A + (size_t)r*512 + k0 + half*32 + u*4);
      int kk = half*32 + u*4;
      As[kk+0][r]=a.x; As[kk+1][r]=a.y; As[kk+2][r]=a.z; As[kk+3][r]=a.w;
    }
    int kk = t>>2, cb = (t&3)*16;
    #pragma unroll
    for (int u=0;u<4;++u)
      *(float4*)&Bs[kk][cb+u*4] = *(const float4*)(IP + (size_t)(k0+kk)*1536 + cb + u*4);
    __syncthreads();
    for (int k2=0;k2<64;++k2){
      float4 b = *(const float4*)&Bs[k2][c0];
      float4 a0 = *(const float4*)&As[k2][r0];
      float4 a1 = *(const float4*)&As[k2][r0+4];
      float av[8] = {a0.x,a0.y,a0.z,a0.w,a1.x,a1.y,a1.z,a1.w};
      #pragma unroll
      for (int i=0;i<8;++i){
        acc[i][0] += av[i]*b.x; acc[i][1] += av[i]*b.y;
        acc[i][2] += av[i]*b.z; acc[i][3] += av[i]*b.w;
      }
    }
    __syncthreads();
  }
  #pragma unroll
  for (int j=0;j<4;++j){
    us8v pk;
    #pragma unroll
    for (int i=0;i<8;++i) pk[i] = f2bf(acc[i][j]);
    *(us8v*)(wqkvT + ((size_t)l*1536 + qk*512 + bn + c0 + j)*128 + r0) = pk;
  }
}

__global__ __launch_bounds__(256) void eff_b_kernel(
    const float* __restrict__ bq, const float* __restrict__ bk,
    const float* __restrict__ inproj_w, const float* __restrict__ inproj_b,
    float* __restrict__ bq_eff, float* __restrict__ bk_eff) {
  int idx = blockIdx.x*256 + threadIdx.x;       // 3*2*512 = 3072
  if (idx >= 3072) return;
  int c = idx & 511;
  int lq = idx >> 9; int l = lq >> 1, qk = lq & 1;
  const float* bv = (qk ? bk : bq) + (size_t)l*EH_;
  int cc = qk ? EH_ + c : c;
  const float* ip = inproj_w + (size_t)l*EH_*3*EH_ + cc;
  float acc = inproj_b[(size_t)l*3*EH_ + cc];
  for (int kk = 0; kk < EH_; ++kk) acc += bv[kk]*ip[(size_t)kk*3*EH_];
  (qk ? bk_eff : bq_eff)[(size_t)l*EH_ + c] = acc;
}

// ---------- pack v-part of wqkvT, outT, ffnT, bqkv ----------
__global__ __launch_bounds__(256) void wconv2_kernel(
    const float* __restrict__ wv, const float* __restrict__ out_w,
    const float* __restrict__ ffn_w,
    const float* __restrict__ bq_eff, const float* __restrict__ bk_eff,
    const float* __restrict__ bvv,
    unsigned short* __restrict__ wqkvT, unsigned short* __restrict__ outT,
    unsigned short* __restrict__ ffnT, float* __restrict__ bqkv) {
  int idx = blockIdx.x*256 + threadIdx.x;   // 768*256 = 196608
  {  // v part: wqkvT[l][1024+n][k] = wv[l][k][n]
    int k = idx & 127; int nl = idx >> 7; int n = nl & 511; int lay = nl >> 9;
    wqkvT[((size_t)lay*1536 + 1024 + n)*128 + k] =
        f2bf(wv[((size_t)lay*128 + k)*512 + n]);
  }
  {  // outT[l][n][k] = out_w[l][k][n]
    int k = idx & 511; int nl = idx >> 9; int n = nl & 127; int lay = nl >> 7;
    outT[idx] = f2bf(out_w[((size_t)lay*512 + k)*128 + n]);
  }
  if (idx < 3*128*128) {   // ffnT[l][n][k] = ffn_w[l][k][n]
    int k = idx & 127; int nl = idx >> 7; int n = nl & 127; int lay = nl >> 7;
    ffnT[idx] = f2bf(ffn_w[((size_t)lay*128 + k)*128 + n]);
  }
  if (idx < 3*1536) {
    int n = idx % 1536; int lay = idx / 1536;
    float v = (n < 512) ? bq_eff[lay*512 + n]
            : (n < 1024) ? bk_eff[lay*512 + n - 512]
            : bvv[lay*512 + n - 1024];
    bqkv[idx] = v;
  }
}

// ---------- embed weight prep: quadratic expansion A/B/C + split bf16 ----------
__global__ __launch_bounds__(128) void embW1_kernel(
    const float* __restrict__ emb_w, const float* __restrict__ comp_w,
    unsigned short* __restrict__ WHi, unsigned short* __restrict__ WLo,
    float* __restrict__ Cpart) {
  int p = blockIdx.x, e = threadIdx.x;
  if (p < 10) {
    float Cp = 0.f;
    for (int ff=0; ff<10; ++ff){
      int f = p*10+ff;
      float A=0.f, Bv=0.f;
      #pragma unroll
      for (int s=0;s<10;++s){
        float wv = emb_w[(size_t)(f*10+s)*128 + e];
        A += wv; Bv += 0.2f*s*wv; Cp += 0.01f*(s*s)*wv;
      }
      int kA = 92+f, kB = 192+f;
      unsigned short hA = f2bf(A);
      WHi[e*320+kA]=hA; WLo[e*320+kA]=f2bf(A - bf2f(hA));
      unsigned short hB = f2bf(Bv);
      WHi[e*320+kB]=hB; WLo[e*320+kB]=f2bf(Bv - bf2f(hB));
    }
    Cpart[p*128+e] = Cp;
  } else if (p == 10) {
    for (int kk=0;kk<92;++kk){
      float v = comp_w[(size_t)kk*128 + e];
      unsigned short h = f2bf(v);
      WHi[e*320+kk]=h; WLo[e*320+kk]=f2bf(v - bf2f(h));
    }
  } else {
    for (int kk=292;kk<320;++kk){ WHi[e*320+kk]=0; WLo[e*320+kk]=0; }
  }
}

__global__ __launch_bounds__(128) void embBias_kernel(
    const float* __restrict__ Cpart, const float* __restrict__ comp_b,
    const float* __restrict__ emb_b, float* __restrict__ biasE){
  int e = threadIdx.x; float c=0.f;
  for (int p=0;p<10;++p) c += Cpart[p*128+e];
  biasE[e] = comp_b[e] + emb_b[e] + c;
}

// ---------- feature builder: FeatHi/Lo [M][320] + w_row ----------
__global__ __launch_bounds__(256) void feat_kernel(
    const float* __restrict__ str_fea, const int* __restrict__ comp_fea,
    const float* __restrict__ af_table,
    unsigned short* __restrict__ FHi, unsigned short* __restrict__ FLo,
    float* __restrict__ w_row) {
  int row = blockIdx.x*64 + (threadIdx.x>>2);
  int p = threadIdx.x & 3;
  const float* sr = str_fea + (size_t)row*F_;
  if (p==0) w_row[row] = sr[0];
  const float* af = af_table + (size_t)comp_fea[row]*92;
  for (int c0 = p*80; c0 < p*80+80; c0 += 8){
    us8v hi, lo;
    #pragma unroll
    for (int e=0;e<8;++e){
      int kk = c0+e; float v;
      if (kk < 92) v = af[kk];
      else if (kk < 192) { float u = 1.f - sr[1+kk-92]; v = u*u; }
      else if (kk < 292) v = 1.f - sr[1+kk-192];
      else v = 0.f;
      unsigned short h = f2bf(v);
      hi[e] = h; lo[e] = f2bf(v - bf2f(h));
    }
    *(us8v*)(FHi + (size_t)row*320 + c0) = hi;
    *(us8v*)(FLo + (size_t)row*320 + c0) = lo;
  }
}

// ---------- embed GEMM (split bf16, 3-MFMA) + LN0 epilogue ----------
__global__ __launch_bounds__(256) void embgemm_kernel(
    const unsigned short* __restrict__ FHi, const unsigned short* __restrict__ FLo,
    const unsigned short* __restrict__ WHi, const unsigned short* __restrict__ WLo,
    const float* __restrict__ biasE,
    const float* __restrict__ g0, const float* __restrict__ b0,
    float* __restrict__ x, float* __restrict__ x_init,
    unsigned short* __restrict__ xnb) {
  __shared__ unsigned short lds[24576];    // 48 KB
  unsigned short* AHi = lds;
  unsigned short* ALo = lds + 4096;
  unsigned short* BHi = lds + 8192;
  unsigned short* BLo = lds + 16384;
  const int bm = blockIdx.x*64;
  const int t = threadIdx.x, w = t>>6, l = t&63;
  f4v acc[8];
  #pragma unroll
  for (int i=0;i<8;++i) acc[i] = (f4v){0.f,0.f,0.f,0.f};
  const int srow = t>>3, sseg = t&7;
  for (int k0=0;k0<320;k0+=64){
    #pragma unroll
    for (int c=0;c<2;++c){
      int row = c*32+srow;
      GLOAD16(FHi + (size_t)(bm+row)*320 + k0 + ((sseg^(row&7))<<3), (char*)AHi + c*4096 + w*1024);
      GLOAD16(FLo + (size_t)(bm+row)*320 + k0 + ((sseg^(row&7))<<3), (char*)ALo + c*4096 + w*1024);
    }
    #pragma unroll
    for (int c=0;c<4;++c){
      int row = c*32+srow;
      GLOAD16(WHi + (size_t)row*320 + k0 + ((sseg^(row&7))<<3), (char*)BHi + c*4096 + w*1024);
      GLOAD16(WLo + (size_t)row*320 + k0 + ((sseg^(row&7))<<3), (char*)BLo + c*4096 + w*1024);
    }
    __syncthreads();
    #pragma unroll
    for (int ks=0;ks<2;++ks){
      int arow = w*16 + (l&15);
      int aswz = ((((l>>4)+ks*4) ^ (arow&7))<<4);
      s8v ah = *(const s8v*)((const char*)AHi + arow*128 + aswz);
      s8v al = *(const s8v*)((const char*)ALo + arow*128 + aswz);
      #pragma unroll
      for (int ct=0;ct<8;++ct){
        int col = ct*16 + (l&15);
        int bswz = ((((l>>4)+ks*4) ^ (col&7))<<4);
        s8v bh = *(const s8v*)((const char*)BHi + col*128 + bswz);
        s8v bl = *(const s8v*)((const char*)BLo + col*128 + bswz);
        acc[ct] = MFMA16(ah, bh, acc[ct]);
        acc[ct] = MFMA16(ah, bl, acc[ct]);
        acc[ct] = MFMA16(al, bh, acc[ct]);
      }
    }
    __syncthreads();
  }
  float vv[8][4], gc[8], bc[8];
  #pragma unroll
  for (int ct=0;ct<8;++ct){
    int c = ct*16 + (l&15);
    float be = biasE[c]; gc[ct] = g0[c]; bc[ct] = b0[c];
    #pragma unroll
    for (int r=0;r<4;++r) vv[ct][r] = acc[ct][r] + be;
  }
  #pragma unroll
  for (int r=0;r<4;++r){
    float s=0.f, sq=0.f;
    #pragma unroll
    for (int ct=0;ct<8;++ct){ s += vv[ct][r]; sq += vv[ct][r]*vv[ct][r]; }
    #pragma unroll
    for (int m=1;m<16;m<<=1){ s += __shfl_xor(s,m,64); sq += __shfl_xor(sq,m,64); }
    float mean = s*(1.f/128.f);
    float rstd = rsqrtf(sq*(1.f/128.f) - mean*mean + 1e-5f);
    int row = bm + w*16 + (l>>4)*4 + r;
    #pragma unroll
    for (int ct=0;ct<8;++ct){
      int c = ct*16 + (l&15);
      float v = vv[ct][r];
      x[(size_t)row*128 + c] = v;
      x_init[(size_t)row*128 + c] = v;
      xnb[(size_t)row*128 + c] = f2bf((v-mean)*rstd*gc[ct] + bc[ct]);
    }
  }
}

// ---------- bf16 MFMA GEMM ----------
// EPI 0: bf16 out -> qkb (n<1024) or transposed vT (n>=1024)
// EPI 1: o1 = acc+bias+res (f32) ; xnb = LN(o1; g1,b1)
// EPI 2: x = LN(res + softplus(acc+bias); g1,b1) (f32); if g2: xnb = LN(x; g2,b2)
template<int RT, int EPI>
__global__ __launch_bounds__(256) void mgemm_kernel(
    const unsigned short* __restrict__ A,
    const unsigned short* __restrict__ Bt,
    const float* __restrict__ bias,
    const float* __restrict__ res,
    unsigned short* __restrict__ qkb,
    unsigned short* __restrict__ vT,
    float* __restrict__ outF,
    unsigned short* __restrict__ xnbO,
    const float* __restrict__ g1, const float* __restrict__ b1,
    const float* __restrict__ g2, const float* __restrict__ b2,
    int K) {
  constexpr int BM = RT*32;
  __shared__ float smem[8192];   // 32 KB: staging + epilogue reuse
  unsigned short* Al = (unsigned short*)smem;
  unsigned short* Bl = Al + BM*64;
  const int bm = blockIdx.x*BM;
  const int bn = blockIdx.y*128;
  const int t = threadIdx.x;
  const int w = t>>6, l = t&63;
  const int wr = w>>1, wc = w&1;
  f4v acc[RT][4];
  #pragma unroll
  for (int i=0;i<RT;++i)
    #pragma unroll
    for (int j=0;j<4;++j) acc[i][j] = (f4v){0.f,0.f,0.f,0.f};
  const int srow = t>>3, sseg = t&7;
  for (int k0 = 0; k0 < K; k0 += 64) {
    #pragma unroll
    for (int c=0;c<BM/32;++c){
      int row = c*32 + srow;
      GLOAD16(A + (size_t)(bm+row)*K + k0 + ((sseg ^ (row&7))<<3),
              (char*)Al + c*4096 + w*1024);
    }
    #pragma unroll
    for (int c=0;c<4;++c){
      int row = c*32 + srow;
      GLOAD16(Bt + (size_t)(bn+row)*K + k0 + ((sseg ^ (row&7))<<3),
              (char*)Bl + c*4096 + w*1024);
    }
    __syncthreads();
    #pragma unroll
    for (int ks=0;ks<2;++ks){
      s8v bf[4];
      #pragma unroll
      for (int ct=0;ct<4;++ct){
        int col = wc*64 + ct*16 + (l&15);
        bf[ct] = *(const s8v*)((const char*)Bl + col*128 + ((((l>>4)+ks*4) ^ (col&7))<<4));
      }
      #pragma unroll
      for (int rt=0;rt<RT;++rt){
        int arow = wr*(RT*16) + rt*16 + (l&15);
        s8v af = *(const s8v*)((const char*)Al + arow*128 + ((((l>>4)+ks*4) ^ (arow&7))<<4));
        #pragma unroll
        for (int ct=0;ct<4;++ct)
          acc[rt][ct] = MFMA16(af, bf[ct], acc[rt][ct]);
      }
    }
    __syncthreads();
  }
  float bia[4];
  #pragma unroll
  for (int ct=0;ct<4;++ct) bia[ct] = bias[bn + wc*64 + ct*16 + (l&15)];
  if (EPI == 0) {
    unsigned short* lds = (unsigned short*)smem;
    if (bn < 1024) {
      #pragma unroll
      for (int rt=0;rt<RT;++rt)
        #pragma unroll
        for (int ct=0;ct<4;++ct)
          #pragma unroll
          for (int r=0;r<4;++r){
            int rr = wr*(RT*16) + rt*16 + (l>>4)*4 + r;
            int cc = wc*64 + ct*16 + (l&15);
            lds[rr*128 + cc] = f2bf(acc[rt][ct][r] + bia[ct]);
          }
      __syncthreads();
      #pragma unroll
      for (int it=0; it<BM/16; ++it){
        int row = it*16 + (t>>4), seg = t&15;
        u4v v = *(const u4v*)(lds + row*128 + seg*8);
        *(u4v*)(qkb + (size_t)(bm+row)*1024 + bn + seg*8) = v;
      }
    } else {
      #pragma unroll
      for (int rt=0;rt<RT;++rt)
        #pragma unroll
        for (int ct=0;ct<4;++ct){
          int rbase = bm + wr*(RT*16) + rt*16 + (l>>4)*4;
          int bb = rbase >> 9, nn = rbase & 511;
          int d = bn - 1024 + wc*64 + ct*16 + (l&15);
          unsigned int lo = (unsigned int)f2bf(acc[rt][ct][0] + bia[ct])
                          | ((unsigned int)f2bf(acc[rt][ct][1] + bia[ct])<<16);
          unsigned int hi = (unsigned int)f2bf(acc[rt][ct][2] + bia[ct])
                          | ((unsigned int)f2bf(acc[rt][ct][3] + bia[ct])<<16);
          uint2 pk; pk.x = lo; pk.y = hi;
          *(uint2*)(vT + ((size_t)(bb*512 + d))*512 + nn) = pk;
        }
    }
  } else {
    // stage v into f32 LDS then per-row LN
    float* vst = smem;
    #pragma unroll
    for (int rt=0;rt<RT;++rt)
      #pragma unroll
      for (int ct=0;ct<4;++ct)
        #pragma unroll
        for (int r=0;r<4;++r){
          int rr = wr*(RT*16) + rt*16 + (l>>4)*4 + r;
          int cc = wc*64 + ct*16 + (l&15);
          float v = acc[rt][ct][r] + bia[ct];
          if (EPI == 1) v += res[(size_t)(bm+rr)*128 + cc];
          if (EPI == 2) v = res[(size_t)(bm+rr)*128 + cc] + softplus_f(v);
          vst[rr*128 + cc] = v;
        }
    __syncthreads();
    const float2 g1v = *(const float2*)(g1 + l*2);
    const float2 b1v = *(const float2*)(b1 + l*2);
    for (int rr=0; rr<16; ++rr){
      int row = w*16 + rr;
      float2 vv = *(const float2*)&vst[row*128 + l*2];
      float s = vv.x+vv.y, sq = vv.x*vv.x + vv.y*vv.y;
      #pragma unroll
      for (int m=1;m<64;m<<=1){ s += __shfl_xor(s,m,64); sq += __shfl_xor(sq,m,64); }
      float mean = s*(1.f/128.f);
      float rstd = rsqrtf(sq*(1.f/128.f) - mean*mean + 1e-5f);
      float xa = (vv.x-mean)*rstd*g1v.x + b1v.x;
      float xb = (vv.y-mean)*rstd*g1v.y + b1v.y;
      if (EPI == 1) {
        *(float2*)(outF + (size_t)(bm+row)*128 + l*2) = vv;
        unsigned int pk = (unsigned int)f2bf(xa) | ((unsigned int)f2bf(xb)<<16);
        *(unsigned int*)(xnbO + (size_t)(bm+row)*128 + l*2) = pk;
      } else {
        float2 xo; xo.x = xa; xo.y = xb;
        *(float2*)(outF + (size_t)(bm+row)*128 + l*2) = xo;
        if (g2) {
          float s2 = xa+xb, sq2 = xa*xa + xb*xb;
          #pragma unroll
          for (int m=1;m<64;m<<=1){ s2 += __shfl_xor(s2,m,64); sq2 += __shfl_xor(sq2,m,64); }
          float mean2 = s2*(1.f/128.f);
          float rstd2 = rsqrtf(sq2*(1.f/128.f) - mean2*mean2 + 1e-5f);
          const float2 g2v = *(const float2*)(g2 + l*2);
          const float2 b2v = *(const float2*)(b2 + l*2);
          float ya = (xa-mean2)*rstd2*g2v.x + b2v.x;
          float yb = (xb-mean2)*rstd2*g2v.y + b2v.y;
          unsigned int pk = (unsigned int)f2bf(ya) | ((unsigned int)f2bf(yb)<<16);
          *(unsigned int*)(xnbO + (size_t)(bm+row)*128 + l*2) = pk;
        }
      }
    }
  }
}

// ---------- attention stage A ----------
__global__ __launch_bounds__(256) void attnA_kernel(
    const unsigned short* __restrict__ qkb, const float* __restrict__ w_row,
    unsigned short* __restrict__ P, float* __restrict__ Sinv) {
  __shared__ unsigned short Qlds[64*128];
  __shared__ unsigned short Klds[64*128];
  __shared__ unsigned short Ptile[64*64];
  __shared__ float w_s[512];
  const int i0 = blockIdx.x*64;
  const int h = blockIdx.y, b = blockIdx.z;
  const int t = threadIdx.x, w = t>>6, l = t&63;
  const float SC = 0.088388347648318447f;   // 1/sqrt(128)
  for (int j=t;j<512;j+=256) w_s[j] = w_row[b*512+j];
  {
    int row = t>>4, seg = t&15;
    #pragma unroll
    for (int c=0;c<4;++c)
      GLOAD16(qkb + (size_t)(b*512 + i0 + c*16 + row)*1024 + h*128 + ((seg ^ (row&7))<<3),
              (char*)Qlds + c*4096 + w*1024);
  }
  __syncthreads();
  s8v qf[4];
  #pragma unroll
  for (int ks=0;ks<4;++ks){
    int arow = w*16 + (l&15);
    qf[ks] = *(const s8v*)((const char*)Qlds + arow*256 + ((((l>>4)+ks*4) ^ (arow&7))<<4));
  }
  float sp[4] = {0.f,0.f,0.f,0.f};
  for (int j0=0;j0<512;j0+=64){
    {
      int row = t>>4, seg = t&15;
      #pragma unroll
      for (int c=0;c<4;++c)
        GLOAD16(qkb + (size_t)(b*512 + j0 + c*16 + row)*1024 + 512 + h*128 + ((seg ^ (row&7))<<3),
                (char*)Klds + c*4096 + w*1024);
    }
    __syncthreads();
    #pragma unroll
    for (int jt=0;jt<4;++jt){
      f4v a = (f4v){0.f,0.f,0.f,0.f};
      #pragma unroll
      for (int ks=0;ks<4;++ks){
        int col = jt*16 + (l&15);
        s8v kf = *(const s8v*)((const char*)Klds + col*256 + ((((l>>4)+ks*4) ^ (col&7))<<4));
        a = MFMA16(qf[ks], kf, a);
      }
      int jl = jt*16 + (l&15);
      float mw = (w_s[j0+jl] != 0.f) ? 1.f : 0.f;
      #pragma unroll
      for (int r=0;r<4;++r){
        float e = __expf(a[r]*SC);
        sp[r] += e*mw;
        Ptile[(w*16 + (l>>4)*4 + r)*64 + jl] = f2bf(e);
      }
    }
    __syncthreads();
    #pragma unroll
    for (int it=0;it<2;++it){
      int row = it*32 + (t>>3), seg = t&7;
      u4v pv = *(const u4v*)(Ptile + row*64 + seg*8);
      *(u4v*)(P + ((size_t)((b*4+h)*512 + i0 + row))*512 + j0 + seg*8) = pv;
    }
  }
  #pragma unroll
  for (int r=0;r<4;++r){
    float s = sp[r];
    s += __shfl_xor(s,1,64); s += __shfl_xor(s,2,64);
    s += __shfl_xor(s,4,64); s += __shfl_xor(s,8,64);
    sp[r] = s;
  }
  if ((l&15)==0){
    #pragma unroll
    for (int r=0;r<4;++r)
      Sinv[(size_t)(b*4+h)*512 + i0 + w*16 + (l>>4)*4 + r] = 1.f/sp[r];
  }
}

// ---------- attention stage B ----------
__global__ __launch_bounds__(256) void attnB_kernel(
    const unsigned short* __restrict__ P, const float* __restrict__ Sinv,
    const unsigned short* __restrict__ vT, const float* __restrict__ w_row,
    unsigned short* __restrict__ att) {
  __shared__ unsigned short Vlds[512*64];
  __shared__ unsigned short cA[64*64];
  __shared__ float w_s[512];
  __shared__ float sinv_s[4][64];
  __shared__ float zred[64][4];
  __shared__ float zinv_s[64];
  const int i0 = blockIdx.x*64, b = blockIdx.y;
  const int t = threadIdx.x, w = t>>6, l = t&63;
  for (int j=t;j<512;j+=256) w_s[j] = w_row[b*512+j];
  { int hh = t>>6, ii = t&63;
    sinv_s[hh][ii] = Sinv[(size_t)(b*4+hh)*512 + i0 + ii]; }
  __syncthreads();
  f4v acc[4][8];
  #pragma unroll
  for (int i=0;i<4;++i)
    #pragma unroll
    for (int j=0;j<8;++j) acc[i][j] = (f4v){0.f,0.f,0.f,0.f};
  const int ci = t>>2, cjq = t&3;
  float zacc = 0.f;
  for (int j0=0;j0<512;j0+=64){
    { int seg = t&7;
      #pragma unroll
      for (int c=0;c<16;++c){
        int d = c*32 + (t>>3);
        GLOAD16(vT + ((size_t)(b*512 + d))*512 + j0 + ((seg ^ (d&7))<<3),
                (char*)Vlds + c*4096 + w*1024);
      }
    }
    float cv[16];
    #pragma unroll
    for (int e=0;e<16;++e) cv[e]=0.f;
    #pragma unroll
    for (int hh=0;hh<4;++hh){
      const unsigned short* pp = P + ((size_t)((b*4+hh)*512 + i0 + ci))*512 + j0 + cjq*16;
      u4v p0 = *(const u4v*)pp;
      u4v p1 = *(const u4v*)(pp+8);
      float si = sinv_s[hh][ci];
      #pragma unroll
      for (int e=0;e<4;++e){
        cv[2*e]     += bf2f(p0[e]&0xffffu)*si;
        cv[2*e+1]   += bf2f(p0[e]>>16)*si;
        cv[8+2*e]   += bf2f(p1[e]&0xffffu)*si;
        cv[8+2*e+1] += bf2f(p1[e]>>16)*si;
      }
    }
    us8v pk0, pk1;
    #pragma unroll
    for (int e=0;e<8;++e){
      float v0 = cv[e]   * w_s[j0 + cjq*16 + e];
      float v1 = cv[8+e] * w_s[j0 + cjq*16 + 8 + e];
      zacc += v0 + v1;
      pk0[e] = f2bf(v0); pk1[e] = f2bf(v1);
    }
    *(us8v*)((char*)cA + ci*128 + (((cjq*2)   ^ (ci&7))<<4)) = pk0;
    *(us8v*)((char*)cA + ci*128 + (((cjq*2+1) ^ (ci&7))<<4)) = pk1;
    __syncthreads();
    #pragma unroll
    for (int ks=0;ks<2;++ks){
      s8v af[4];
      #pragma unroll
      for (int rt=0;rt<4;++rt){
        int arow = rt*16 + (l&15);
        af[rt] = *(const s8v*)((const char*)cA + arow*128 + ((((l>>4)+ks*4) ^ (arow&7))<<4));
      }
      #pragma unroll
      for (int ct=0;ct<8;++ct){
        int d = w*128 + ct*16 + (l&15);
        s8v vf = *(const s8v*)((const char*)Vlds + d*128 + ((((l>>4)+ks*4) ^ (d&7))<<4));
        #pragma unroll
        for (int rt=0;rt<4;++rt)
          acc[rt][ct] = MFMA16(af[rt], vf, acc[rt][ct]);
      }
    }
    __syncthreads();
  }
  zred[ci][cjq] = zacc;
  __syncthreads();
  if (t < 64) zinv_s[t] = 1.f/(zred[t][0]+zred[t][1]+zred[t][2]+zred[t][3]);
  __syncthreads();
  #pragma unroll
  for (int rt=0;rt<4;++rt)
    #pragma unroll
    for (int ct=0;ct<8;++ct)
      #pragma unroll
      for (int r=0;r<4;++r){
        int rr = rt*16 + (l>>4)*4 + r;
        int d = w*128 + ct*16 + (l&15);
        Vlds[rr*512 + d] = f2bf(acc[rt][ct][r]*zinv_s[rr]);
      }
  __syncthreads();
  #pragma unroll
  for (int it=0; it<16; ++it){
    int row = it*4 + w;
    u4v v = *(const u4v*)(Vlds + row*512 + l*8);
    *(u4v*)(att + ((size_t)(b*512 + i0 + row))*512 + l*8) = v;
  }
}

// ---------- pooling (parallel partials) + final ----------
__global__ __launch_bounds__(128) void pool_part_kernel(const float* __restrict__ x,
    const float* __restrict__ x_init,
    const float* __restrict__ w_row, float* __restrict__ partial) {
  int b = blockIdx.x, p = blockIdx.y, e = threadIdx.x;
  float acc = 0.f;
  for (int n = p*64; n < p*64+64; ++n) {
    float w = w_row[(size_t)b*N_ + n];
    size_t o = ((size_t)b*N_ + n)*E_ + e;
    acc += w * (x[o] + x_init[o]);
  }
  partial[((size_t)b*8 + p)*E_ + e] = acc;
}

__global__ __launch_bounds__(128) void final_kernel(const float* __restrict__ partial,
    const float* __restrict__ g, const float* __restrict__ bt,
    const float* __restrict__ fw, const float* __restrict__ fb, float* __restrict__ out) {
  int b = blockIdx.x, t = threadIdx.x;
  float v = 0.f;
  for (int p=0;p<8;++p) v += partial[((size_t)b*8+p)*E_ + t];
  float s = v, sq = v*v;
  #pragma unroll
  for (int m = 1; m < 64; m <<= 1) { s += __shfl_xor(s, m, 64); sq += __shfl_xor(sq, m, 64); }
  __shared__ float red[4];
  int wv = t >> 6, ln = t & 63;
  if (ln == 0) { red[wv*2] = s; red[wv*2+1] = sq; }
  __syncthreads();
  s = red[0] + red[2]; sq = red[1] + red[3];
  float mean = s*(1.f/E_), var = sq*(1.f/E_) - mean*mean;
  float rstd = rsqrtf(var + 1e-5f);
  float xl = (v - mean)*rstd*g[t] + bt[t];
  float p = xl * fw[t];
  #pragma unroll
  for (int m = 1; m < 64; m <<= 1) p += __shfl_xor(p, m, 64);
  __shared__ float red2[2];
  if (ln == 0) red2[wv] = p;
  __syncthreads();
  if (t == 0) out[b] = red2[0] + red2[1] + fb[0];
}

extern "C" void kernel_launch(void* const* d_in, const int* in_sizes, int n_in,
                              void* d_out, int out_size, void* d_ws, size_t ws_size,
                              hipStream_t stream) {
  (void)in_sizes; (void)n_in; (void)out_size; (void)ws_size;
  const float* str_fea  = (const float*)d_in[0];
  const int*   comp_fea = (const int*)  d_in[1];
  const float* af_table = (const float*)d_in[3];
  const float* comp_w   = (const float*)d_in[4];
  const float* comp_b   = (const float*)d_in[5];
  const float* emb_w    = (const float*)d_in[6];
  const float* emb_b    = (const float*)d_in[7];
  const float* ln_g     = (const float*)d_in[8];
  const float* ln_b     = (const float*)d_in[9];
  const float* wq       = (const float*)d_in[10];
  const float* bq       = (const float*)d_in[11];
  const float* wk       = (const float*)d_in[12];
  const float* bk       = (const float*)d_in[13];
  const float* wv       = (const float*)d_in[14];
  const float* bv       = (const float*)d_in[15];
  const float* inproj_w = (const float*)d_in[16];
  const float* inproj_b = (const float*)d_in[17];
  const float* out_w    = (const float*)d_in[18];
  const float* out_b    = (const float*)d_in[19];
  const float* ffn_w    = (const float*)d_in[20];
  const float* ffn_b    = (const float*)d_in[21];
  const float* ln2_g    = (const float*)d_in[22];
  const float* ln2_b    = (const float*)d_in[23];
  const float* final_w  = (const float*)d_in[24];
  const float* final_b  = (const float*)d_in[25];
  float* out = (float*)d_out;

  float* ws = (float*)d_ws;
  size_t off = 0;
  float* x      = ws + off; off += 2097152;
  float* x_init = ws + off; off += 2097152;
  float* o1     = ws + off; off += 2097152;
  float* w_row  = ws + off; off += 16384;
  unsigned short* xnb  = (unsigned short*)(ws + off); off += 1048576;   // [M][128]
  unsigned short* qkb  = (unsigned short*)(ws + off); off += 8388608;   // [M][1024]
  unsigned short* vTb  = (unsigned short*)(ws + off); off += 4194304;   // [B][512][512]
  unsigned short* attb = (unsigned short*)(ws + off); off += 4194304;   // [M][512]
  unsigned short* Pb   = (unsigned short*)(ws + off); off += 16777216;  // [B][H][512][512]
  float* Sinvb  = ws + off; off += 65536;
  float* bq_eff = ws + off; off += 1536;
  float* bk_eff = ws + off; off += 1536;
  float* bqkv   = ws + off; off += 4608;
  unsigned short* wqkvT = (unsigned short*)(ws + off); off += 294912;   // [3][1536][128]
  unsigned short* outT  = (unsigned short*)(ws + off); off += 98304;    // [3][128][512]
  unsigned short* ffnT  = (unsigned short*)(ws + off); off += 24576;    // [3][128][128]
  unsigned short* FHi   = (unsigned short*)(ws + off); off += 2621440;  // [M][320]
  unsigned short* FLo   = (unsigned short*)(ws + off); off += 2621440;
  unsigned short* WHi   = (unsigned short*)(ws + off); off += 20480;    // [128][320]
  unsigned short* WLo   = (unsigned short*)(ws + off); off += 20480;
  float* biasE  = ws + off; off += 128;
  float* Cpart  = ws + off; off += 1280;
  float* partial= ws + off; off += 32768;

  eff_gemm_kernel<<<48, 256, 0, stream>>>(wq, wk, inproj_w, wqkvT);
  eff_b_kernel<<<12, 256, 0, stream>>>(bq, bk, inproj_w, inproj_b, bq_eff, bk_eff);
  wconv2_kernel<<<768, 256, 0, stream>>>(wv, out_w, ffn_w, bq_eff, bk_eff, bv,
                                         wqkvT, outT, ffnT, bqkv);
  embW1_kernel<<<12, 128, 0, stream>>>(emb_w, comp_w, WHi, WLo, Cpart);
  embBias_kernel<<<1, 128, 0, stream>>>(Cpart, comp_b, emb_b, biasE);
  feat_kernel<<<M_/64, 256, 0, stream>>>(str_fea, comp_fea, af_table, FHi, FLo, w_row);
  embgemm_kernel<<<M_/64, 256, 0, stream>>>(FHi, FLo, WHi, WLo, biasE,
                                            ln_g, ln_b, x, x_init, xnb);

  for (int l = 0; l < L_; ++l) {
    mgemm_kernel<4,0><<<dim3(M_/128, 12), 256, 0, stream>>>(
        xnb, wqkvT + (size_t)l*196608, bqkv + l*1536, nullptr,
        qkb, vTb, nullptr, nullptr, nullptr, nullptr, nullptr, nullptr, 128);
    attnA_kernel<<<dim3(8, 4, 32), 256, 0, stream>>>(qkb, w_row, Pb, Sinvb);
    attnB_kernel<<<dim3(8, 32), 256, 0, stream>>>(Pb, Sinvb, vTb, w_row, attb);
    mgemm_kernel<2,1><<<dim3(M_/64, 1), 256, 0, stream>>>(
        attb, outT + (size_t)l*65536, out_b + (size_t)l*E_, x,
        nullptr, nullptr, o1, xnb, ln_g + l*E_, ln_b + l*E_, nullptr, nullptr, 512);
    mgemm_kernel<2,2><<<dim3(M_/64, 1), 256, 0, stream>>>(
        xnb, ffnT + (size_t)l*16384, ffn_b + (size_t)l*E_, o1,
        nullptr, nullptr, x, xnb, ln_g + l*E_, ln_b + l*E_,
        (l < 2) ? (ln_g + (l+1)*E_) : nullptr,
        (l < 2) ? (ln_b + (l+1)*E_) : nullptr, 128);
  }

  pool_part_kernel<<<dim3(B_, 8), 128, 0, stream>>>(x, x_init, w_row, partial);
  final_kernel<<<B_, 128, 0, stream>>>(partial, ln2_g, ln2_b, final_w, final_b, out);
}

// Round 4
// 508.659 us; speedup vs baseline: 6.8653x; 1.1124x over previous
//
#include <hip/hip_runtime.h>
#include <math.h>

#define B_ 32
#define N_ 512
#define F_ 101
#define E_ 128
#define H_ 4
#define EH_ 512
#define L_ 3
#define M_ (B_*N_)   // 16384

typedef __attribute__((ext_vector_type(8))) short s8v;
typedef __attribute__((ext_vector_type(8))) unsigned short us8v;
typedef __attribute__((ext_vector_type(4))) float f4v;
typedef __attribute__((ext_vector_type(4))) unsigned int u4v;

__device__ __forceinline__ unsigned short f2bf(float f){
  unsigned int u = __builtin_bit_cast(unsigned int, f);
  u += 0x7fffu + ((u>>16)&1u);
  return (unsigned short)(u>>16);
}
__device__ __forceinline__ float bf2f(unsigned int h){
  unsigned int u = h<<16; return __builtin_bit_cast(float, u);
}
__device__ __forceinline__ float softplus_f(float v) {
  return fmaxf(v, 0.f) + log1pf(__expf(-fabsf(v)));
}

#define GLOAD16(gp, lp) __builtin_amdgcn_global_load_lds( \
    (__attribute__((address_space(1))) unsigned int*)(gp), \
    (__attribute__((address_space(3))) unsigned int*)(lp), 16, 0, 0)

#define MFMA16(a,b,c) __builtin_amdgcn_mfma_f32_16x16x32_bf16(a,b,c,0,0,0)

// ---------- eff fold GEMM: wqkvT[l][qk*512+n][r] = bf16( sum_kk wqk[l][r][kk] * ip[kk][n] ) ----------
__global__ __launch_bounds__(256) void eff_gemm_kernel(
    const float* __restrict__ wq, const float* __restrict__ wk,
    const float* __restrict__ inproj_w, unsigned short* __restrict__ wqkvT) {
  __shared__ float As[64][132];   // [kk][r]
  __shared__ float Bs[64][68];    // [kk][c]
  const int blk = blockIdx.x;     // 48 = 6 lq * 8 ntiles
  const int lq = blk>>3, nt = blk&7;
  const int l = lq>>1, qk = lq&1;
  const int bn = nt*64;
  const float* A = (qk ? wk : wq) + (size_t)l*128*512;
  const float* IP = inproj_w + (size_t)l*512*1536 + qk*512 + bn;
  const int t = threadIdx.x;
  float acc[8][4];
  #pragma unroll
  for (int i=0;i<8;++i)
    #pragma unroll
    for (int j=0;j<4;++j) acc[i][j]=0.f;
  const int r0 = (t&15)*8, c0 = (t>>4)*4;
  for (int k0=0;k0<512;k0+=64){
    int r = t & 127, half = t>>7;
    #pragma unroll
    for (int u=0;u<8;++u){
      float4 a = *(const float4*)(A + (size_t)r*512 + k0 + half*32 + u*4);
      int kk = half*32 + u*4;
      As[kk+0][r]=a.x; As[kk+1][r]=a.y; As[kk+2][r]=a.z; As[kk+3][r]=a.w;
    }
    int kk = t>>2, cb = (t&3)*16;
    #pragma unroll
    for (int u=0;u<4;++u)
      *(float4*)&Bs[kk][cb+u*4] = *(const float4*)(IP + (size_t)(k0+kk)*1536 + cb + u*4);
    __syncthreads();
    for (int k2=0;k2<64;++k2){
      float4 b = *(const float4*)&Bs[k2][c0];
      float4 a0 = *(const float4*)&As[k2][r0];
      float4 a1 = *(const float4*)&As[k2][r0+4];
      float av[8] = {a0.x,a0.y,a0.z,a0.w,a1.x,a1.y,a1.z,a1.w};
      #pragma unroll
      for (int i=0;i<8;++i){
        acc[i][0] += av[i]*b.x; acc[i][1] += av[i]*b.y;
        acc[i][2] += av[i]*b.z; acc[i][3] += av[i]*b.w;
      }
    }
    __syncthreads();
  }
  #pragma unroll
  for (int j=0;j<4;++j){
    us8v pk;
    #pragma unroll
    for (int i=0;i<8;++i) pk[i] = f2bf(acc[i][j]);
    *(us8v*)(wqkvT + ((size_t)l*1536 + qk*512 + bn + c0 + j)*128 + r0) = pk;
  }
}

__global__ __launch_bounds__(256) void eff_b_kernel(
    const float* __restrict__ bq, const float* __restrict__ bk,
    const float* __restrict__ inproj_w, const float* __restrict__ inproj_b,
    float* __restrict__ bq_eff, float* __restrict__ bk_eff) {
  int idx = blockIdx.x*256 + threadIdx.x;       // 3*2*512 = 3072
  if (idx >= 3072) return;
  int c = idx & 511;
  int lq = idx >> 9; int l = lq >> 1, qk = lq & 1;
  const float* bv = (qk ? bk : bq) + (size_t)l*EH_;
  int cc = qk ? EH_ + c : c;
  const float* ip = inproj_w + (size_t)l*EH_*3*EH_ + cc;
  float acc = inproj_b[(size_t)l*3*EH_ + cc];
  for (int kk = 0; kk < EH_; ++kk) acc += bv[kk]*ip[(size_t)kk*3*EH_];
  (qk ? bk_eff : bq_eff)[(size_t)l*EH_ + c] = acc;
}

// ---------- pack v-part of wqkvT, outT, ffnT, bqkv ----------
__global__ __launch_bounds__(256) void wconv2_kernel(
    const float* __restrict__ wv, const float* __restrict__ out_w,
    const float* __restrict__ ffn_w,
    const float* __restrict__ bq_eff, const float* __restrict__ bk_eff,
    const float* __restrict__ bvv,
    unsigned short* __restrict__ wqkvT, unsigned short* __restrict__ outT,
    unsigned short* __restrict__ ffnT, float* __restrict__ bqkv) {
  int idx = blockIdx.x*256 + threadIdx.x;   // 768*256 = 196608
  {  // v part: wqkvT[l][1024+n][k] = wv[l][k][n]
    int k = idx & 127; int nl = idx >> 7; int n = nl & 511; int lay = nl >> 9;
    wqkvT[((size_t)lay*1536 + 1024 + n)*128 + k] =
        f2bf(wv[((size_t)lay*128 + k)*512 + n]);
  }
  {  // outT[l][n][k] = out_w[l][k][n]
    int k = idx & 511; int nl = idx >> 9; int n = nl & 127; int lay = nl >> 7;
    outT[idx] = f2bf(out_w[((size_t)lay*512 + k)*128 + n]);
  }
  if (idx < 3*128*128) {   // ffnT[l][n][k] = ffn_w[l][k][n]
    int k = idx & 127; int nl = idx >> 7; int n = nl & 127; int lay = nl >> 7;
    ffnT[idx] = f2bf(ffn_w[((size_t)lay*128 + k)*128 + n]);
  }
  if (idx < 3*1536) {
    int n = idx % 1536; int lay = idx / 1536;
    float v = (n < 512) ? bq_eff[lay*512 + n]
            : (n < 1024) ? bk_eff[lay*512 + n - 512]
            : bvv[lay*512 + n - 1024];
    bqkv[idx] = v;
  }
}

// ---------- embed weight prep: quadratic expansion A/B/C + split bf16 ----------
__global__ __launch_bounds__(128) void embW1_kernel(
    const float* __restrict__ emb_w, const float* __restrict__ comp_w,
    unsigned short* __restrict__ WHi, unsigned short* __restrict__ WLo,
    float* __restrict__ Cpart) {
  int p = blockIdx.x, e = threadIdx.x;
  if (p < 10) {
    float Cp = 0.f;
    for (int ff=0; ff<10; ++ff){
      int f = p*10+ff;
      float A=0.f, Bv=0.f;
      #pragma unroll
      for (int s=0;s<10;++s){
        float wv = emb_w[(size_t)(f*10+s)*128 + e];
        A += wv; Bv += 0.2f*s*wv; Cp += 0.01f*(s*s)*wv;
      }
      int kA = 92+f, kB = 192+f;
      unsigned short hA = f2bf(A);
      WHi[e*320+kA]=hA; WLo[e*320+kA]=f2bf(A - bf2f(hA));
      unsigned short hB = f2bf(Bv);
      WHi[e*320+kB]=hB; WLo[e*320+kB]=f2bf(Bv - bf2f(hB));
    }
    Cpart[p*128+e] = Cp;
  } else if (p == 10) {
    for (int kk=0;kk<92;++kk){
      float v = comp_w[(size_t)kk*128 + e];
      unsigned short h = f2bf(v);
      WHi[e*320+kk]=h; WLo[e*320+kk]=f2bf(v - bf2f(h));
    }
  } else {
    for (int kk=292;kk<320;++kk){ WHi[e*320+kk]=0; WLo[e*320+kk]=0; }
  }
}

__global__ __launch_bounds__(128) void embBias_kernel(
    const float* __restrict__ Cpart, const float* __restrict__ comp_b,
    const float* __restrict__ emb_b, float* __restrict__ biasE){
  int e = threadIdx.x; float c=0.f;
  for (int p=0;p<10;++p) c += Cpart[p*128+e];
  biasE[e] = comp_b[e] + emb_b[e] + c;
}

// ---------- feature builder (coalesced): one thread per (row, 8-col seg) ----------
__global__ __launch_bounds__(256) void feat_kernel(
    const float* __restrict__ str_fea, const int* __restrict__ comp_fea,
    const float* __restrict__ af_table,
    unsigned short* __restrict__ FHi, unsigned short* __restrict__ FLo,
    float* __restrict__ w_row) {
  int g = blockIdx.x*256 + threadIdx.x;      // M*40 = 655360
  int row = g / 40, seg = g - row*40;
  const float* sr = str_fea + (size_t)row*F_;
  if (seg == 0) w_row[row] = sr[0];
  const float* af = af_table + (size_t)comp_fea[row]*92;
  const int c0 = seg*8;
  us8v hi, lo;
  #pragma unroll
  for (int e=0;e<8;++e){
    int kk = c0+e; float v;
    if (kk < 92) v = af[kk];
    else if (kk < 192) { float u = 1.f - sr[1+kk-92]; v = u*u; }
    else if (kk < 292) v = 1.f - sr[1+kk-192];
    else v = 0.f;
    unsigned short h = f2bf(v);
    hi[e] = h; lo[e] = f2bf(v - bf2f(h));
  }
  *(us8v*)(FHi + (size_t)row*320 + c0) = hi;
  *(us8v*)(FLo + (size_t)row*320 + c0) = lo;
}

// ---------- embed GEMM (split bf16, 3-MFMA) + LN0 epilogue ----------
__global__ __launch_bounds__(256) void embgemm_kernel(
    const unsigned short* __restrict__ FHi, const unsigned short* __restrict__ FLo,
    const unsigned short* __restrict__ WHi, const unsigned short* __restrict__ WLo,
    const float* __restrict__ biasE,
    const float* __restrict__ g0, const float* __restrict__ b0,
    float* __restrict__ x, float* __restrict__ x_init,
    unsigned short* __restrict__ xnb) {
  __shared__ unsigned short lds[24576];    // 48 KB
  unsigned short* AHi = lds;
  unsigned short* ALo = lds + 4096;
  unsigned short* BHi = lds + 8192;
  unsigned short* BLo = lds + 16384;
  const int bm = blockIdx.x*64;
  const int t = threadIdx.x, w = t>>6, l = t&63;
  f4v acc[8];
  #pragma unroll
  for (int i=0;i<8;++i) acc[i] = (f4v){0.f,0.f,0.f,0.f};
  const int srow = t>>3, sseg = t&7;
  for (int k0=0;k0<320;k0+=64){
    #pragma unroll
    for (int c=0;c<2;++c){
      int row = c*32+srow;
      GLOAD16(FHi + (size_t)(bm+row)*320 + k0 + ((sseg^(row&7))<<3), (char*)AHi + c*4096 + w*1024);
      GLOAD16(FLo + (size_t)(bm+row)*320 + k0 + ((sseg^(row&7))<<3), (char*)ALo + c*4096 + w*1024);
    }
    #pragma unroll
    for (int c=0;c<4;++c){
      int row = c*32+srow;
      GLOAD16(WHi + (size_t)row*320 + k0 + ((sseg^(row&7))<<3), (char*)BHi + c*4096 + w*1024);
      GLOAD16(WLo + (size_t)row*320 + k0 + ((sseg^(row&7))<<3), (char*)BLo + c*4096 + w*1024);
    }
    __syncthreads();
    #pragma unroll
    for (int ks=0;ks<2;++ks){
      int arow = w*16 + (l&15);
      int aswz = ((((l>>4)+ks*4) ^ (arow&7))<<4);
      s8v ah = *(const s8v*)((const char*)AHi + arow*128 + aswz);
      s8v al = *(const s8v*)((const char*)ALo + arow*128 + aswz);
      #pragma unroll
      for (int ct=0;ct<8;++ct){
        int col = ct*16 + (l&15);
        int bswz = ((((l>>4)+ks*4) ^ (col&7))<<4);
        s8v bh = *(const s8v*)((const char*)BHi + col*128 + bswz);
        s8v bl = *(const s8v*)((const char*)BLo + col*128 + bswz);
        acc[ct] = MFMA16(ah, bh, acc[ct]);
        acc[ct] = MFMA16(ah, bl, acc[ct]);
        acc[ct] = MFMA16(al, bh, acc[ct]);
      }
    }
    __syncthreads();
  }
  float vv[8][4], gc[8], bc[8];
  #pragma unroll
  for (int ct=0;ct<8;++ct){
    int c = ct*16 + (l&15);
    float be = biasE[c]; gc[ct] = g0[c]; bc[ct] = b0[c];
    #pragma unroll
    for (int r=0;r<4;++r) vv[ct][r] = acc[ct][r] + be;
  }
  #pragma unroll
  for (int r=0;r<4;++r){
    float s=0.f, sq=0.f;
    #pragma unroll
    for (int ct=0;ct<8;++ct){ s += vv[ct][r]; sq += vv[ct][r]*vv[ct][r]; }
    #pragma unroll
    for (int m=1;m<16;m<<=1){ s += __shfl_xor(s,m,64); sq += __shfl_xor(sq,m,64); }
    float mean = s*(1.f/128.f);
    float rstd = rsqrtf(sq*(1.f/128.f) - mean*mean + 1e-5f);
    int row = bm + w*16 + (l>>4)*4 + r;
    #pragma unroll
    for (int ct=0;ct<8;++ct){
      int c = ct*16 + (l&15);
      float v = vv[ct][r];
      x[(size_t)row*128 + c] = v;
      x_init[(size_t)row*128 + c] = v;
      xnb[(size_t)row*128 + c] = f2bf((v-mean)*rstd*gc[ct] + bc[ct]);
    }
  }
}

// ---------- bf16 MFMA GEMM ----------
// EPI 0: bf16 out -> qkb (n<1024, ld 1024) or transposed vT (n>=1024)
// EPI 3: batched (z=b): plain bf16 out, ld 512, rowbase z*512+bm, no bias
template<int RT, int EPI>
__global__ __launch_bounds__(256) void mgemm_kernel(
    const unsigned short* __restrict__ A,
    const unsigned short* __restrict__ Bt,
    const float* __restrict__ bias,
    unsigned short* __restrict__ Cb,
    unsigned short* __restrict__ vT,
    int K) {
  constexpr int BM = RT*32;
  __shared__ float smem[8192];   // 32 KB
  unsigned short* Al = (unsigned short*)smem;
  unsigned short* Bl = Al + BM*64;
  if (EPI == 3) {
    A  += (size_t)blockIdx.z*512*K;
    Bt += (size_t)blockIdx.z*512*K;
  }
  const int bm = blockIdx.x*BM;
  const int bn = blockIdx.y*128;
  const int t = threadIdx.x;
  const int w = t>>6, l = t&63;
  const int wr = w>>1, wc = w&1;
  f4v acc[RT][4];
  #pragma unroll
  for (int i=0;i<RT;++i)
    #pragma unroll
    for (int j=0;j<4;++j) acc[i][j] = (f4v){0.f,0.f,0.f,0.f};
  const int srow = t>>3, sseg = t&7;
  for (int k0 = 0; k0 < K; k0 += 64) {
    #pragma unroll
    for (int c=0;c<BM/32;++c){
      int row = c*32 + srow;
      GLOAD16(A + (size_t)(bm+row)*K + k0 + ((sseg ^ (row&7))<<3),
              (char*)Al + c*4096 + w*1024);
    }
    #pragma unroll
    for (int c=0;c<4;++c){
      int row = c*32 + srow;
      GLOAD16(Bt + (size_t)(bn+row)*K + k0 + ((sseg ^ (row&7))<<3),
              (char*)Bl + c*4096 + w*1024);
    }
    __syncthreads();
    #pragma unroll
    for (int ks=0;ks<2;++ks){
      s8v bf[4];
      #pragma unroll
      for (int ct=0;ct<4;++ct){
        int col = wc*64 + ct*16 + (l&15);
        bf[ct] = *(const s8v*)((const char*)Bl + col*128 + ((((l>>4)+ks*4) ^ (col&7))<<4));
      }
      #pragma unroll
      for (int rt=0;rt<RT;++rt){
        int arow = wr*(RT*16) + rt*16 + (l&15);
        s8v af = *(const s8v*)((const char*)Al + arow*128 + ((((l>>4)+ks*4) ^ (arow&7))<<4));
        #pragma unroll
        for (int ct=0;ct<4;++ct)
          acc[rt][ct] = MFMA16(af, bf[ct], acc[rt][ct]);
      }
    }
    __syncthreads();
  }
  float bia[4];
  #pragma unroll
  for (int ct=0;ct<4;++ct)
    bia[ct] = (EPI==3) ? 0.f : bias[bn + wc*64 + ct*16 + (l&15)];
  unsigned short* lds16 = (unsigned short*)smem;
  if (EPI == 3 || bn < 1024) {
    #pragma unroll
    for (int rt=0;rt<RT;++rt)
      #pragma unroll
      for (int ct=0;ct<4;++ct)
        #pragma unroll
        for (int r=0;r<4;++r){
          int rr = wr*(RT*16) + rt*16 + (l>>4)*4 + r;
          int cc = wc*64 + ct*16 + (l&15);
          lds16[rr*128 + cc] = f2bf(acc[rt][ct][r] + bia[ct]);
        }
    __syncthreads();
    const int ldC = (EPI==3) ? 512 : 1024;
    const size_t rowbase = (EPI==3) ? ((size_t)blockIdx.z*512 + bm) : (size_t)bm;
    #pragma unroll
    for (int it=0; it<BM/16; ++it){
      int row = it*16 + (t>>4), seg = t&15;
      u4v v = *(const u4v*)(lds16 + row*128 + seg*8);
      *(u4v*)(Cb + (rowbase+row)*ldC + bn + seg*8) = v;
    }
  } else {
    #pragma unroll
    for (int rt=0;rt<RT;++rt)
      #pragma unroll
      for (int ct=0;ct<4;++ct){
        int rbase = bm + wr*(RT*16) + rt*16 + (l>>4)*4;
        int bb = rbase >> 9, nn = rbase & 511;
        int d = bn - 1024 + wc*64 + ct*16 + (l&15);
        unsigned int lo = (unsigned int)f2bf(acc[rt][ct][0] + bia[ct])
                        | ((unsigned int)f2bf(acc[rt][ct][1] + bia[ct])<<16);
        unsigned int hi = (unsigned int)f2bf(acc[rt][ct][2] + bia[ct])
                        | ((unsigned int)f2bf(acc[rt][ct][3] + bia[ct])<<16);
        uint2 pk; pk.x = lo; pk.y = hi;
        *(uint2*)(vT + ((size_t)(bb*512 + d))*512 + nn) = pk;
      }
  }
}

// ---------- attention stage A: P = exp(QK^T*sc), Sinv ----------
__global__ __launch_bounds__(256) void attnA_kernel(
    const unsigned short* __restrict__ qkb, const float* __restrict__ w_row,
    unsigned short* __restrict__ P, float* __restrict__ Sinv) {
  __shared__ unsigned short Qlds[64*128];
  __shared__ unsigned short Klds[64*128];
  __shared__ unsigned short Ptile[64*64];
  __shared__ float w_s[512];
  const int i0 = blockIdx.x*64;
  const int h = blockIdx.y, b = blockIdx.z;
  const int t = threadIdx.x, w = t>>6, l = t&63;
  const float SC = 0.088388347648318447f;   // 1/sqrt(128)
  for (int j=t;j<512;j+=256) w_s[j] = w_row[b*512+j];
  {
    int row = t>>4, seg = t&15;
    #pragma unroll
    for (int c=0;c<4;++c)
      GLOAD16(qkb + (size_t)(b*512 + i0 + c*16 + row)*1024 + h*128 + ((seg ^ (row&7))<<3),
              (char*)Qlds + c*4096 + w*1024);
  }
  __syncthreads();
  s8v qf[4];
  #pragma unroll
  for (int ks=0;ks<4;++ks){
    int arow = w*16 + (l&15);
    qf[ks] = *(const s8v*)((const char*)Qlds + arow*256 + ((((l>>4)+ks*4) ^ (arow&7))<<4));
  }
  float sp[4] = {0.f,0.f,0.f,0.f};
  for (int j0=0;j0<512;j0+=64){
    {
      int row = t>>4, seg = t&15;
      #pragma unroll
      for (int c=0;c<4;++c)
        GLOAD16(qkb + (size_t)(b*512 + j0 + c*16 + row)*1024 + 512 + h*128 + ((seg ^ (row&7))<<3),
                (char*)Klds + c*4096 + w*1024);
    }
    __syncthreads();
    #pragma unroll
    for (int jt=0;jt<4;++jt){
      f4v a = (f4v){0.f,0.f,0.f,0.f};
      #pragma unroll
      for (int ks=0;ks<4;++ks){
        int col = jt*16 + (l&15);
        s8v kf = *(const s8v*)((const char*)Klds + col*256 + ((((l>>4)+ks*4) ^ (col&7))<<4));
        a = MFMA16(qf[ks], kf, a);
      }
      int jl = jt*16 + (l&15);
      float mw = (w_s[j0+jl] != 0.f) ? 1.f : 0.f;
      #pragma unroll
      for (int r=0;r<4;++r){
        float e = __expf(a[r]*SC);
        sp[r] += e*mw;
        Ptile[(w*16 + (l>>4)*4 + r)*64 + jl] = f2bf(e);
      }
    }
    __syncthreads();
    #pragma unroll
    for (int it=0;it<2;++it){
      int row = it*32 + (t>>3), seg = t&7;
      u4v pv = *(const u4v*)(Ptile + row*64 + seg*8);
      *(u4v*)(P + ((size_t)((b*4+h)*512 + i0 + row))*512 + j0 + seg*8) = pv;
    }
  }
  #pragma unroll
  for (int r=0;r<4;++r){
    float s = sp[r];
    s += __shfl_xor(s,1,64); s += __shfl_xor(s,2,64);
    s += __shfl_xor(s,4,64); s += __shfl_xor(s,8,64);
    sp[r] = s;
  }
  if ((l&15)==0){
    #pragma unroll
    for (int r=0;r<4;++r)
      Sinv[(size_t)(b*4+h)*512 + i0 + w*16 + (l>>4)*4 + r] = 1.f/sp[r];
  }
}

// ---------- attention stage C: combine heads, w-weight, row-normalize -> cwn ----------
__global__ __launch_bounds__(256) void attnC_kernel(
    const unsigned short* __restrict__ P, const float* __restrict__ Sinv,
    const float* __restrict__ w_row, unsigned short* __restrict__ cwn) {
  __shared__ float w_s[512];
  __shared__ float sinv_s[4][32];
  const int i0 = blockIdx.x*32, b = blockIdx.y;
  const int t = threadIdx.x;
  for (int j=t;j<512;j+=256) w_s[j] = w_row[b*512+j];
  if (t < 128) sinv_s[t>>5][t&31] = Sinv[(size_t)(b*4+(t>>5))*512 + i0 + (t&31)];
  __syncthreads();
  const int i = t>>3, jc = t&7;
  float cv[8][8];
  #pragma unroll
  for (int u=0;u<8;++u)
    #pragma unroll
    for (int e=0;e<8;++e) cv[u][e] = 0.f;
  #pragma unroll
  for (int hh=0;hh<4;++hh){
    const unsigned short* pp = P + ((size_t)((b*4+hh)*512 + i0 + i))*512 + jc*8;
    float si = sinv_s[hh][i];
    #pragma unroll
    for (int u=0;u<8;++u){
      u4v p = *(const u4v*)(pp + u*64);
      #pragma unroll
      for (int e=0;e<4;++e){
        cv[u][2*e]   += bf2f(p[e]&0xffffu)*si;
        cv[u][2*e+1] += bf2f(p[e]>>16)*si;
      }
    }
  }
  float z = 0.f;
  #pragma unroll
  for (int u=0;u<8;++u)
    #pragma unroll
    for (int e=0;e<8;++e){
      cv[u][e] *= w_s[jc*8 + u*64 + e];
      z += cv[u][e];
    }
  z += __shfl_xor(z,1,64); z += __shfl_xor(z,2,64); z += __shfl_xor(z,4,64);
  float zi = 1.f/z;
  #pragma unroll
  for (int u=0;u<8;++u){
    us8v pk;
    #pragma unroll
    for (int e=0;e<8;++e) pk[e] = f2bf(cv[u][e]*zi);
    *(us8v*)(cwn + ((size_t)(b*512 + i0 + i))*512 + jc*8 + u*64) = pk;
  }
}

// ---------- fused tail: out-proj + LN + ffn + softplus + add + LN (+ next LN) ----------
__global__ __launch_bounds__(256) void tail_kernel(
    const unsigned short* __restrict__ attb, const unsigned short* __restrict__ outT,
    const float* __restrict__ out_b,
    const unsigned short* __restrict__ ffnT, const float* __restrict__ ffn_b,
    float* __restrict__ x, unsigned short* __restrict__ xnb,
    const float* __restrict__ g1, const float* __restrict__ b1,
    const float* __restrict__ g2, const float* __restrict__ b2) {
  __shared__ char smem[81920];                            // 80 KB
  unsigned short* Al   = (unsigned short*)smem;           // [0,8K) gemm1 A
  unsigned short* Bl   = (unsigned short*)(smem+8192);    // [8K,24K) gemm1 B
  char* xnl  = smem;                                      // [0,16K) after gemm1
  char* ffnB = smem + 16384;                              // [16K,48K)
  float* vst = (float*)(smem + 49152);                    // [48K,80K) 64x128 f32
  const int bm = blockIdx.x*64;
  const int t = threadIdx.x, w = t>>6, l = t&63;
  const int wr = w>>1, wc = w&1;
  f4v acc[2][4];
  #pragma unroll
  for (int i=0;i<2;++i)
    #pragma unroll
    for (int j=0;j<4;++j) acc[i][j] = (f4v){0.f,0.f,0.f,0.f};
  const int srow = t>>3, sseg = t&7;
  for (int k0 = 0; k0 < 512; k0 += 64) {
    #pragma unroll
    for (int c=0;c<2;++c){
      int row = c*32 + srow;
      GLOAD16(attb + (size_t)(bm+row)*512 + k0 + ((sseg ^ (row&7))<<3),
              (char*)Al + c*4096 + w*1024);
    }
    #pragma unroll
    for (int c=0;c<4;++c){
      int row = c*32 + srow;
      GLOAD16(outT + (size_t)row*512 + k0 + ((sseg ^ (row&7))<<3),
              (char*)Bl + c*4096 + w*1024);
    }
    __syncthreads();
    #pragma unroll
    for (int ks=0;ks<2;++ks){
      s8v bf[4];
      #pragma unroll
      for (int ct=0;ct<4;++ct){
        int col = wc*64 + ct*16 + (l&15);
        bf[ct] = *(const s8v*)((const char*)Bl + col*128 + ((((l>>4)+ks*4) ^ (col&7))<<4));
      }
      #pragma unroll
      for (int rt=0;rt<2;++rt){
        int arow = wr*32 + rt*16 + (l&15);
        s8v af = *(const s8v*)((const char*)Al + arow*128 + ((((l>>4)+ks*4) ^ (arow&7))<<4));
        #pragma unroll
        for (int ct=0;ct<4;++ct)
          acc[rt][ct] = MFMA16(af, bf[ct], acc[rt][ct]);
      }
    }
    __syncthreads();
  }
  // stage ffn weights (async, lands before next barrier)
  #pragma unroll
  for (int kh=0;kh<2;++kh)
    #pragma unroll
    for (int c=0;c<4;++c){
      int row = c*32 + srow;
      GLOAD16(ffnT + (size_t)row*128 + kh*64 + ((sseg ^ (row&7))<<3),
              ffnB + kh*16384 + c*4096 + w*1024);
    }
  // epilogue1: o1 = acc + out_b + x  -> vst
  {
    float bia[4];
    #pragma unroll
    for (int ct=0;ct<4;++ct) bia[ct] = out_b[wc*64 + ct*16 + (l&15)];
    #pragma unroll
    for (int rt=0;rt<2;++rt)
      #pragma unroll
      for (int ct=0;ct<4;++ct)
        #pragma unroll
        for (int r=0;r<4;++r){
          int rr = wr*32 + rt*16 + (l>>4)*4 + r;
          int cc = wc*64 + ct*16 + (l&15);
          vst[rr*128 + cc] = acc[rt][ct][r] + bia[ct] + x[(size_t)(bm+rr)*128 + cc];
        }
  }
  __syncthreads();
  // LN1 -> xnl (swizzled bf16 A-layout)
  {
    const float2 g1v = *(const float2*)(g1 + l*2);
    const float2 b1v = *(const float2*)(b1 + l*2);
    for (int rr=0; rr<16; ++rr){
      int row = w*16 + rr;
      float2 vv = *(const float2*)&vst[row*128 + l*2];
      float s = vv.x+vv.y, sq = vv.x*vv.x + vv.y*vv.y;
      #pragma unroll
      for (int m=1;m<64;m<<=1){ s += __shfl_xor(s,m,64); sq += __shfl_xor(sq,m,64); }
      float mean = s*(1.f/128.f);
      float rstd = rsqrtf(sq*(1.f/128.f) - mean*mean + 1e-5f);
      float xa = (vv.x-mean)*rstd*g1v.x + b1v.x;
      float xb = (vv.y-mean)*rstd*g1v.y + b1v.y;
      int col = l*2;
      int byte = row*256 + (((col>>3) ^ (row&7))<<4) + ((col&7)<<1);
      unsigned int pk = (unsigned int)f2bf(xa) | ((unsigned int)f2bf(xb)<<16);
      *(unsigned int*)(xnl + byte) = pk;
    }
  }
  __syncthreads();
  // GEMM2: o2 = xn @ ffnT^T
  f4v acc2[2][4];
  #pragma unroll
  for (int i=0;i<2;++i)
    #pragma unroll
    for (int j=0;j<4;++j) acc2[i][j] = (f4v){0.f,0.f,0.f,0.f};
  #pragma unroll
  for (int ks2=0;ks2<4;++ks2){
    int kh = ks2>>1, ks = ks2&1;
    s8v bf[4];
    #pragma unroll
    for (int ct=0;ct<4;++ct){
      int col = wc*64 + ct*16 + (l&15);
      bf[ct] = *(const s8v*)(ffnB + kh*16384 + col*128 + ((((l>>4)+ks*4) ^ (col&7))<<4));
    }
    #pragma unroll
    for (int rt=0;rt<2;++rt){
      int arow = wr*32 + rt*16 + (l&15);
      s8v af = *(const s8v*)(xnl + arow*256 + ((((l>>4)+ks2*4) ^ (arow&7))<<4));
      #pragma unroll
      for (int ct=0;ct<4;++ct)
        acc2[rt][ct] = MFMA16(af, bf[ct], acc2[rt][ct]);
    }
  }
  // epilogue2: vst += softplus(acc2 + ffn_b)   (same-thread element mapping)
  {
    float fb[4];
    #pragma unroll
    for (int ct=0;ct<4;++ct) fb[ct] = ffn_b[wc*64 + ct*16 + (l&15)];
    #pragma unroll
    for (int rt=0;rt<2;++rt)
      #pragma unroll
      for (int ct=0;ct<4;++ct)
        #pragma unroll
        for (int r=0;r<4;++r){
          int rr = wr*32 + rt*16 + (l>>4)*4 + r;
          int cc = wc*64 + ct*16 + (l&15);
          vst[rr*128 + cc] += softplus_f(acc2[rt][ct][r] + fb[ct]);
        }
  }
  __syncthreads();
  // LN2 -> x ; optional LN3 -> xnb
  {
    const float2 g1v = *(const float2*)(g1 + l*2);
    const float2 b1v = *(const float2*)(b1 + l*2);
    for (int rr=0; rr<16; ++rr){
      int row = w*16 + rr;
      float2 vv = *(const float2*)&vst[row*128 + l*2];
      float s = vv.x+vv.y, sq = vv.x*vv.x + vv.y*vv.y;
      #pragma unroll
      for (int m=1;m<64;m<<=1){ s += __shfl_xor(s,m,64); sq += __shfl_xor(sq,m,64); }
      float mean = s*(1.f/128.f);
      float rstd = rsqrtf(sq*(1.f/128.f) - mean*mean + 1e-5f);
      float xa = (vv.x-mean)*rstd*g1v.x + b1v.x;
      float xb = (vv.y-mean)*rstd*g1v.y + b1v.y;
      float2 xo; xo.x = xa; xo.y = xb;
      *(float2*)(x + (size_t)(bm+row)*128 + l*2) = xo;
      if (g2) {
        float s2 = xa+xb, sq2 = xa*xa + xb*xb;
        #pragma unroll
        for (int m=1;m<64;m<<=1){ s2 += __shfl_xor(s2,m,64); sq2 += __shfl_xor(sq2,m,64); }
        float mean2 = s2*(1.f/128.f);
        float rstd2 = rsqrtf(sq2*(1.f/128.f) - mean2*mean2 + 1e-5f);
        const float2 g2v = *(const float2*)(g2 + l*2);
        const float2 b2v = *(const float2*)(b2 + l*2);
        float ya = (xa-mean2)*rstd2*g2v.x + b2v.x;
        float yb = (xb-mean2)*rstd2*g2v.y + b2v.y;
        unsigned int pk = (unsigned int)f2bf(ya) | ((unsigned int)f2bf(yb)<<16);
        *(unsigned int*)(xnb + (size_t)(bm+row)*128 + l*2) = pk;
      }
    }
  }
}

// ---------- pooling (parallel partials) + final ----------
__global__ __launch_bounds__(128) void pool_part_kernel(const float* __restrict__ x,
    const float* __restrict__ x_init,
    const float* __restrict__ w_row, float* __restrict__ partial) {
  int b = blockIdx.x, p = blockIdx.y, e = threadIdx.x;
  float acc = 0.f;
  for (int n = p*64; n < p*64+64; ++n) {
    float w = w_row[(size_t)b*N_ + n];
    size_t o = ((size_t)b*N_ + n)*E_ + e;
    acc += w * (x[o] + x_init[o]);
  }
  partial[((size_t)b*8 + p)*E_ + e] = acc;
}

__global__ __launch_bounds__(128) void final_kernel(const float* __restrict__ partial,
    const float* __restrict__ g, const float* __restrict__ bt,
    const float* __restrict__ fw, const float* __restrict__ fb, float* __restrict__ out) {
  int b = blockIdx.x, t = threadIdx.x;
  float v = 0.f;
  for (int p=0;p<8;++p) v += partial[((size_t)b*8+p)*E_ + t];
  float s = v, sq = v*v;
  #pragma unroll
  for (int m = 1; m < 64; m <<= 1) { s += __shfl_xor(s, m, 64); sq += __shfl_xor(sq, m, 64); }
  __shared__ float red[4];
  int wv = t >> 6, ln = t & 63;
  if (ln == 0) { red[wv*2] = s; red[wv*2+1] = sq; }
  __syncthreads();
  s = red[0] + red[2]; sq = red[1] + red[3];
  float mean = s*(1.f/E_), var = sq*(1.f/E_) - mean*mean;
  float rstd = rsqrtf(var + 1e-5f);
  float xl = (v - mean)*rstd*g[t] + bt[t];
  float p = xl * fw[t];
  #pragma unroll
  for (int m = 1; m < 64; m <<= 1) p += __shfl_xor(p, m, 64);
  __shared__ float red2[2];
  if (ln == 0) red2[wv] = p;
  __syncthreads();
  if (t == 0) out[b] = red2[0] + red2[1] + fb[0];
}

extern "C" void kernel_launch(void* const* d_in, const int* in_sizes, int n_in,
                              void* d_out, int out_size, void* d_ws, size_t ws_size,
                              hipStream_t stream) {
  (void)in_sizes; (void)n_in; (void)out_size; (void)ws_size;
  const float* str_fea  = (const float*)d_in[0];
  const int*   comp_fea = (const int*)  d_in[1];
  const float* af_table = (const float*)d_in[3];
  const float* comp_w   = (const float*)d_in[4];
  const float* comp_b   = (const float*)d_in[5];
  const float* emb_w    = (const float*)d_in[6];
  const float* emb_b    = (const float*)d_in[7];
  const float* ln_g     = (const float*)d_in[8];
  const float* ln_b     = (const float*)d_in[9];
  const float* wq       = (const float*)d_in[10];
  const float* bq       = (const float*)d_in[11];
  const float* wk       = (const float*)d_in[12];
  const float* bk       = (const float*)d_in[13];
  const float* wv       = (const float*)d_in[14];
  const float* bv       = (const float*)d_in[15];
  const float* inproj_w = (const float*)d_in[16];
  const float* inproj_b = (const float*)d_in[17];
  const float* out_w    = (const float*)d_in[18];
  const float* out_b    = (const float*)d_in[19];
  const float* ffn_w    = (const float*)d_in[20];
  const float* ffn_b    = (const float*)d_in[21];
  const float* ln2_g    = (const float*)d_in[22];
  const float* ln2_b    = (const float*)d_in[23];
  const float* final_w  = (const float*)d_in[24];
  const float* final_b  = (const float*)d_in[25];
  float* out = (float*)d_out;

  float* ws = (float*)d_ws;
  size_t off = 0;
  float* x      = ws + off; off += 2097152;
  float* x_init = ws + off; off += 2097152;
  float* w_row  = ws + off; off += 16384;
  unsigned short* xnb  = (unsigned short*)(ws + off); off += 1048576;   // [M][128]
  unsigned short* qkb  = (unsigned short*)(ws + off); off += 8388608;   // [M][1024]
  unsigned short* vTb  = (unsigned short*)(ws + off); off += 4194304;   // [B][512][512]
  unsigned short* attb = (unsigned short*)(ws + off); off += 4194304;   // [M][512]
  unsigned short* Pb   = (unsigned short*)(ws + off); off += 16777216;  // [B][H][512][512]
  float* Sinvb  = ws + off; off += 65536;
  float* bq_eff = ws + off; off += 1536;
  float* bk_eff = ws + off; off += 1536;
  float* bqkv   = ws + off; off += 4608;
  unsigned short* wqkvT = (unsigned short*)(ws + off); off += 294912;   // [3][1536][128]
  unsigned short* outT  = (unsigned short*)(ws + off); off += 98304;    // [3][128][512]
  unsigned short* ffnT  = (unsigned short*)(ws + off); off += 24576;    // [3][128][128]
  unsigned short* FHi   = (unsigned short*)(ws + off); off += 2621440;  // [M][320]
  unsigned short* FLo   = (unsigned short*)(ws + off); off += 2621440;
  unsigned short* WHi   = (unsigned short*)(ws + off); off += 20480;    // [128][320]
  unsigned short* WLo   = (unsigned short*)(ws + off); off += 20480;
  float* biasE  = ws + off; off += 128;
  float* Cpart  = ws + off; off += 1280;
  float* partial= ws + off; off += 32768;
  // cwn aliases the first 16.8 MB of qkb: written by attnC strictly after attnA's
  // last read of qkb, consumed by attnPV, clobbered by next layer's qkv GEMM.
  unsigned short* cwn = qkb;

  eff_gemm_kernel<<<48, 256, 0, stream>>>(wq, wk, inproj_w, wqkvT);
  eff_b_kernel<<<12, 256, 0, stream>>>(bq, bk, inproj_w, inproj_b, bq_eff, bk_eff);
  wconv2_kernel<<<768, 256, 0, stream>>>(wv, out_w, ffn_w, bq_eff, bk_eff, bv,
                                         wqkvT, outT, ffnT, bqkv);
  embW1_kernel<<<12, 128, 0, stream>>>(emb_w, comp_w, WHi, WLo, Cpart);
  embBias_kernel<<<1, 128, 0, stream>>>(Cpart, comp_b, emb_b, biasE);
  feat_kernel<<<M_*40/256, 256, 0, stream>>>(str_fea, comp_fea, af_table, FHi, FLo, w_row);
  embgemm_kernel<<<M_/64, 256, 0, stream>>>(FHi, FLo, WHi, WLo, biasE,
                                            ln_g, ln_b, x, x_init, xnb);

  for (int l = 0; l < L_; ++l) {
    mgemm_kernel<4,0><<<dim3(M_/128, 12), 256, 0, stream>>>(
        xnb, wqkvT + (size_t)l*196608, bqkv + l*1536, qkb, vTb, 128);
    attnA_kernel<<<dim3(8, 4, 32), 256, 0, stream>>>(qkb, w_row, Pb, Sinvb);
    attnC_kernel<<<dim3(16, 32), 256, 0, stream>>>(Pb, Sinvb, w_row, cwn);
    mgemm_kernel<4,3><<<dim3(4, 4, 32), 256, 0, stream>>>(
        cwn, vTb, nullptr, attb, nullptr, 512);
    tail_kernel<<<M_/64, 256, 0, stream>>>(
        attb, outT + (size_t)l*65536, out_b + (size_t)l*E_,
        ffnT + (size_t)l*16384, ffn_b + (size_t)l*E_,
        x, xnb, ln_g + l*E_, ln_b + l*E_,
        (l < 2) ? (ln_g + (l+1)*E_) : nullptr,
        (l < 2) ? (ln_b + (l+1)*E_) : nullptr);
  }

  pool_part_kernel<<<dim3(B_, 8), 128, 0, stream>>>(x, x_init, w_row, partial);
  final_kernel<<<B_, 128, 0, stream>>>(partial, ln2_g, ln2_b, final_w, final_b, out);
}

// Round 5
// 473.959 us; speedup vs baseline: 7.3679x; 1.0732x over previous
//
#include <hip/hip_runtime.h>
#include <math.h>

#define B_ 32
#define N_ 512
#define F_ 101
#define E_ 128
#define H_ 4
#define EH_ 512
#define L_ 3
#define M_ (B_*N_)   // 16384

typedef __attribute__((ext_vector_type(8))) short s8v;
typedef __attribute__((ext_vector_type(8))) unsigned short us8v;
typedef __attribute__((ext_vector_type(4))) float f4v;
typedef __attribute__((ext_vector_type(4))) unsigned int u4v;

__device__ __forceinline__ unsigned short f2bf(float f){
  unsigned int u = __builtin_bit_cast(unsigned int, f);
  u += 0x7fffu + ((u>>16)&1u);
  return (unsigned short)(u>>16);
}
__device__ __forceinline__ float bf2f(unsigned int h){
  unsigned int u = h<<16; return __builtin_bit_cast(float, u);
}
__device__ __forceinline__ float softplus_f(float v) {
  return fmaxf(v, 0.f) + log1pf(__expf(-fabsf(v)));
}

#define GLOAD16(gp, lp) __builtin_amdgcn_global_load_lds( \
    (__attribute__((address_space(1))) unsigned int*)(gp), \
    (__attribute__((address_space(3))) unsigned int*)(lp), 16, 0, 0)

#define MFMA16(a,b,c) __builtin_amdgcn_mfma_f32_16x16x32_bf16(a,b,c,0,0,0)

// ---------- eff fold GEMM: wqkvT[l][qk*512+n][r] = bf16( sum_kk wqk[l][r][kk] * ip[kk][n] ) ----------
__global__ __launch_bounds__(256) void eff_gemm_kernel(
    const float* __restrict__ wq, const float* __restrict__ wk,
    const float* __restrict__ inproj_w, unsigned short* __restrict__ wqkvT) {
  __shared__ float As[64][132];   // [kk][r]
  __shared__ float Bs[64][68];    // [kk][c]
  const int blk = blockIdx.x;     // 48 = 6 lq * 8 ntiles
  const int lq = blk>>3, nt = blk&7;
  const int l = lq>>1, qk = lq&1;
  const int bn = nt*64;
  const float* A = (qk ? wk : wq) + (size_t)l*128*512;
  const float* IP = inproj_w + (size_t)l*512*1536 + qk*512 + bn;
  const int t = threadIdx.x;
  float acc[8][4];
  #pragma unroll
  for (int i=0;i<8;++i)
    #pragma unroll
    for (int j=0;j<4;++j) acc[i][j]=0.f;
  const int r0 = (t&15)*8, c0 = (t>>4)*4;
  for (int k0=0;k0<512;k0+=64){
    int r = t & 127, half = t>>7;
    #pragma unroll
    for (int u=0;u<8;++u){
      float4 a = *(const float4*)(A + (size_t)r*512 + k0 + half*32 + u*4);
      int kk = half*32 + u*4;
      As[kk+0][r]=a.x; As[kk+1][r]=a.y; As[kk+2][r]=a.z; As[kk+3][r]=a.w;
    }
    int kk = t>>2, cb = (t&3)*16;
    #pragma unroll
    for (int u=0;u<4;++u)
      *(float4*)&Bs[kk][cb+u*4] = *(const float4*)(IP + (size_t)(k0+kk)*1536 + cb + u*4);
    __syncthreads();
    for (int k2=0;k2<64;++k2){
      float4 b = *(const float4*)&Bs[k2][c0];
      float4 a0 = *(const float4*)&As[k2][r0];
      float4 a1 = *(const float4*)&As[k2][r0+4];
      float av[8] = {a0.x,a0.y,a0.z,a0.w,a1.x,a1.y,a1.z,a1.w};
      #pragma unroll
      for (int i=0;i<8;++i){
        acc[i][0] += av[i]*b.x; acc[i][1] += av[i]*b.y;
        acc[i][2] += av[i]*b.z; acc[i][3] += av[i]*b.w;
      }
    }
    __syncthreads();
  }
  #pragma unroll
  for (int j=0;j<4;++j){
    us8v pk;
    #pragma unroll
    for (int i=0;i<8;++i) pk[i] = f2bf(acc[i][j]);
    *(us8v*)(wqkvT + ((size_t)l*1536 + qk*512 + bn + c0 + j)*128 + r0) = pk;
  }
}

// ---------- eff bias partials: part[lq][kt][512] ----------
__global__ __launch_bounds__(256) void effb_part_kernel(
    const float* __restrict__ bq, const float* __restrict__ bk,
    const float* __restrict__ inproj_w, float* __restrict__ part) {
  const int lq = blockIdx.x, kt = blockIdx.y;   // 6 x 8
  const int l = lq>>1, qk = lq&1;
  const float* bv = (qk?bk:bq) + l*512 + kt*64;
  const float* IP = inproj_w + ((size_t)l*512 + kt*64)*1536 + qk*512;
  const int t = threadIdx.x;
  float a0=0.f, a1=0.f;
  for (int kk=0; kk<64; ++kk){
    float b = bv[kk];
    const float* row = IP + (size_t)kk*1536;
    a0 += b*row[t];
    a1 += b*row[t+256];
  }
  part[(lq*8+kt)*512 + t]       = a0;
  part[(lq*8+kt)*512 + t + 256] = a1;
}

// ---------- weight transposes (LDS-tiled) + bqkv assembly ----------
__global__ __launch_bounds__(256) void wtrans_kernel(
    const float* __restrict__ wv, const float* __restrict__ out_w,
    const float* __restrict__ ffn_w,
    const float* __restrict__ inproj_b, const float* __restrict__ bvv,
    const float* __restrict__ part,
    unsigned short* __restrict__ wqkvT, unsigned short* __restrict__ outT,
    unsigned short* __restrict__ ffnT, float* __restrict__ bqkv) {
  const int blk = blockIdx.x;   // 0..125
  const int t = threadIdx.x;
  if (blk < 108) {
    __shared__ float tile[64][65];
    const float* src; unsigned short* dst; int srcld, dstld;
    if (blk < 48) {              // wv [3][128][512] -> wqkvT v-part [n][k]
      int lay = blk/16, rem = blk%16, kt = rem>>3, nt = rem&7;
      src = wv + ((size_t)lay*128 + kt*64)*512 + nt*64; srcld = 512;
      dst = wqkvT + ((size_t)lay*1536 + 1024 + nt*64)*128 + kt*64; dstld = 128;
    } else if (blk < 96) {       // out_w [3][512][128] -> outT [n][k]
      int b2 = blk-48; int lay = b2/16, rem = b2%16, kt = rem>>1, nt = rem&1;
      src = out_w + ((size_t)lay*512 + kt*64)*128 + nt*64; srcld = 128;
      dst = outT + ((size_t)lay*128 + nt*64)*512 + kt*64; dstld = 512;
    } else {                     // ffn_w [3][128][128] -> ffnT [n][k]
      int b3 = blk-96; int lay = b3/4, rem = b3%4, kt = rem>>1, nt = rem&1;
      src = ffn_w + ((size_t)lay*128 + kt*64)*128 + nt*64; srcld = 128;
      dst = ffnT + ((size_t)lay*128 + nt*64)*128 + kt*64; dstld = 128;
    }
    #pragma unroll
    for (int rp=0; rp<4; ++rp){
      int r = rp*16 + (t>>4), c = (t&15)*4;
      float4 v = *(const float4*)(src + (size_t)r*srcld + c);
      tile[r][c+0]=v.x; tile[r][c+1]=v.y; tile[r][c+2]=v.z; tile[r][c+3]=v.w;
    }
    __syncthreads();
    #pragma unroll
    for (int wp=0; wp<2; ++wp){
      int n = wp*32 + (t>>3), kk = (t&7)*8;
      us8v pk;
      #pragma unroll
      for (int e=0;e<8;++e) pk[e] = f2bf(tile[kk+e][n]);
      *(us8v*)(dst + (size_t)n*dstld + kk) = pk;
    }
  } else {
    int idx = (blk-108)*256 + t;          // 0..4607
    int l = idx/1536, n = idx - l*1536;
    float v;
    if (n < 1024) {
      int qk = n>>9, c = n&511;
      v = inproj_b[(size_t)l*1536 + n];
      #pragma unroll
      for (int kt=0;kt<8;++kt) v += part[((l*2+qk)*8+kt)*512 + c];
    } else {
      v = bvv[(size_t)l*512 + (n-1024)];
    }
    bqkv[idx] = v;
  }
}

// ---------- embed weight prep: quadratic expansion A/B/C + split bf16 ----------
__global__ __launch_bounds__(128) void embW1_kernel(
    const float* __restrict__ emb_w, const float* __restrict__ comp_w,
    unsigned short* __restrict__ WHi, unsigned short* __restrict__ WLo,
    float* __restrict__ Cpart) {
  int p = blockIdx.x, e = threadIdx.x;
  if (p < 10) {
    float Cp = 0.f;
    for (int ff=0; ff<10; ++ff){
      int f = p*10+ff;
      float A=0.f, Bv=0.f;
      #pragma unroll
      for (int s=0;s<10;++s){
        float wv = emb_w[(size_t)(f*10+s)*128 + e];
        A += wv; Bv += 0.2f*s*wv; Cp += 0.01f*(s*s)*wv;
      }
      int kA = 92+f, kB = 192+f;
      unsigned short hA = f2bf(A);
      WHi[e*320+kA]=hA; WLo[e*320+kA]=f2bf(A - bf2f(hA));
      unsigned short hB = f2bf(Bv);
      WHi[e*320+kB]=hB; WLo[e*320+kB]=f2bf(Bv - bf2f(hB));
    }
    Cpart[p*128+e] = Cp;
  } else if (p == 10) {
    for (int kk=0;kk<92;++kk){
      float v = comp_w[(size_t)kk*128 + e];
      unsigned short h = f2bf(v);
      WHi[e*320+kk]=h; WLo[e*320+kk]=f2bf(v - bf2f(h));
    }
  } else {
    for (int kk=292;kk<320;++kk){ WHi[e*320+kk]=0; WLo[e*320+kk]=0; }
  }
}

__global__ __launch_bounds__(128) void embBias_kernel(
    const float* __restrict__ Cpart, const float* __restrict__ comp_b,
    const float* __restrict__ emb_b, float* __restrict__ biasE){
  int e = threadIdx.x; float c=0.f;
  for (int p=0;p<10;++p) c += Cpart[p*128+e];
  biasE[e] = comp_b[e] + emb_b[e] + c;
}

// ---------- feature builder (coalesced) ----------
__global__ __launch_bounds__(256) void feat_kernel(
    const float* __restrict__ str_fea, const int* __restrict__ comp_fea,
    const float* __restrict__ af_table,
    unsigned short* __restrict__ FHi, unsigned short* __restrict__ FLo,
    float* __restrict__ w_row) {
  int g = blockIdx.x*256 + threadIdx.x;      // M*40 = 655360
  int row = g / 40, seg = g - row*40;
  const float* sr = str_fea + (size_t)row*F_;
  if (seg == 0) w_row[row] = sr[0];
  const float* af = af_table + (size_t)comp_fea[row]*92;
  const int c0 = seg*8;
  us8v hi, lo;
  #pragma unroll
  for (int e=0;e<8;++e){
    int kk = c0+e; float v;
    if (kk < 92) v = af[kk];
    else if (kk < 192) { float u = 1.f - sr[1+kk-92]; v = u*u; }
    else if (kk < 292) v = 1.f - sr[1+kk-192];
    else v = 0.f;
    unsigned short h = f2bf(v);
    hi[e] = h; lo[e] = f2bf(v - bf2f(h));
  }
  *(us8v*)(FHi + (size_t)row*320 + c0) = hi;
  *(us8v*)(FLo + (size_t)row*320 + c0) = lo;
}

// ---------- embed GEMM (split bf16, 3-MFMA) + LN0 epilogue ----------
__global__ __launch_bounds__(256) void embgemm_kernel(
    const unsigned short* __restrict__ FHi, const unsigned short* __restrict__ FLo,
    const unsigned short* __restrict__ WHi, const unsigned short* __restrict__ WLo,
    const float* __restrict__ biasE,
    const float* __restrict__ g0, const float* __restrict__ b0,
    float* __restrict__ x, float* __restrict__ x_init,
    unsigned short* __restrict__ xnb) {
  __shared__ unsigned short lds[24576];    // 48 KB
  unsigned short* AHi = lds;
  unsigned short* ALo = lds + 4096;
  unsigned short* BHi = lds + 8192;
  unsigned short* BLo = lds + 16384;
  const int bm = blockIdx.x*64;
  const int t = threadIdx.x, w = t>>6, l = t&63;
  f4v acc[8];
  #pragma unroll
  for (int i=0;i<8;++i) acc[i] = (f4v){0.f,0.f,0.f,0.f};
  const int srow = t>>3, sseg = t&7;
  for (int k0=0;k0<320;k0+=64){
    #pragma unroll
    for (int c=0;c<2;++c){
      int row = c*32+srow;
      GLOAD16(FHi + (size_t)(bm+row)*320 + k0 + ((sseg^(row&7))<<3), (char*)AHi + c*4096 + w*1024);
      GLOAD16(FLo + (size_t)(bm+row)*320 + k0 + ((sseg^(row&7))<<3), (char*)ALo + c*4096 + w*1024);
    }
    #pragma unroll
    for (int c=0;c<4;++c){
      int row = c*32+srow;
      GLOAD16(WHi + (size_t)row*320 + k0 + ((sseg^(row&7))<<3), (char*)BHi + c*4096 + w*1024);
      GLOAD16(WLo + (size_t)row*320 + k0 + ((sseg^(row&7))<<3), (char*)BLo + c*4096 + w*1024);
    }
    __syncthreads();
    #pragma unroll
    for (int ks=0;ks<2;++ks){
      int arow = w*16 + (l&15);
      int aswz = ((((l>>4)+ks*4) ^ (arow&7))<<4);
      s8v ah = *(const s8v*)((const char*)AHi + arow*128 + aswz);
      s8v al = *(const s8v*)((const char*)ALo + arow*128 + aswz);
      #pragma unroll
      for (int ct=0;ct<8;++ct){
        int col = ct*16 + (l&15);
        int bswz = ((((l>>4)+ks*4) ^ (col&7))<<4);
        s8v bh = *(const s8v*)((const char*)BHi + col*128 + bswz);
        s8v bl = *(const s8v*)((const char*)BLo + col*128 + bswz);
        acc[ct] = MFMA16(ah, bh, acc[ct]);
        acc[ct] = MFMA16(ah, bl, acc[ct]);
        acc[ct] = MFMA16(al, bh, acc[ct]);
      }
    }
    __syncthreads();
  }
  float vv[8][4], gc[8], bc[8];
  #pragma unroll
  for (int ct=0;ct<8;++ct){
    int c = ct*16 + (l&15);
    float be = biasE[c]; gc[ct] = g0[c]; bc[ct] = b0[c];
    #pragma unroll
    for (int r=0;r<4;++r) vv[ct][r] = acc[ct][r] + be;
  }
  #pragma unroll
  for (int r=0;r<4;++r){
    float s=0.f, sq=0.f;
    #pragma unroll
    for (int ct=0;ct<8;++ct){ s += vv[ct][r]; sq += vv[ct][r]*vv[ct][r]; }
    #pragma unroll
    for (int m=1;m<16;m<<=1){ s += __shfl_xor(s,m,64); sq += __shfl_xor(sq,m,64); }
    float mean = s*(1.f/128.f);
    float rstd = rsqrtf(sq*(1.f/128.f) - mean*mean + 1e-5f);
    int row = bm + w*16 + (l>>4)*4 + r;
    #pragma unroll
    for (int ct=0;ct<8;++ct){
      int c = ct*16 + (l&15);
      float v = vv[ct][r];
      x[(size_t)row*128 + c] = v;
      x_init[(size_t)row*128 + c] = v;
      xnb[(size_t)row*128 + c] = f2bf((v-mean)*rstd*gc[ct] + bc[ct]);
    }
  }
}

// ---------- bf16 MFMA GEMM (qkv): bf16 out -> qkb (n<1024) or transposed vT ----------
template<int RT>
__global__ __launch_bounds__(256) void mgemm_kernel(
    const unsigned short* __restrict__ A,
    const unsigned short* __restrict__ Bt,
    const float* __restrict__ bias,
    unsigned short* __restrict__ Cb,
    unsigned short* __restrict__ vT,
    int K) {
  constexpr int BM = RT*32;
  __shared__ float smem[8192];   // 32 KB
  unsigned short* Al = (unsigned short*)smem;
  unsigned short* Bl = Al + BM*64;
  const int bm = blockIdx.x*BM;
  const int bn = blockIdx.y*128;
  const int t = threadIdx.x;
  const int w = t>>6, l = t&63;
  const int wr = w>>1, wc = w&1;
  f4v acc[RT][4];
  #pragma unroll
  for (int i=0;i<RT;++i)
    #pragma unroll
    for (int j=0;j<4;++j) acc[i][j] = (f4v){0.f,0.f,0.f,0.f};
  const int srow = t>>3, sseg = t&7;
  for (int k0 = 0; k0 < K; k0 += 64) {
    #pragma unroll
    for (int c=0;c<BM/32;++c){
      int row = c*32 + srow;
      GLOAD16(A + (size_t)(bm+row)*K + k0 + ((sseg ^ (row&7))<<3),
              (char*)Al + c*4096 + w*1024);
    }
    #pragma unroll
    for (int c=0;c<4;++c){
      int row = c*32 + srow;
      GLOAD16(Bt + (size_t)(bn+row)*K + k0 + ((sseg ^ (row&7))<<3),
              (char*)Bl + c*4096 + w*1024);
    }
    __syncthreads();
    #pragma unroll
    for (int ks=0;ks<2;++ks){
      s8v bf[4];
      #pragma unroll
      for (int ct=0;ct<4;++ct){
        int col = wc*64 + ct*16 + (l&15);
        bf[ct] = *(const s8v*)((const char*)Bl + col*128 + ((((l>>4)+ks*4) ^ (col&7))<<4));
      }
      #pragma unroll
      for (int rt=0;rt<RT;++rt){
        int arow = wr*(RT*16) + rt*16 + (l&15);
        s8v af = *(const s8v*)((const char*)Al + arow*128 + ((((l>>4)+ks*4) ^ (arow&7))<<4));
        #pragma unroll
        for (int ct=0;ct<4;++ct)
          acc[rt][ct] = MFMA16(af, bf[ct], acc[rt][ct]);
      }
    }
    __syncthreads();
  }
  float bia[4];
  #pragma unroll
  for (int ct=0;ct<4;++ct) bia[ct] = bias[bn + wc*64 + ct*16 + (l&15)];
  unsigned short* lds16 = (unsigned short*)smem;
  if (bn < 1024) {
    #pragma unroll
    for (int rt=0;rt<RT;++rt)
      #pragma unroll
      for (int ct=0;ct<4;++ct)
        #pragma unroll
        for (int r=0;r<4;++r){
          int rr = wr*(RT*16) + rt*16 + (l>>4)*4 + r;
          int cc = wc*64 + ct*16 + (l&15);
          lds16[rr*128 + cc] = f2bf(acc[rt][ct][r] + bia[ct]);
        }
    __syncthreads();
    #pragma unroll
    for (int it=0; it<BM/16; ++it){
      int row = it*16 + (t>>4), seg = t&15;
      u4v v = *(const u4v*)(lds16 + row*128 + seg*8);
      *(u4v*)(Cb + (size_t)(bm+row)*1024 + bn + seg*8) = v;
    }
  } else {
    #pragma unroll
    for (int rt=0;rt<RT;++rt)
      #pragma unroll
      for (int ct=0;ct<4;++ct){
        int rbase = bm + wr*(RT*16) + rt*16 + (l>>4)*4;
        int bb = rbase >> 9, nn = rbase & 511;
        int d = bn - 1024 + wc*64 + ct*16 + (l&15);
        unsigned int lo = (unsigned int)f2bf(acc[rt][ct][0] + bia[ct])
                        | ((unsigned int)f2bf(acc[rt][ct][1] + bia[ct])<<16);
        unsigned int hi = (unsigned int)f2bf(acc[rt][ct][2] + bia[ct])
                        | ((unsigned int)f2bf(acc[rt][ct][3] + bia[ct])<<16);
        uint2 pk; pk.x = lo; pk.y = hi;
        *(uint2*)(vT + ((size_t)(bb*512 + d))*512 + nn) = pk;
      }
  }
}

// ---------- attention stage A: P = exp(QK^T*sc), Sinv, rho ----------
__global__ __launch_bounds__(256) void attnA_kernel(
    const unsigned short* __restrict__ qkb, const float* __restrict__ w_row,
    unsigned short* __restrict__ P, float* __restrict__ Sinv,
    float* __restrict__ rho) {
  __shared__ unsigned short Qlds[64*128];
  __shared__ unsigned short Klds[64*128];
  __shared__ unsigned short Ptile[64*64];
  __shared__ float w_s[512];
  const int i0 = blockIdx.x*64;
  const int h = blockIdx.y, b = blockIdx.z;
  const int t = threadIdx.x, w = t>>6, l = t&63;
  const float SC = 0.088388347648318447f;   // 1/sqrt(128)
  for (int j=t;j<512;j+=256) w_s[j] = w_row[b*512+j];
  {
    int row = t>>4, seg = t&15;
    #pragma unroll
    for (int c=0;c<4;++c)
      GLOAD16(qkb + (size_t)(b*512 + i0 + c*16 + row)*1024 + h*128 + ((seg ^ (row&7))<<3),
              (char*)Qlds + c*4096 + w*1024);
  }
  __syncthreads();
  s8v qf[4];
  #pragma unroll
  for (int ks=0;ks<4;++ks){
    int arow = w*16 + (l&15);
    qf[ks] = *(const s8v*)((const char*)Qlds + arow*256 + ((((l>>4)+ks*4) ^ (arow&7))<<4));
  }
  float sp[4] = {0.f,0.f,0.f,0.f};
  float swp[4] = {0.f,0.f,0.f,0.f};
  for (int j0=0;j0<512;j0+=64){
    {
      int row = t>>4, seg = t&15;
      #pragma unroll
      for (int c=0;c<4;++c)
        GLOAD16(qkb + (size_t)(b*512 + j0 + c*16 + row)*1024 + 512 + h*128 + ((seg ^ (row&7))<<3),
                (char*)Klds + c*4096 + w*1024);
    }
    __syncthreads();
    #pragma unroll
    for (int jt=0;jt<4;++jt){
      f4v a = (f4v){0.f,0.f,0.f,0.f};
      #pragma unroll
      for (int ks=0;ks<4;++ks){
        int col = jt*16 + (l&15);
        s8v kf = *(const s8v*)((const char*)Klds + col*256 + ((((l>>4)+ks*4) ^ (col&7))<<4));
        a = MFMA16(qf[ks], kf, a);
      }
      int jl = jt*16 + (l&15);
      float wv = w_s[j0+jl];
      float mw = (wv != 0.f) ? 1.f : 0.f;
      #pragma unroll
      for (int r=0;r<4;++r){
        float e = __expf(a[r]*SC);
        sp[r]  += e*mw;
        swp[r] += e*wv;
        Ptile[(w*16 + (l>>4)*4 + r)*64 + jl] = f2bf(e);
      }
    }
    __syncthreads();
    #pragma unroll
    for (int it=0;it<2;++it){
      int row = it*32 + (t>>3), seg = t&7;
      u4v pv = *(const u4v*)(Ptile + row*64 + seg*8);
      *(u4v*)(P + ((size_t)((b*4+h)*512 + i0 + row))*512 + j0 + seg*8) = pv;
    }
  }
  #pragma unroll
  for (int r=0;r<4;++r){
    float s = sp[r], sw = swp[r];
    #pragma unroll
    for (int m=1;m<16;m<<=1){ s += __shfl_xor(s,m,64); sw += __shfl_xor(sw,m,64); }
    sp[r] = s; swp[r] = sw;
  }
  if ((l&15)==0){
    #pragma unroll
    for (int r=0;r<4;++r){
      size_t idx = (size_t)(b*4+h)*512 + i0 + w*16 + (l>>4)*4 + r;
      float si = 1.f/sp[r];
      Sinv[idx] = si;
      rho[idx]  = swp[r]*si;
    }
  }
}

// ---------- fused combine + PV: att = (w * sum_h P*Sinv) @ V / Z ----------
__global__ __launch_bounds__(256) void attnPV_kernel(
    const unsigned short* __restrict__ P, const float* __restrict__ Sinv,
    const float* __restrict__ rho, const unsigned short* __restrict__ vT,
    const float* __restrict__ w_row, unsigned short* __restrict__ att) {
  __shared__ unsigned short cL[32*520];   // [i][512] bf16, row stride 520 (pad kills stride-128B conflicts)
  __shared__ unsigned short Vl[8192];     // 16 KB V tile; reused as epilogue staging
  __shared__ float w_s[512];
  __shared__ float sinv_s[4][32];
  __shared__ float zinv_s[32];
  const int bm = blockIdx.x*32, b = blockIdx.y;
  const int t = threadIdx.x, w = t>>6, l = t&63;
  const int wd = w>>1, wi = w&1;
  for (int j=t;j<512;j+=256) w_s[j] = w_row[b*512+j];
  if (t < 128) sinv_s[t>>5][t&31] = Sinv[(size_t)(b*4+(t>>5))*512 + bm + (t&31)];
  if (t >= 128 && t < 160){
    int i = t-128; float z=0.f;
    #pragma unroll
    for (int hh=0;hh<4;++hh) z += rho[(size_t)(b*4+hh)*512 + bm + i];
    zinv_s[i] = 1.f/z;
  }
  __syncthreads();
  // combine phase: build c-tile for all 512 j
  {
    const int i = t&31, jseg = t>>5;
    float cv[64];
    #pragma unroll
    for (int e=0;e<64;++e) cv[e]=0.f;
    #pragma unroll
    for (int hh=0;hh<4;++hh){
      const unsigned short* pp = P + ((size_t)((b*4+hh)*512 + bm + i))*512 + jseg*64;
      float si = sinv_s[hh][i];
      #pragma unroll
      for (int u=0;u<8;++u){
        u4v p = *(const u4v*)(pp + u*8);
        #pragma unroll
        for (int e=0;e<4;++e){
          cv[u*8+2*e]   += bf2f(p[e]&0xffffu)*si;
          cv[u*8+2*e+1] += bf2f(p[e]>>16)*si;
        }
      }
    }
    #pragma unroll
    for (int u=0;u<8;++u){
      us8v pk;
      #pragma unroll
      for (int e=0;e<8;++e)
        pk[e] = f2bf(cv[u*8+e] * w_s[jseg*64 + u*8 + e]);
      *(us8v*)((char*)cL + i*1040 + jseg*128 + u*16) = pk;
    }
  }
  __syncthreads();
  const int srow = t>>3, sseg = t&7;
  #pragma unroll 1
  for (int nt=0; nt<4; ++nt){
    const int bn = nt*128;
    f4v acc[4];
    #pragma unroll
    for (int j=0;j<4;++j) acc[j] = (f4v){0.f,0.f,0.f,0.f};
    for (int k0=0;k0<512;k0+=64){
      #pragma unroll
      for (int c=0;c<4;++c){
        int row = c*32 + srow;
        GLOAD16(vT + ((size_t)(b*512 + bn + row))*512 + k0 + ((sseg^(row&7))<<3),
                (char*)Vl + c*4096 + w*1024);
      }
      __syncthreads();
      #pragma unroll
      for (int ks=0;ks<2;++ks){
        int kidx = (l>>4) + ks*4;
        int arow = wi*16 + (l&15);
        s8v af = *(const s8v*)((const char*)cL + arow*1040 + k0*2 + kidx*16);
        #pragma unroll
        for (int ct=0;ct<4;++ct){
          int col = wd*64 + ct*16 + (l&15);
          s8v bf = *(const s8v*)((const char*)Vl + col*128 + ((kidx ^ (col&7))<<4));
          acc[ct] = MFMA16(af, bf, acc[ct]);
        }
      }
      __syncthreads();
    }
    // epilogue: scale by 1/Z, repack, coalesced store
    #pragma unroll
    for (int ct=0;ct<4;++ct)
      #pragma unroll
      for (int r=0;r<4;++r){
        int rr = wi*16 + (l>>4)*4 + r;
        int cc = wd*64 + ct*16 + (l&15);
        Vl[rr*128 + cc] = f2bf(acc[ct][r]*zinv_s[rr]);
      }
    __syncthreads();
    #pragma unroll
    for (int it=0; it<2; ++it){
      int row = it*16 + (t>>4), seg = t&15;
      u4v v = *(const u4v*)(Vl + row*128 + seg*8);
      *(u4v*)(att + ((size_t)(b*512 + bm + row))*512 + bn + seg*8) = v;
    }
    __syncthreads();
  }
}

// ---------- fused tail: out-proj + LN + ffn + softplus + add + LN (+ next LN) ----------
__global__ __launch_bounds__(256) void tail_kernel(
    const unsigned short* __restrict__ attb, const unsigned short* __restrict__ outT,
    const float* __restrict__ out_b,
    const unsigned short* __restrict__ ffnT, const float* __restrict__ ffn_b,
    float* __restrict__ x, unsigned short* __restrict__ xnb,
    const float* __restrict__ g1, const float* __restrict__ b1,
    const float* __restrict__ g2, const float* __restrict__ b2) {
  __shared__ char smem[81920];                            // 80 KB
  unsigned short* Al   = (unsigned short*)smem;           // [0,8K) gemm1 A
  unsigned short* Bl   = (unsigned short*)(smem+8192);    // [8K,24K) gemm1 B
  char* xnl  = smem;                                      // [0,16K) after gemm1
  char* ffnB = smem + 16384;                              // [16K,48K)
  float* vst = (float*)(smem + 49152);                    // [48K,80K) 64x128 f32
  const int bm = blockIdx.x*64;
  const int t = threadIdx.x, w = t>>6, l = t&63;
  const int wr = w>>1, wc = w&1;
  f4v acc[2][4];
  #pragma unroll
  for (int i=0;i<2;++i)
    #pragma unroll
    for (int j=0;j<4;++j) acc[i][j] = (f4v){0.f,0.f,0.f,0.f};
  const int srow = t>>3, sseg = t&7;
  for (int k0 = 0; k0 < 512; k0 += 64) {
    #pragma unroll
    for (int c=0;c<2;++c){
      int row = c*32 + srow;
      GLOAD16(attb + (size_t)(bm+row)*512 + k0 + ((sseg ^ (row&7))<<3),
              (char*)Al + c*4096 + w*1024);
    }
    #pragma unroll
    for (int c=0;c<4;++c){
      int row = c*32 + srow;
      GLOAD16(outT + (size_t)row*512 + k0 + ((sseg ^ (row&7))<<3),
              (char*)Bl + c*4096 + w*1024);
    }
    __syncthreads();
    #pragma unroll
    for (int ks=0;ks<2;++ks){
      s8v bf[4];
      #pragma unroll
      for (int ct=0;ct<4;++ct){
        int col = wc*64 + ct*16 + (l&15);
        bf[ct] = *(const s8v*)((const char*)Bl + col*128 + ((((l>>4)+ks*4) ^ (col&7))<<4));
      }
      #pragma unroll
      for (int rt=0;rt<2;++rt){
        int arow = wr*32 + rt*16 + (l&15);
        s8v af = *(const s8v*)((const char*)Al + arow*128 + ((((l>>4)+ks*4) ^ (arow&7))<<4));
        #pragma unroll
        for (int ct=0;ct<4;++ct)
          acc[rt][ct] = MFMA16(af, bf[ct], acc[rt][ct]);
      }
    }
    __syncthreads();
  }
  // stage ffn weights (async, lands before next barrier)
  #pragma unroll
  for (int kh=0;kh<2;++kh)
    #pragma unroll
    for (int c=0;c<4;++c){
      int row = c*32 + srow;
      GLOAD16(ffnT + (size_t)row*128 + kh*64 + ((sseg ^ (row&7))<<3),
              ffnB + kh*16384 + c*4096 + w*1024);
    }
  // epilogue1: o1 = acc + out_b + x  -> vst
  {
    float bia[4];
    #pragma unroll
    for (int ct=0;ct<4;++ct) bia[ct] = out_b[wc*64 + ct*16 + (l&15)];
    #pragma unroll
    for (int rt=0;rt<2;++rt)
      #pragma unroll
      for (int ct=0;ct<4;++ct)
        #pragma unroll
        for (int r=0;r<4;++r){
          int rr = wr*32 + rt*16 + (l>>4)*4 + r;
          int cc = wc*64 + ct*16 + (l&15);
          vst[rr*128 + cc] = acc[rt][ct][r] + bia[ct] + x[(size_t)(bm+rr)*128 + cc];
        }
  }
  __syncthreads();
  // LN1 -> xnl (swizzled bf16 A-layout)
  {
    const float2 g1v = *(const float2*)(g1 + l*2);
    const float2 b1v = *(const float2*)(b1 + l*2);
    for (int rr=0; rr<16; ++rr){
      int row = w*16 + rr;
      float2 vv = *(const float2*)&vst[row*128 + l*2];
      float s = vv.x+vv.y, sq = vv.x*vv.x + vv.y*vv.y;
      #pragma unroll
      for (int m=1;m<64;m<<=1){ s += __shfl_xor(s,m,64); sq += __shfl_xor(sq,m,64); }
      float mean = s*(1.f/128.f);
      float rstd = rsqrtf(sq*(1.f/128.f) - mean*mean + 1e-5f);
      float xa = (vv.x-mean)*rstd*g1v.x + b1v.x;
      float xb = (vv.y-mean)*rstd*g1v.y + b1v.y;
      int col = l*2;
      int byte = row*256 + (((col>>3) ^ (row&7))<<4) + ((col&7)<<1);
      unsigned int pk = (unsigned int)f2bf(xa) | ((unsigned int)f2bf(xb)<<16);
      *(unsigned int*)(xnl + byte) = pk;
    }
  }
  __syncthreads();
  // GEMM2: o2 = xn @ ffnT^T
  f4v acc2[2][4];
  #pragma unroll
  for (int i=0;i<2;++i)
    #pragma unroll
    for (int j=0;j<4;++j) acc2[i][j] = (f4v){0.f,0.f,0.f,0.f};
  #pragma unroll
  for (int ks2=0;ks2<4;++ks2){
    int kh = ks2>>1, ks = ks2&1;
    s8v bf[4];
    #pragma unroll
    for (int ct=0;ct<4;++ct){
      int col = wc*64 + ct*16 + (l&15);
      bf[ct] = *(const s8v*)(ffnB + kh*16384 + col*128 + ((((l>>4)+ks*4) ^ (col&7))<<4));
    }
    #pragma unroll
    for (int rt=0;rt<2;++rt){
      int arow = wr*32 + rt*16 + (l&15);
      s8v af = *(const s8v*)(xnl + arow*256 + ((((l>>4)+ks2*4) ^ (arow&7))<<4));
      #pragma unroll
      for (int ct=0;ct<4;++ct)
        acc2[rt][ct] = MFMA16(af, bf[ct], acc2[rt][ct]);
    }
  }
  // epilogue2: vst += softplus(acc2 + ffn_b)
  {
    float fb[4];
    #pragma unroll
    for (int ct=0;ct<4;++ct) fb[ct] = ffn_b[wc*64 + ct*16 + (l&15)];
    #pragma unroll
    for (int rt=0;rt<2;++rt)
      #pragma unroll
      for (int ct=0;ct<4;++ct)
        #pragma unroll
        for (int r=0;r<4;++r){
          int rr = wr*32 + rt*16 + (l>>4)*4 + r;
          int cc = wc*64 + ct*16 + (l&15);
          vst[rr*128 + cc] += softplus_f(acc2[rt][ct][r] + fb[ct]);
        }
  }
  __syncthreads();
  // LN2 -> x ; optional LN3 -> xnb
  {
    const float2 g1v = *(const float2*)(g1 + l*2);
    const float2 b1v = *(const float2*)(b1 + l*2);
    for (int rr=0; rr<16; ++rr){
      int row = w*16 + rr;
      float2 vv = *(const float2*)&vst[row*128 + l*2];
      float s = vv.x+vv.y, sq = vv.x*vv.x + vv.y*vv.y;
      #pragma unroll
      for (int m=1;m<64;m<<=1){ s += __shfl_xor(s,m,64); sq += __shfl_xor(sq,m,64); }
      float mean = s*(1.f/128.f);
      float rstd = rsqrtf(sq*(1.f/128.f) - mean*mean + 1e-5f);
      float xa = (vv.x-mean)*rstd*g1v.x + b1v.x;
      float xb = (vv.y-mean)*rstd*g1v.y + b1v.y;
      float2 xo; xo.x = xa; xo.y = xb;
      *(float2*)(x + (size_t)(bm+row)*128 + l*2) = xo;
      if (g2) {
        float s2 = xa+xb, sq2 = xa*xa + xb*xb;
        #pragma unroll
        for (int m=1;m<64;m<<=1){ s2 += __shfl_xor(s2,m,64); sq2 += __shfl_xor(sq2,m,64); }
        float mean2 = s2*(1.f/128.f);
        float rstd2 = rsqrtf(sq2*(1.f/128.f) - mean2*mean2 + 1e-5f);
        const float2 g2v = *(const float2*)(g2 + l*2);
        const float2 b2v = *(const float2*)(b2 + l*2);
        float ya = (xa-mean2)*rstd2*g2v.x + b2v.x;
        float yb = (xb-mean2)*rstd2*g2v.y + b2v.y;
        unsigned int pk = (unsigned int)f2bf(ya) | ((unsigned int)f2bf(yb)<<16);
        *(unsigned int*)(xnb + (size_t)(bm+row)*128 + l*2) = pk;
      }
    }
  }
}

// ---------- pooling (parallel partials) + final ----------
__global__ __launch_bounds__(128) void pool_part_kernel(const float* __restrict__ x,
    const float* __restrict__ x_init,
    const float* __restrict__ w_row, float* __restrict__ partial) {
  int b = blockIdx.x, p = blockIdx.y, e = threadIdx.x;
  float acc = 0.f;
  for (int n = p*64; n < p*64+64; ++n) {
    float w = w_row[(size_t)b*N_ + n];
    size_t o = ((size_t)b*N_ + n)*E_ + e;
    acc += w * (x[o] + x_init[o]);
  }
  partial[((size_t)b*8 + p)*E_ + e] = acc;
}

__global__ __launch_bounds__(128) void final_kernel(const float* __restrict__ partial,
    const float* __restrict__ g, const float* __restrict__ bt,
    const float* __restrict__ fw, const float* __restrict__ fb, float* __restrict__ out) {
  int b = blockIdx.x, t = threadIdx.x;
  float v = 0.f;
  for (int p=0;p<8;++p) v += partial[((size_t)b*8+p)*E_ + t];
  float s = v, sq = v*v;
  #pragma unroll
  for (int m = 1; m < 64; m <<= 1) { s += __shfl_xor(s, m, 64); sq += __shfl_xor(sq, m, 64); }
  __shared__ float red[4];
  int wv = t >> 6, ln = t & 63;
  if (ln == 0) { red[wv*2] = s; red[wv*2+1] = sq; }
  __syncthreads();
  s = red[0] + red[2]; sq = red[1] + red[3];
  float mean = s*(1.f/E_), var = sq*(1.f/E_) - mean*mean;
  float rstd = rsqrtf(var + 1e-5f);
  float xl = (v - mean)*rstd*g[t] + bt[t];
  float p = xl * fw[t];
  #pragma unroll
  for (int m = 1; m < 64; m <<= 1) p += __shfl_xor(p, m, 64);
  __shared__ float red2[2];
  if (ln == 0) red2[wv] = p;
  __syncthreads();
  if (t == 0) out[b] = red2[0] + red2[1] + fb[0];
}

extern "C" void kernel_launch(void* const* d_in, const int* in_sizes, int n_in,
                              void* d_out, int out_size, void* d_ws, size_t ws_size,
                              hipStream_t stream) {
  (void)in_sizes; (void)n_in; (void)out_size; (void)ws_size;
  const float* str_fea  = (const float*)d_in[0];
  const int*   comp_fea = (const int*)  d_in[1];
  const float* af_table = (const float*)d_in[3];
  const float* comp_w   = (const float*)d_in[4];
  const float* comp_b   = (const float*)d_in[5];
  const float* emb_w    = (const float*)d_in[6];
  const float* emb_b    = (const float*)d_in[7];
  const float* ln_g     = (const float*)d_in[8];
  const float* ln_b     = (const float*)d_in[9];
  const float* wq       = (const float*)d_in[10];
  const float* bq       = (const float*)d_in[11];
  const float* wk       = (const float*)d_in[12];
  const float* bk       = (const float*)d_in[13];
  const float* wv       = (const float*)d_in[14];
  const float* bv       = (const float*)d_in[15];
  const float* inproj_w = (const float*)d_in[16];
  const float* inproj_b = (const float*)d_in[17];
  const float* out_w    = (const float*)d_in[18];
  const float* out_b    = (const float*)d_in[19];
  const float* ffn_w    = (const float*)d_in[20];
  const float* ffn_b    = (const float*)d_in[21];
  const float* ln2_g    = (const float*)d_in[22];
  const float* ln2_b    = (const float*)d_in[23];
  const float* final_w  = (const float*)d_in[24];
  const float* final_b  = (const float*)d_in[25];
  float* out = (float*)d_out;

  float* ws = (float*)d_ws;
  size_t off = 0;
  float* x      = ws + off; off += 2097152;
  float* x_init = ws + off; off += 2097152;
  float* w_row  = ws + off; off += 16384;
  unsigned short* xnb  = (unsigned short*)(ws + off); off += 1048576;   // [M][128]
  unsigned short* qkb  = (unsigned short*)(ws + off); off += 8388608;   // [M][1024]
  unsigned short* vTb  = (unsigned short*)(ws + off); off += 4194304;   // [B][512][512]
  unsigned short* attb = (unsigned short*)(ws + off); off += 4194304;   // [M][512]
  unsigned short* Pb   = (unsigned short*)(ws + off); off += 16777216;  // [B][H][512][512]
  float* Sinvb  = ws + off; off += 65536;
  float* rhob   = ws + off; off += 65536;
  float* part   = ws + off; off += 24576;    // [6][8][512]
  float* bqkv   = ws + off; off += 4608;
  unsigned short* wqkvT = (unsigned short*)(ws + off); off += 294912;   // [3][1536][128]
  unsigned short* outT  = (unsigned short*)(ws + off); off += 98304;    // [3][128][512]
  unsigned short* ffnT  = (unsigned short*)(ws + off); off += 24576;    // [3][128][128]
  unsigned short* FHi   = (unsigned short*)(ws + off); off += 2621440;  // [M][320]
  unsigned short* FLo   = (unsigned short*)(ws + off); off += 2621440;
  unsigned short* WHi   = (unsigned short*)(ws + off); off += 20480;    // [128][320]
  unsigned short* WLo   = (unsigned short*)(ws + off); off += 20480;
  float* biasE  = ws + off; off += 128;
  float* Cpart  = ws + off; off += 1280;
  float* partial= ws + off; off += 32768;

  effb_part_kernel<<<dim3(6,8), 256, 0, stream>>>(bq, bk, inproj_w, part);
  eff_gemm_kernel<<<48, 256, 0, stream>>>(wq, wk, inproj_w, wqkvT);
  wtrans_kernel<<<126, 256, 0, stream>>>(wv, out_w, ffn_w, inproj_b, bv, part,
                                         wqkvT, outT, ffnT, bqkv);
  embW1_kernel<<<12, 128, 0, stream>>>(emb_w, comp_w, WHi, WLo, Cpart);
  embBias_kernel<<<1, 128, 0, stream>>>(Cpart, comp_b, emb_b, biasE);
  feat_kernel<<<M_*40/256, 256, 0, stream>>>(str_fea, comp_fea, af_table, FHi, FLo, w_row);
  embgemm_kernel<<<M_/64, 256, 0, stream>>>(FHi, FLo, WHi, WLo, biasE,
                                            ln_g, ln_b, x, x_init, xnb);

  for (int l = 0; l < L_; ++l) {
    mgemm_kernel<4><<<dim3(M_/128, 12), 256, 0, stream>>>(
        xnb, wqkvT + (size_t)l*196608, bqkv + l*1536, qkb, vTb, 128);
    attnA_kernel<<<dim3(8, 4, 32), 256, 0, stream>>>(qkb, w_row, Pb, Sinvb, rhob);
    attnPV_kernel<<<dim3(16, 32), 256, 0, stream>>>(Pb, Sinvb, rhob, vTb, w_row, attb);
    tail_kernel<<<M_/64, 256, 0, stream>>>(
        attb, outT + (size_t)l*65536, out_b + (size_t)l*E_,
        ffnT + (size_t)l*16384, ffn_b + (size_t)l*E_,
        x, xnb, ln_g + l*E_, ln_b + l*E_,
        (l < 2) ? (ln_g + (l+1)*E_) : nullptr,
        (l < 2) ? (ln_b + (l+1)*E_) : nullptr);
  }

  pool_part_kernel<<<dim3(B_, 8), 128, 0, stream>>>(x, x_init, w_row, partial);
  final_kernel<<<B_, 128, 0, stream>>>(partial, ln2_g, ln2_b, final_w, final_b, out);
}

// Round 6
// 447.992 us; speedup vs baseline: 7.7950x; 1.0580x over previous
//
#include <hip/hip_runtime.h>
#include <math.h>

#define B_ 32
#define N_ 512
#define F_ 101
#define E_ 128
#define H_ 4
#define EH_ 512
#define L_ 3
#define M_ (B_*N_)   // 16384

typedef __attribute__((ext_vector_type(8))) short s8v;
typedef __attribute__((ext_vector_type(8))) unsigned short us8v;
typedef __attribute__((ext_vector_type(4))) float f4v;
typedef __attribute__((ext_vector_type(4))) unsigned int u4v;

__device__ __forceinline__ unsigned short f2bf(float f){
  unsigned int u = __builtin_bit_cast(unsigned int, f);
  u += 0x7fffu + ((u>>16)&1u);
  return (unsigned short)(u>>16);
}
__device__ __forceinline__ float bf2f(unsigned int h){
  unsigned int u = h<<16; return __builtin_bit_cast(float, u);
}
__device__ __forceinline__ float softplus_f(float v) {
  return fmaxf(v, 0.f) + log1pf(__expf(-fabsf(v)));
}

#define GLOAD16(gp, lp) __builtin_amdgcn_global_load_lds( \
    (__attribute__((address_space(1))) unsigned int*)(gp), \
    (__attribute__((address_space(3))) unsigned int*)(lp), 16, 0, 0)

#define MFMA16(a,b,c) __builtin_amdgcn_mfma_f32_16x16x32_bf16(a,b,c,0,0,0)

// ---------- eff fold partials: split-K, 384 blocks ----------
// part[ks][lq][nt][n64][m128] f32; block = (lq*8+nt, ks), K-chunk = 64
__global__ __launch_bounds__(256) void effp_kernel(
    const float* __restrict__ wq, const float* __restrict__ wk,
    const float* __restrict__ inproj_w, float* __restrict__ part) {
  __shared__ float As[64][132];   // [kk][r]
  __shared__ float Bs[64][68];    // [kk][c]
  const int blk = blockIdx.x;     // 48 = 6 lq * 8 ntiles
  const int ks = blockIdx.y;      // 8 K-chunks of 64
  const int lq = blk>>3, nt = blk&7;
  const int l = lq>>1, qk = lq&1;
  const int bn = nt*64;
  const int k0 = ks*64;
  const float* A = (qk ? wk : wq) + (size_t)l*128*512;
  const float* IP = inproj_w + (size_t)l*512*1536 + qk*512 + bn;
  const int t = threadIdx.x;
  float acc[8][4];
  #pragma unroll
  for (int i=0;i<8;++i)
    #pragma unroll
    for (int j=0;j<4;++j) acc[i][j]=0.f;
  const int r0 = (t&15)*8, c0 = (t>>4)*4;
  {
    int r = t & 127, half = t>>7;
    #pragma unroll
    for (int u=0;u<8;++u){
      float4 a = *(const float4*)(A + (size_t)r*512 + k0 + half*32 + u*4);
      int kk = half*32 + u*4;
      As[kk+0][r]=a.x; As[kk+1][r]=a.y; As[kk+2][r]=a.z; As[kk+3][r]=a.w;
    }
    int kk = t>>2, cb = (t&3)*16;
    #pragma unroll
    for (int u=0;u<4;++u)
      *(float4*)&Bs[kk][cb+u*4] = *(const float4*)(IP + (size_t)(k0+kk)*1536 + cb + u*4);
  }
  __syncthreads();
  for (int k2=0;k2<64;++k2){
    float4 b = *(const float4*)&Bs[k2][c0];
    float4 a0 = *(const float4*)&As[k2][r0];
    float4 a1 = *(const float4*)&As[k2][r0+4];
    float av[8] = {a0.x,a0.y,a0.z,a0.w,a1.x,a1.y,a1.z,a1.w};
    #pragma unroll
    for (int i=0;i<8;++i){
      acc[i][0] += av[i]*b.x; acc[i][1] += av[i]*b.y;
      acc[i][2] += av[i]*b.z; acc[i][3] += av[i]*b.w;
    }
  }
  // write transposed [n][m], coalesced on m
  #pragma unroll
  for (int j=0;j<4;++j){
    float* dst = part + (((size_t)ks*48 + blk)*64 + c0 + j)*128 + r0;
    float4 v0 = {acc[0][j], acc[1][j], acc[2][j], acc[3][j]};
    float4 v1 = {acc[4][j], acc[5][j], acc[6][j], acc[7][j]};
    *(float4*)dst = v0;
    *(float4*)(dst+4) = v1;
  }
}

// ---------- reduce 8 partials -> bf16 wqkvT ----------
__global__ __launch_bounds__(256) void effred_kernel(
    const float* __restrict__ part, unsigned short* __restrict__ wqkvT) {
  int idx = blockIdx.x*256 + threadIdx.x;   // 6*512*128 = 393216
  int m = idx & 127;
  int n = (idx>>7) & 511;
  int lq = idx >> 16;
  int l = lq>>1, qk = lq&1;
  size_t base = (((size_t)(lq*8 + (n>>6)))*64 + (n&63))*128 + m;
  float v = 0.f;
  #pragma unroll
  for (int ks=0;ks<8;++ks) v += part[(size_t)ks*393216 + base];
  wqkvT[((size_t)l*1536 + qk*512 + n)*128 + m] = f2bf(v);
}

// ---------- eff bias partials: part[lq][kt][512] ----------
__global__ __launch_bounds__(256) void effb_part_kernel(
    const float* __restrict__ bq, const float* __restrict__ bk,
    const float* __restrict__ inproj_w, float* __restrict__ part) {
  const int lq = blockIdx.x, kt = blockIdx.y;   // 6 x 8
  const int l = lq>>1, qk = lq&1;
  const float* bv = (qk?bk:bq) + l*512 + kt*64;
  const float* IP = inproj_w + ((size_t)l*512 + kt*64)*1536 + qk*512;
  const int t = threadIdx.x;
  float a0=0.f, a1=0.f;
  for (int kk=0; kk<64; ++kk){
    float b = bv[kk];
    const float* row = IP + (size_t)kk*1536;
    a0 += b*row[t];
    a1 += b*row[t+256];
  }
  part[(lq*8+kt)*512 + t]       = a0;
  part[(lq*8+kt)*512 + t + 256] = a1;
}

// ---------- weight transposes (LDS-tiled) + bqkv assembly ----------
__global__ __launch_bounds__(256) void wtrans_kernel(
    const float* __restrict__ wv, const float* __restrict__ out_w,
    const float* __restrict__ ffn_w,
    const float* __restrict__ inproj_b, const float* __restrict__ bvv,
    const float* __restrict__ part,
    unsigned short* __restrict__ wqkvT, unsigned short* __restrict__ outT,
    unsigned short* __restrict__ ffnT, float* __restrict__ bqkv) {
  const int blk = blockIdx.x;   // 0..125
  const int t = threadIdx.x;
  if (blk < 108) {
    __shared__ float tile[64][65];
    const float* src; unsigned short* dst; int srcld, dstld;
    if (blk < 48) {              // wv [3][128][512] -> wqkvT v-part [n][k]
      int lay = blk/16, rem = blk%16, kt = rem>>3, nt = rem&7;
      src = wv + ((size_t)lay*128 + kt*64)*512 + nt*64; srcld = 512;
      dst = wqkvT + ((size_t)lay*1536 + 1024 + nt*64)*128 + kt*64; dstld = 128;
    } else if (blk < 96) {       // out_w [3][512][128] -> outT [n][k]
      int b2 = blk-48; int lay = b2/16, rem = b2%16, kt = rem>>1, nt = rem&1;
      src = out_w + ((size_t)lay*512 + kt*64)*128 + nt*64; srcld = 128;
      dst = outT + ((size_t)lay*128 + nt*64)*512 + kt*64; dstld = 512;
    } else {                     // ffn_w [3][128][128] -> ffnT [n][k]
      int b3 = blk-96; int lay = b3/4, rem = b3%4, kt = rem>>1, nt = rem&1;
      src = ffn_w + ((size_t)lay*128 + kt*64)*128 + nt*64; srcld = 128;
      dst = ffnT + ((size_t)lay*128 + nt*64)*128 + kt*64; dstld = 128;
    }
    #pragma unroll
    for (int rp=0; rp<4; ++rp){
      int r = rp*16 + (t>>4), c = (t&15)*4;
      float4 v = *(const float4*)(src + (size_t)r*srcld + c);
      tile[r][c+0]=v.x; tile[r][c+1]=v.y; tile[r][c+2]=v.z; tile[r][c+3]=v.w;
    }
    __syncthreads();
    #pragma unroll
    for (int wp=0; wp<2; ++wp){
      int n = wp*32 + (t>>3), kk = (t&7)*8;
      us8v pk;
      #pragma unroll
      for (int e=0;e<8;++e) pk[e] = f2bf(tile[kk+e][n]);
      *(us8v*)(dst + (size_t)n*dstld + kk) = pk;
    }
  } else {
    int idx = (blk-108)*256 + t;          // 0..4607
    int l = idx/1536, n = idx - l*1536;
    float v;
    if (n < 1024) {
      int qk = n>>9, c = n&511;
      v = inproj_b[(size_t)l*1536 + n];
      #pragma unroll
      for (int kt=0;kt<8;++kt) v += part[((l*2+qk)*8+kt)*512 + c];
    } else {
      v = bvv[(size_t)l*512 + (n-1024)];
    }
    bqkv[idx] = v;
  }
}

// ---------- embed weight prep: quadratic expansion A/B/C + split bf16 ----------
__global__ __launch_bounds__(128) void embW1_kernel(
    const float* __restrict__ emb_w, const float* __restrict__ comp_w,
    unsigned short* __restrict__ WHi, unsigned short* __restrict__ WLo,
    float* __restrict__ Cpart) {
  int p = blockIdx.x, e = threadIdx.x;
  if (p < 10) {
    float Cp = 0.f;
    for (int ff=0; ff<10; ++ff){
      int f = p*10+ff;
      float A=0.f, Bv=0.f;
      #pragma unroll
      for (int s=0;s<10;++s){
        float wv = emb_w[(size_t)(f*10+s)*128 + e];
        A += wv; Bv += 0.2f*s*wv; Cp += 0.01f*(s*s)*wv;
      }
      int kA = 92+f, kB = 192+f;
      unsigned short hA = f2bf(A);
      WHi[e*320+kA]=hA; WLo[e*320+kA]=f2bf(A - bf2f(hA));
      unsigned short hB = f2bf(Bv);
      WHi[e*320+kB]=hB; WLo[e*320+kB]=f2bf(Bv - bf2f(hB));
    }
    Cpart[p*128+e] = Cp;
  } else if (p == 10) {
    for (int kk=0;kk<92;++kk){
      float v = comp_w[(size_t)kk*128 + e];
      unsigned short h = f2bf(v);
      WHi[e*320+kk]=h; WLo[e*320+kk]=f2bf(v - bf2f(h));
    }
  } else {
    for (int kk=292;kk<320;++kk){ WHi[e*320+kk]=0; WLo[e*320+kk]=0; }
  }
}

__global__ __launch_bounds__(128) void embBias_kernel(
    const float* __restrict__ Cpart, const float* __restrict__ comp_b,
    const float* __restrict__ emb_b, float* __restrict__ biasE){
  int e = threadIdx.x; float c=0.f;
  for (int p=0;p<10;++p) c += Cpart[p*128+e];
  biasE[e] = comp_b[e] + emb_b[e] + c;
}

// ---------- feature builder (coalesced) ----------
__global__ __launch_bounds__(256) void feat_kernel(
    const float* __restrict__ str_fea, const int* __restrict__ comp_fea,
    const float* __restrict__ af_table,
    unsigned short* __restrict__ FHi, unsigned short* __restrict__ FLo,
    float* __restrict__ w_row) {
  int g = blockIdx.x*256 + threadIdx.x;      // M*40 = 655360
  int row = g / 40, seg = g - row*40;
  const float* sr = str_fea + (size_t)row*F_;
  if (seg == 0) w_row[row] = sr[0];
  const float* af = af_table + (size_t)comp_fea[row]*92;
  const int c0 = seg*8;
  us8v hi, lo;
  #pragma unroll
  for (int e=0;e<8;++e){
    int kk = c0+e; float v;
    if (kk < 92) v = af[kk];
    else if (kk < 192) { float u = 1.f - sr[1+kk-92]; v = u*u; }
    else if (kk < 292) v = 1.f - sr[1+kk-192];
    else v = 0.f;
    unsigned short h = f2bf(v);
    hi[e] = h; lo[e] = f2bf(v - bf2f(h));
  }
  *(us8v*)(FHi + (size_t)row*320 + c0) = hi;
  *(us8v*)(FLo + (size_t)row*320 + c0) = lo;
}

// ---------- embed GEMM (split bf16, 3-MFMA) + LN0 epilogue ----------
__global__ __launch_bounds__(256) void embgemm_kernel(
    const unsigned short* __restrict__ FHi, const unsigned short* __restrict__ FLo,
    const unsigned short* __restrict__ WHi, const unsigned short* __restrict__ WLo,
    const float* __restrict__ biasE,
    const float* __restrict__ g0, const float* __restrict__ b0,
    float* __restrict__ x, float* __restrict__ x_init,
    unsigned short* __restrict__ xnb) {
  __shared__ unsigned short lds[24576];    // 48 KB
  unsigned short* AHi = lds;
  unsigned short* ALo = lds + 4096;
  unsigned short* BHi = lds + 8192;
  unsigned short* BLo = lds + 16384;
  const int bm = blockIdx.x*64;
  const int t = threadIdx.x, w = t>>6, l = t&63;
  f4v acc[8];
  #pragma unroll
  for (int i=0;i<8;++i) acc[i] = (f4v){0.f,0.f,0.f,0.f};
  const int srow = t>>3, sseg = t&7;
  for (int k0=0;k0<320;k0+=64){
    #pragma unroll
    for (int c=0;c<2;++c){
      int row = c*32+srow;
      GLOAD16(FHi + (size_t)(bm+row)*320 + k0 + ((sseg^(row&7))<<3), (char*)AHi + c*4096 + w*1024);
      GLOAD16(FLo + (size_t)(bm+row)*320 + k0 + ((sseg^(row&7))<<3), (char*)ALo + c*4096 + w*1024);
    }
    #pragma unroll
    for (int c=0;c<4;++c){
      int row = c*32+srow;
      GLOAD16(WHi + (size_t)row*320 + k0 + ((sseg^(row&7))<<3), (char*)BHi + c*4096 + w*1024);
      GLOAD16(WLo + (size_t)row*320 + k0 + ((sseg^(row&7))<<3), (char*)BLo + c*4096 + w*1024);
    }
    __syncthreads();
    #pragma unroll
    for (int ks=0;ks<2;++ks){
      int arow = w*16 + (l&15);
      int aswz = ((((l>>4)+ks*4) ^ (arow&7))<<4);
      s8v ah = *(const s8v*)((const char*)AHi + arow*128 + aswz);
      s8v al = *(const s8v*)((const char*)ALo + arow*128 + aswz);
      #pragma unroll
      for (int ct=0;ct<8;++ct){
        int col = ct*16 + (l&15);
        int bswz = ((((l>>4)+ks*4) ^ (col&7))<<4);
        s8v bh = *(const s8v*)((const char*)BHi + col*128 + bswz);
        s8v bl = *(const s8v*)((const char*)BLo + col*128 + bswz);
        acc[ct] = MFMA16(ah, bh, acc[ct]);
        acc[ct] = MFMA16(ah, bl, acc[ct]);
        acc[ct] = MFMA16(al, bh, acc[ct]);
      }
    }
    __syncthreads();
  }
  float vv[8][4], gc[8], bc[8];
  #pragma unroll
  for (int ct=0;ct<8;++ct){
    int c = ct*16 + (l&15);
    float be = biasE[c]; gc[ct] = g0[c]; bc[ct] = b0[c];
    #pragma unroll
    for (int r=0;r<4;++r) vv[ct][r] = acc[ct][r] + be;
  }
  #pragma unroll
  for (int r=0;r<4;++r){
    float s=0.f, sq=0.f;
    #pragma unroll
    for (int ct=0;ct<8;++ct){ s += vv[ct][r]; sq += vv[ct][r]*vv[ct][r]; }
    #pragma unroll
    for (int m=1;m<16;m<<=1){ s += __shfl_xor(s,m,64); sq += __shfl_xor(sq,m,64); }
    float mean = s*(1.f/128.f);
    float rstd = rsqrtf(sq*(1.f/128.f) - mean*mean + 1e-5f);
    int row = bm + w*16 + (l>>4)*4 + r;
    #pragma unroll
    for (int ct=0;ct<8;++ct){
      int c = ct*16 + (l&15);
      float v = vv[ct][r];
      x[(size_t)row*128 + c] = v;
      x_init[(size_t)row*128 + c] = v;
      xnb[(size_t)row*128 + c] = f2bf((v-mean)*rstd*gc[ct] + bc[ct]);
    }
  }
}

// ---------- bf16 MFMA GEMM (qkv): bf16 out -> qkb (n<1024) or transposed vT ----------
template<int RT>
__global__ __launch_bounds__(256) void mgemm_kernel(
    const unsigned short* __restrict__ A,
    const unsigned short* __restrict__ Bt,
    const float* __restrict__ bias,
    unsigned short* __restrict__ Cb,
    unsigned short* __restrict__ vT,
    int K) {
  constexpr int BM = RT*32;
  __shared__ float smem[8192];   // 32 KB
  unsigned short* Al = (unsigned short*)smem;
  unsigned short* Bl = Al + BM*64;
  const int bm = blockIdx.x*BM;
  const int bn = blockIdx.y*128;
  const int t = threadIdx.x;
  const int w = t>>6, l = t&63;
  const int wr = w>>1, wc = w&1;
  f4v acc[RT][4];
  #pragma unroll
  for (int i=0;i<RT;++i)
    #pragma unroll
    for (int j=0;j<4;++j) acc[i][j] = (f4v){0.f,0.f,0.f,0.f};
  const int srow = t>>3, sseg = t&7;
  for (int k0 = 0; k0 < K; k0 += 64) {
    #pragma unroll
    for (int c=0;c<BM/32;++c){
      int row = c*32 + srow;
      GLOAD16(A + (size_t)(bm+row)*K + k0 + ((sseg ^ (row&7))<<3),
              (char*)Al + c*4096 + w*1024);
    }
    #pragma unroll
    for (int c=0;c<4;++c){
      int row = c*32 + srow;
      GLOAD16(Bt + (size_t)(bn+row)*K + k0 + ((sseg ^ (row&7))<<3),
              (char*)Bl + c*4096 + w*1024);
    }
    __syncthreads();
    #pragma unroll
    for (int ks=0;ks<2;++ks){
      s8v bf[4];
      #pragma unroll
      for (int ct=0;ct<4;++ct){
        int col = wc*64 + ct*16 + (l&15);
        bf[ct] = *(const s8v*)((const char*)Bl + col*128 + ((((l>>4)+ks*4) ^ (col&7))<<4));
      }
      #pragma unroll
      for (int rt=0;rt<RT;++rt){
        int arow = wr*(RT*16) + rt*16 + (l&15);
        s8v af = *(const s8v*)((const char*)Al + arow*128 + ((((l>>4)+ks*4) ^ (arow&7))<<4));
        #pragma unroll
        for (int ct=0;ct<4;++ct)
          acc[rt][ct] = MFMA16(af, bf[ct], acc[rt][ct]);
      }
    }
    __syncthreads();
  }
  float bia[4];
  #pragma unroll
  for (int ct=0;ct<4;++ct) bia[ct] = bias[bn + wc*64 + ct*16 + (l&15)];
  unsigned short* lds16 = (unsigned short*)smem;
  if (bn < 1024) {
    #pragma unroll
    for (int rt=0;rt<RT;++rt)
      #pragma unroll
      for (int ct=0;ct<4;++ct)
        #pragma unroll
        for (int r=0;r<4;++r){
          int rr = wr*(RT*16) + rt*16 + (l>>4)*4 + r;
          int cc = wc*64 + ct*16 + (l&15);
          lds16[rr*128 + cc] = f2bf(acc[rt][ct][r] + bia[ct]);
        }
    __syncthreads();
    #pragma unroll
    for (int it=0; it<BM/16; ++it){
      int row = it*16 + (t>>4), seg = t&15;
      u4v v = *(const u4v*)(lds16 + row*128 + seg*8);
      *(u4v*)(Cb + (size_t)(bm+row)*1024 + bn + seg*8) = v;
    }
  } else {
    #pragma unroll
    for (int rt=0;rt<RT;++rt)
      #pragma unroll
      for (int ct=0;ct<4;++ct){
        int rbase = bm + wr*(RT*16) + rt*16 + (l>>4)*4;
        int bb = rbase >> 9, nn = rbase & 511;
        int d = bn - 1024 + wc*64 + ct*16 + (l&15);
        unsigned int lo = (unsigned int)f2bf(acc[rt][ct][0] + bia[ct])
                        | ((unsigned int)f2bf(acc[rt][ct][1] + bia[ct])<<16);
        unsigned int hi = (unsigned int)f2bf(acc[rt][ct][2] + bia[ct])
                        | ((unsigned int)f2bf(acc[rt][ct][3] + bia[ct])<<16);
        uint2 pk; pk.x = lo; pk.y = hi;
        *(uint2*)(vT + ((size_t)(bb*512 + d))*512 + nn) = pk;
      }
  }
}

// ---------- attention stage A: P = exp(QK^T*sc), Sinv, rho ----------
__global__ __launch_bounds__(256) void attnA_kernel(
    const unsigned short* __restrict__ qkb, const float* __restrict__ w_row,
    unsigned short* __restrict__ P, float* __restrict__ Sinv,
    float* __restrict__ rho) {
  __shared__ unsigned short Qlds[64*128];
  __shared__ unsigned short Klds[64*128];
  __shared__ unsigned short Ptile[64*64];
  __shared__ float w_s[512];
  const int i0 = blockIdx.x*64;
  const int h = blockIdx.y, b = blockIdx.z;
  const int t = threadIdx.x, w = t>>6, l = t&63;
  const float SC = 0.088388347648318447f;   // 1/sqrt(128)
  for (int j=t;j<512;j+=256) w_s[j] = w_row[b*512+j];
  {
    int row = t>>4, seg = t&15;
    #pragma unroll
    for (int c=0;c<4;++c)
      GLOAD16(qkb + (size_t)(b*512 + i0 + c*16 + row)*1024 + h*128 + ((seg ^ (row&7))<<3),
              (char*)Qlds + c*4096 + w*1024);
  }
  __syncthreads();
  s8v qf[4];
  #pragma unroll
  for (int ks=0;ks<4;++ks){
    int arow = w*16 + (l&15);
    qf[ks] = *(const s8v*)((const char*)Qlds + arow*256 + ((((l>>4)+ks*4) ^ (arow&7))<<4));
  }
  float sp[4] = {0.f,0.f,0.f,0.f};
  float swp[4] = {0.f,0.f,0.f,0.f};
  for (int j0=0;j0<512;j0+=64){
    {
      int row = t>>4, seg = t&15;
      #pragma unroll
      for (int c=0;c<4;++c)
        GLOAD16(qkb + (size_t)(b*512 + j0 + c*16 + row)*1024 + 512 + h*128 + ((seg ^ (row&7))<<3),
                (char*)Klds + c*4096 + w*1024);
    }
    __syncthreads();
    #pragma unroll
    for (int jt=0;jt<4;++jt){
      f4v a = (f4v){0.f,0.f,0.f,0.f};
      #pragma unroll
      for (int ks=0;ks<4;++ks){
        int col = jt*16 + (l&15);
        s8v kf = *(const s8v*)((const char*)Klds + col*256 + ((((l>>4)+ks*4) ^ (col&7))<<4));
        a = MFMA16(qf[ks], kf, a);
      }
      int jl = jt*16 + (l&15);
      float wv = w_s[j0+jl];
      float mw = (wv != 0.f) ? 1.f : 0.f;
      #pragma unroll
      for (int r=0;r<4;++r){
        float e = __expf(a[r]*SC);
        sp[r]  += e*mw;
        swp[r] += e*wv;
        Ptile[(w*16 + (l>>4)*4 + r)*64 + jl] = f2bf(e);
      }
    }
    __syncthreads();
    #pragma unroll
    for (int it=0;it<2;++it){
      int row = it*32 + (t>>3), seg = t&7;
      u4v pv = *(const u4v*)(Ptile + row*64 + seg*8);
      *(u4v*)(P + ((size_t)((b*4+h)*512 + i0 + row))*512 + j0 + seg*8) = pv;
    }
  }
  #pragma unroll
  for (int r=0;r<4;++r){
    float s = sp[r], sw = swp[r];
    #pragma unroll
    for (int m=1;m<16;m<<=1){ s += __shfl_xor(s,m,64); sw += __shfl_xor(sw,m,64); }
    sp[r] = s; swp[r] = sw;
  }
  if ((l&15)==0){
    #pragma unroll
    for (int r=0;r<4;++r){
      size_t idx = (size_t)(b*4+h)*512 + i0 + w*16 + (l>>4)*4 + r;
      float si = 1.f/sp[r];
      Sinv[idx] = si;
      rho[idx]  = swp[r]*si;
    }
  }
}

// ---------- fused combine + PV: att = (w * sum_h P*Sinv) @ V / Z ----------
__global__ __launch_bounds__(256) void attnPV_kernel(
    const unsigned short* __restrict__ P, const float* __restrict__ Sinv,
    const float* __restrict__ rho, const unsigned short* __restrict__ vT,
    const float* __restrict__ w_row, unsigned short* __restrict__ att) {
  __shared__ unsigned short cL[32*520];   // [i][512] bf16, row stride 520
  __shared__ unsigned short Vl[8192];     // 16 KB V tile; reused as epilogue staging
  __shared__ float w_s[512];
  __shared__ float sinv_s[4][32];
  __shared__ float zinv_s[32];
  const int bm = blockIdx.x*32, b = blockIdx.y;
  const int t = threadIdx.x, w = t>>6, l = t&63;
  const int wd = w>>1, wi = w&1;
  for (int j=t;j<512;j+=256) w_s[j] = w_row[b*512+j];
  if (t < 128) sinv_s[t>>5][t&31] = Sinv[(size_t)(b*4+(t>>5))*512 + bm + (t&31)];
  if (t >= 128 && t < 160){
    int i = t-128; float z=0.f;
    #pragma unroll
    for (int hh=0;hh<4;++hh) z += rho[(size_t)(b*4+hh)*512 + bm + i];
    zinv_s[i] = 1.f/z;
  }
  __syncthreads();
  // combine phase: build c-tile for all 512 j
  {
    const int i = t&31, jseg = t>>5;
    float cv[64];
    #pragma unroll
    for (int e=0;e<64;++e) cv[e]=0.f;
    #pragma unroll
    for (int hh=0;hh<4;++hh){
      const unsigned short* pp = P + ((size_t)((b*4+hh)*512 + bm + i))*512 + jseg*64;
      float si = sinv_s[hh][i];
      #pragma unroll
      for (int u=0;u<8;++u){
        u4v p = *(const u4v*)(pp + u*8);
        #pragma unroll
        for (int e=0;e<4;++e){
          cv[u*8+2*e]   += bf2f(p[e]&0xffffu)*si;
          cv[u*8+2*e+1] += bf2f(p[e]>>16)*si;
        }
      }
    }
    #pragma unroll
    for (int u=0;u<8;++u){
      us8v pk;
      #pragma unroll
      for (int e=0;e<8;++e)
        pk[e] = f2bf(cv[u*8+e] * w_s[jseg*64 + u*8 + e]);
      *(us8v*)((char*)cL + i*1040 + jseg*128 + u*16) = pk;
    }
  }
  __syncthreads();
  const int srow = t>>3, sseg = t&7;
  #pragma unroll 1
  for (int nt=0; nt<4; ++nt){
    const int bn = nt*128;
    f4v acc[4];
    #pragma unroll
    for (int j=0;j<4;++j) acc[j] = (f4v){0.f,0.f,0.f,0.f};
    for (int k0=0;k0<512;k0+=64){
      #pragma unroll
      for (int c=0;c<4;++c){
        int row = c*32 + srow;
        GLOAD16(vT + ((size_t)(b*512 + bn + row))*512 + k0 + ((sseg^(row&7))<<3),
                (char*)Vl + c*4096 + w*1024);
      }
      __syncthreads();
      #pragma unroll
      for (int ks=0;ks<2;++ks){
        int kidx = (l>>4) + ks*4;
        int arow = wi*16 + (l&15);
        s8v af = *(const s8v*)((const char*)cL + arow*1040 + k0*2 + kidx*16);
        #pragma unroll
        for (int ct=0;ct<4;++ct){
          int col = wd*64 + ct*16 + (l&15);
          s8v bf = *(const s8v*)((const char*)Vl + col*128 + ((kidx ^ (col&7))<<4));
          acc[ct] = MFMA16(af, bf, acc[ct]);
        }
      }
      __syncthreads();
    }
    // epilogue: scale by 1/Z, repack, coalesced store
    #pragma unroll
    for (int ct=0;ct<4;++ct)
      #pragma unroll
      for (int r=0;r<4;++r){
        int rr = wi*16 + (l>>4)*4 + r;
        int cc = wd*64 + ct*16 + (l&15);
        Vl[rr*128 + cc] = f2bf(acc[ct][r]*zinv_s[rr]);
      }
    __syncthreads();
    #pragma unroll
    for (int it=0; it<2; ++it){
      int row = it*16 + (t>>4), seg = t&15;
      u4v v = *(const u4v*)(Vl + row*128 + seg*8);
      *(u4v*)(att + ((size_t)(b*512 + bm + row))*512 + bn + seg*8) = v;
    }
    __syncthreads();
  }
}

// ---------- fused tail: out-proj + LN + ffn + softplus + add + LN (+ next LN) ----------
__global__ __launch_bounds__(256) void tail_kernel(
    const unsigned short* __restrict__ attb, const unsigned short* __restrict__ outT,
    const float* __restrict__ out_b,
    const unsigned short* __restrict__ ffnT, const float* __restrict__ ffn_b,
    float* __restrict__ x, unsigned short* __restrict__ xnb,
    const float* __restrict__ g1, const float* __restrict__ b1,
    const float* __restrict__ g2, const float* __restrict__ b2) {
  __shared__ char smem[81920];                            // 80 KB
  unsigned short* Al   = (unsigned short*)smem;           // [0,8K) gemm1 A
  unsigned short* Bl   = (unsigned short*)(smem+8192);    // [8K,24K) gemm1 B
  char* xnl  = smem;                                      // [0,16K) after gemm1
  char* ffnB = smem + 16384;                              // [16K,48K)
  float* vst = (float*)(smem + 49152);                    // [48K,80K) 64x128 f32
  const int bm = blockIdx.x*64;
  const int t = threadIdx.x, w = t>>6, l = t&63;
  const int wr = w>>1, wc = w&1;
  f4v acc[2][4];
  #pragma unroll
  for (int i=0;i<2;++i)
    #pragma unroll
    for (int j=0;j<4;++j) acc[i][j] = (f4v){0.f,0.f,0.f,0.f};
  const int srow = t>>3, sseg = t&7;
  for (int k0 = 0; k0 < 512; k0 += 64) {
    #pragma unroll
    for (int c=0;c<2;++c){
      int row = c*32 + srow;
      GLOAD16(attb + (size_t)(bm+row)*512 + k0 + ((sseg ^ (row&7))<<3),
              (char*)Al + c*4096 + w*1024);
    }
    #pragma unroll
    for (int c=0;c<4;++c){
      int row = c*32 + srow;
      GLOAD16(outT + (size_t)row*512 + k0 + ((sseg ^ (row&7))<<3),
              (char*)Bl + c*4096 + w*1024);
    }
    __syncthreads();
    #pragma unroll
    for (int ks=0;ks<2;++ks){
      s8v bf[4];
      #pragma unroll
      for (int ct=0;ct<4;++ct){
        int col = wc*64 + ct*16 + (l&15);
        bf[ct] = *(const s8v*)((const char*)Bl + col*128 + ((((l>>4)+ks*4) ^ (col&7))<<4));
      }
      #pragma unroll
      for (int rt=0;rt<2;++rt){
        int arow = wr*32 + rt*16 + (l&15);
        s8v af = *(const s8v*)((const char*)Al + arow*128 + ((((l>>4)+ks*4) ^ (arow&7))<<4));
        #pragma unroll
        for (int ct=0;ct<4;++ct)
          acc[rt][ct] = MFMA16(af, bf[ct], acc[rt][ct]);
      }
    }
    __syncthreads();
  }
  // stage ffn weights (async, lands before next barrier)
  #pragma unroll
  for (int kh=0;kh<2;++kh)
    #pragma unroll
    for (int c=0;c<4;++c){
      int row = c*32 + srow;
      GLOAD16(ffnT + (size_t)row*128 + kh*64 + ((sseg ^ (row&7))<<3),
              ffnB + kh*16384 + c*4096 + w*1024);
    }
  // epilogue1: o1 = acc + out_b + x  -> vst
  {
    float bia[4];
    #pragma unroll
    for (int ct=0;ct<4;++ct) bia[ct] = out_b[wc*64 + ct*16 + (l&15)];
    #pragma unroll
    for (int rt=0;rt<2;++rt)
      #pragma unroll
      for (int ct=0;ct<4;++ct)
        #pragma unroll
        for (int r=0;r<4;++r){
          int rr = wr*32 + rt*16 + (l>>4)*4 + r;
          int cc = wc*64 + ct*16 + (l&15);
          vst[rr*128 + cc] = acc[rt][ct][r] + bia[ct] + x[(size_t)(bm+rr)*128 + cc];
        }
  }
  __syncthreads();
  // LN1 -> xnl (swizzled bf16 A-layout)
  {
    const float2 g1v = *(const float2*)(g1 + l*2);
    const float2 b1v = *(const float2*)(b1 + l*2);
    for (int rr=0; rr<16; ++rr){
      int row = w*16 + rr;
      float2 vv = *(const float2*)&vst[row*128 + l*2];
      float s = vv.x+vv.y, sq = vv.x*vv.x + vv.y*vv.y;
      #pragma unroll
      for (int m=1;m<64;m<<=1){ s += __shfl_xor(s,m,64); sq += __shfl_xor(sq,m,64); }
      float mean = s*(1.f/128.f);
      float rstd = rsqrtf(sq*(1.f/128.f) - mean*mean + 1e-5f);
      float xa = (vv.x-mean)*rstd*g1v.x + b1v.x;
      float xb = (vv.y-mean)*rstd*g1v.y + b1v.y;
      int col = l*2;
      int byte = row*256 + (((col>>3) ^ (row&7))<<4) + ((col&7)<<1);
      unsigned int pk = (unsigned int)f2bf(xa) | ((unsigned int)f2bf(xb)<<16);
      *(unsigned int*)(xnl + byte) = pk;
    }
  }
  __syncthreads();
  // GEMM2: o2 = xn @ ffnT^T
  f4v acc2[2][4];
  #pragma unroll
  for (int i=0;i<2;++i)
    #pragma unroll
    for (int j=0;j<4;++j) acc2[i][j] = (f4v){0.f,0.f,0.f,0.f};
  #pragma unroll
  for (int ks2=0;ks2<4;++ks2){
    int kh = ks2>>1, ks = ks2&1;
    s8v bf[4];
    #pragma unroll
    for (int ct=0;ct<4;++ct){
      int col = wc*64 + ct*16 + (l&15);
      bf[ct] = *(const s8v*)(ffnB + kh*16384 + col*128 + ((((l>>4)+ks*4) ^ (col&7))<<4));
    }
    #pragma unroll
    for (int rt=0;rt<2;++rt){
      int arow = wr*32 + rt*16 + (l&15);
      s8v af = *(const s8v*)(xnl + arow*256 + ((((l>>4)+ks2*4) ^ (arow&7))<<4));
      #pragma unroll
      for (int ct=0;ct<4;++ct)
        acc2[rt][ct] = MFMA16(af, bf[ct], acc2[rt][ct]);
    }
  }
  // epilogue2: vst += softplus(acc2 + ffn_b)
  {
    float fb[4];
    #pragma unroll
    for (int ct=0;ct<4;++ct) fb[ct] = ffn_b[wc*64 + ct*16 + (l&15)];
    #pragma unroll
    for (int rt=0;rt<2;++rt)
      #pragma unroll
      for (int ct=0;ct<4;++ct)
        #pragma unroll
        for (int r=0;r<4;++r){
          int rr = wr*32 + rt*16 + (l>>4)*4 + r;
          int cc = wc*64 + ct*16 + (l&15);
          vst[rr*128 + cc] += softplus_f(acc2[rt][ct][r] + fb[ct]);
        }
  }
  __syncthreads();
  // LN2 -> x ; optional LN3 -> xnb
  {
    const float2 g1v = *(const float2*)(g1 + l*2);
    const float2 b1v = *(const float2*)(b1 + l*2);
    for (int rr=0; rr<16; ++rr){
      int row = w*16 + rr;
      float2 vv = *(const float2*)&vst[row*128 + l*2];
      float s = vv.x+vv.y, sq = vv.x*vv.x + vv.y*vv.y;
      #pragma unroll
      for (int m=1;m<64;m<<=1){ s += __shfl_xor(s,m,64); sq += __shfl_xor(sq,m,64); }
      float mean = s*(1.f/128.f);
      float rstd = rsqrtf(sq*(1.f/128.f) - mean*mean + 1e-5f);
      float xa = (vv.x-mean)*rstd*g1v.x + b1v.x;
      float xb = (vv.y-mean)*rstd*g1v.y + b1v.y;
      float2 xo; xo.x = xa; xo.y = xb;
      *(float2*)(x + (size_t)(bm+row)*128 + l*2) = xo;
      if (g2) {
        float s2 = xa+xb, sq2 = xa*xa + xb*xb;
        #pragma unroll
        for (int m=1;m<64;m<<=1){ s2 += __shfl_xor(s2,m,64); sq2 += __shfl_xor(sq2,m,64); }
        float mean2 = s2*(1.f/128.f);
        float rstd2 = rsqrtf(sq2*(1.f/128.f) - mean2*mean2 + 1e-5f);
        const float2 g2v = *(const float2*)(g2 + l*2);
        const float2 b2v = *(const float2*)(b2 + l*2);
        float ya = (xa-mean2)*rstd2*g2v.x + b2v.x;
        float yb = (xb-mean2)*rstd2*g2v.y + b2v.y;
        unsigned int pk = (unsigned int)f2bf(ya) | ((unsigned int)f2bf(yb)<<16);
        *(unsigned int*)(xnb + (size_t)(bm+row)*128 + l*2) = pk;
      }
    }
  }
}

// ---------- pooling (parallel partials) + final ----------
__global__ __launch_bounds__(128) void pool_part_kernel(const float* __restrict__ x,
    const float* __restrict__ x_init,
    const float* __restrict__ w_row, float* __restrict__ partial) {
  int b = blockIdx.x, p = blockIdx.y, e = threadIdx.x;
  float acc = 0.f;
  for (int n = p*64; n < p*64+64; ++n) {
    float w = w_row[(size_t)b*N_ + n];
    size_t o = ((size_t)b*N_ + n)*E_ + e;
    acc += w * (x[o] + x_init[o]);
  }
  partial[((size_t)b*8 + p)*E_ + e] = acc;
}

__global__ __launch_bounds__(128) void final_kernel(const float* __restrict__ partial,
    const float* __restrict__ g, const float* __restrict__ bt,
    const float* __restrict__ fw, const float* __restrict__ fb, float* __restrict__ out) {
  int b = blockIdx.x, t = threadIdx.x;
  float v = 0.f;
  for (int p=0;p<8;++p) v += partial[((size_t)b*8+p)*E_ + t];
  float s = v, sq = v*v;
  #pragma unroll
  for (int m = 1; m < 64; m <<= 1) { s += __shfl_xor(s, m, 64); sq += __shfl_xor(sq, m, 64); }
  __shared__ float red[4];
  int wv = t >> 6, ln = t & 63;
  if (ln == 0) { red[wv*2] = s; red[wv*2+1] = sq; }
  __syncthreads();
  s = red[0] + red[2]; sq = red[1] + red[3];
  float mean = s*(1.f/E_), var = sq*(1.f/E_) - mean*mean;
  float rstd = rsqrtf(var + 1e-5f);
  float xl = (v - mean)*rstd*g[t] + bt[t];
  float p = xl * fw[t];
  #pragma unroll
  for (int m = 1; m < 64; m <<= 1) p += __shfl_xor(p, m, 64);
  __shared__ float red2[2];
  if (ln == 0) red2[wv] = p;
  __syncthreads();
  if (t == 0) out[b] = red2[0] + red2[1] + fb[0];
}

extern "C" void kernel_launch(void* const* d_in, const int* in_sizes, int n_in,
                              void* d_out, int out_size, void* d_ws, size_t ws_size,
                              hipStream_t stream) {
  (void)in_sizes; (void)n_in; (void)out_size; (void)ws_size;
  const float* str_fea  = (const float*)d_in[0];
  const int*   comp_fea = (const int*)  d_in[1];
  const float* af_table = (const float*)d_in[3];
  const float* comp_w   = (const float*)d_in[4];
  const float* comp_b   = (const float*)d_in[5];
  const float* emb_w    = (const float*)d_in[6];
  const float* emb_b    = (const float*)d_in[7];
  const float* ln_g     = (const float*)d_in[8];
  const float* ln_b     = (const float*)d_in[9];
  const float* wq       = (const float*)d_in[10];
  const float* bq       = (const float*)d_in[11];
  const float* wk       = (const float*)d_in[12];
  const float* bk       = (const float*)d_in[13];
  const float* wv       = (const float*)d_in[14];
  const float* bv       = (const float*)d_in[15];
  const float* inproj_w = (const float*)d_in[16];
  const float* inproj_b = (const float*)d_in[17];
  const float* out_w    = (const float*)d_in[18];
  const float* out_b    = (const float*)d_in[19];
  const float* ffn_w    = (const float*)d_in[20];
  const float* ffn_b    = (const float*)d_in[21];
  const float* ln2_g    = (const float*)d_in[22];
  const float* ln2_b    = (const float*)d_in[23];
  const float* final_w  = (const float*)d_in[24];
  const float* final_b  = (const float*)d_in[25];
  float* out = (float*)d_out;

  float* ws = (float*)d_ws;
  size_t off = 0;
  float* x      = ws + off; off += 2097152;
  float* x_init = ws + off; off += 2097152;
  float* w_row  = ws + off; off += 16384;
  unsigned short* xnb  = (unsigned short*)(ws + off); off += 1048576;   // [M][128]
  unsigned short* qkb  = (unsigned short*)(ws + off); off += 8388608;   // [M][1024]
  unsigned short* vTb  = (unsigned short*)(ws + off); off += 4194304;   // [B][512][512]
  unsigned short* attb = (unsigned short*)(ws + off); off += 4194304;   // [M][512]
  unsigned short* Pb   = (unsigned short*)(ws + off); off += 16777216;  // [B][H][512][512]
  float* Sinvb  = ws + off; off += 65536;
  float* rhob   = ws + off; off += 65536;
  float* part   = ws + off; off += 24576;    // [6][8][512]
  float* effpart= ws + off; off += 3145728;  // [8][6][8][64][128] f32 = 12.6 MB
  float* bqkv   = ws + off; off += 4608;
  unsigned short* wqkvT = (unsigned short*)(ws + off); off += 294912;   // [3][1536][128]
  unsigned short* outT  = (unsigned short*)(ws + off); off += 98304;    // [3][128][512]
  unsigned short* ffnT  = (unsigned short*)(ws + off); off += 24576;    // [3][128][128]
  unsigned short* FHi   = (unsigned short*)(ws + off); off += 2621440;  // [M][320]
  unsigned short* FLo   = (unsigned short*)(ws + off); off += 2621440;
  unsigned short* WHi   = (unsigned short*)(ws + off); off += 20480;    // [128][320]
  unsigned short* WLo   = (unsigned short*)(ws + off); off += 20480;
  float* biasE  = ws + off; off += 128;
  float* Cpart  = ws + off; off += 1280;
  float* partial= ws + off; off += 32768;

  effb_part_kernel<<<dim3(6,8), 256, 0, stream>>>(bq, bk, inproj_w, part);
  effp_kernel<<<dim3(48,8), 256, 0, stream>>>(wq, wk, inproj_w, effpart);
  effred_kernel<<<1536, 256, 0, stream>>>(effpart, wqkvT);
  wtrans_kernel<<<126, 256, 0, stream>>>(wv, out_w, ffn_w, inproj_b, bv, part,
                                         wqkvT, outT, ffnT, bqkv);
  embW1_kernel<<<12, 128, 0, stream>>>(emb_w, comp_w, WHi, WLo, Cpart);
  embBias_kernel<<<1, 128, 0, stream>>>(Cpart, comp_b, emb_b, biasE);
  feat_kernel<<<M_*40/256, 256, 0, stream>>>(str_fea, comp_fea, af_table, FHi, FLo, w_row);
  embgemm_kernel<<<M_/64, 256, 0, stream>>>(FHi, FLo, WHi, WLo, biasE,
                                            ln_g, ln_b, x, x_init, xnb);

  for (int l = 0; l < L_; ++l) {
    mgemm_kernel<4><<<dim3(M_/128, 12), 256, 0, stream>>>(
        xnb, wqkvT + (size_t)l*196608, bqkv + l*1536, qkb, vTb, 128);
    attnA_kernel<<<dim3(8, 4, 32), 256, 0, stream>>>(qkb, w_row, Pb, Sinvb, rhob);
    attnPV_kernel<<<dim3(16, 32), 256, 0, stream>>>(Pb, Sinvb, rhob, vTb, w_row, attb);
    tail_kernel<<<M_/64, 256, 0, stream>>>(
        attb, outT + (size_t)l*65536, out_b + (size_t)l*E_,
        ffnT + (size_t)l*16384, ffn_b + (size_t)l*E_,
        x, xnb, ln_g + l*E_, ln_b + l*E_,
        (l < 2) ? (ln_g + (l+1)*E_) : nullptr,
        (l < 2) ? (ln_b + (l+1)*E_) : nullptr);
  }

  pool_part_kernel<<<dim3(B_, 8), 128, 0, stream>>>(x, x_init, w_row, partial);
  final_kernel<<<B_, 128, 0, stream>>>(partial, ln2_g, ln2_b, final_w, final_b, out);
}

// Round 7
// 403.650 us; speedup vs baseline: 8.6513x; 1.1099x over previous
//
#include <hip/hip_runtime.h>
#include <math.h>

#define B_ 32
#define N_ 512
#define F_ 101
#define E_ 128
#define H_ 4
#define EH_ 512
#define L_ 3
#define M_ (B_*N_)   // 16384

typedef __attribute__((ext_vector_type(8))) short s8v;
typedef __attribute__((ext_vector_type(8))) unsigned short us8v;
typedef __attribute__((ext_vector_type(4))) float f4v;
typedef __attribute__((ext_vector_type(4))) unsigned int u4v;

__device__ __forceinline__ unsigned short f2bf(float f){
  unsigned int u = __builtin_bit_cast(unsigned int, f);
  u += 0x7fffu + ((u>>16)&1u);
  return (unsigned short)(u>>16);
}
__device__ __forceinline__ float bf2f(unsigned int h){
  unsigned int u = h<<16; return __builtin_bit_cast(float, u);
}
__device__ __forceinline__ float softplus_f(float v) {
  return fmaxf(v, 0.f) + log1pf(__expf(-fabsf(v)));
}

#define GLOAD16(gp, lp) __builtin_amdgcn_global_load_lds( \
    (__attribute__((address_space(1))) unsigned int*)(gp), \
    (__attribute__((address_space(3))) unsigned int*)(lp), 16, 0, 0)

#define MFMA16(a,b,c) __builtin_amdgcn_mfma_f32_16x16x32_bf16(a,b,c,0,0,0)

// ---------- eff fold partials: split-K, 384 blocks ----------
__global__ __launch_bounds__(256) void effp_kernel(
    const float* __restrict__ wq, const float* __restrict__ wk,
    const float* __restrict__ inproj_w, float* __restrict__ part) {
  __shared__ float As[64][132];   // [kk][r]
  __shared__ float Bs[64][68];    // [kk][c]
  const int blk = blockIdx.x;     // 48 = 6 lq * 8 ntiles
  const int ks = blockIdx.y;      // 8 K-chunks of 64
  const int lq = blk>>3, nt = blk&7;
  const int l = lq>>1, qk = lq&1;
  const int bn = nt*64;
  const int k0 = ks*64;
  const float* A = (qk ? wk : wq) + (size_t)l*128*512;
  const float* IP = inproj_w + (size_t)l*512*1536 + qk*512 + bn;
  const int t = threadIdx.x;
  float acc[8][4];
  #pragma unroll
  for (int i=0;i<8;++i)
    #pragma unroll
    for (int j=0;j<4;++j) acc[i][j]=0.f;
  const int r0 = (t&15)*8, c0 = (t>>4)*4;
  {
    int r = t & 127, half = t>>7;
    #pragma unroll
    for (int u=0;u<8;++u){
      float4 a = *(const float4*)(A + (size_t)r*512 + k0 + half*32 + u*4);
      int kk = half*32 + u*4;
      As[kk+0][r]=a.x; As[kk+1][r]=a.y; As[kk+2][r]=a.z; As[kk+3][r]=a.w;
    }
    int kk = t>>2, cb = (t&3)*16;
    #pragma unroll
    for (int u=0;u<4;++u)
      *(float4*)&Bs[kk][cb+u*4] = *(const float4*)(IP + (size_t)(k0+kk)*1536 + cb + u*4);
  }
  __syncthreads();
  for (int k2=0;k2<64;++k2){
    float4 b = *(const float4*)&Bs[k2][c0];
    float4 a0 = *(const float4*)&As[k2][r0];
    float4 a1 = *(const float4*)&As[k2][r0+4];
    float av[8] = {a0.x,a0.y,a0.z,a0.w,a1.x,a1.y,a1.z,a1.w};
    #pragma unroll
    for (int i=0;i<8;++i){
      acc[i][0] += av[i]*b.x; acc[i][1] += av[i]*b.y;
      acc[i][2] += av[i]*b.z; acc[i][3] += av[i]*b.w;
    }
  }
  #pragma unroll
  for (int j=0;j<4;++j){
    float* dst = part + (((size_t)ks*48 + blk)*64 + c0 + j)*128 + r0;
    float4 v0 = {acc[0][j], acc[1][j], acc[2][j], acc[3][j]};
    float4 v1 = {acc[4][j], acc[5][j], acc[6][j], acc[7][j]};
    *(float4*)dst = v0;
    *(float4*)(dst+4) = v1;
  }
}

// ---------- reduce 8 partials -> bf16 wqkvT ----------
__global__ __launch_bounds__(256) void effred_kernel(
    const float* __restrict__ part, unsigned short* __restrict__ wqkvT) {
  int idx = blockIdx.x*256 + threadIdx.x;   // 6*512*128 = 393216
  int m = idx & 127;
  int n = (idx>>7) & 511;
  int lq = idx >> 16;
  int l = lq>>1, qk = lq&1;
  size_t base = (((size_t)(lq*8 + (n>>6)))*64 + (n&63))*128 + m;
  float v = 0.f;
  #pragma unroll
  for (int ks=0;ks<8;++ks) v += part[(size_t)ks*393216 + base];
  wqkvT[((size_t)l*1536 + qk*512 + n)*128 + m] = f2bf(v);
}

// ---------- eff bias partials: part[lq][kt][512] ----------
__global__ __launch_bounds__(256) void effb_part_kernel(
    const float* __restrict__ bq, const float* __restrict__ bk,
    const float* __restrict__ inproj_w, float* __restrict__ part) {
  const int lq = blockIdx.x, kt = blockIdx.y;   // 6 x 8
  const int l = lq>>1, qk = lq&1;
  const float* bv = (qk?bk:bq) + l*512 + kt*64;
  const float* IP = inproj_w + ((size_t)l*512 + kt*64)*1536 + qk*512;
  const int t = threadIdx.x;
  float a0=0.f, a1=0.f;
  for (int kk=0; kk<64; ++kk){
    float b = bv[kk];
    const float* row = IP + (size_t)kk*1536;
    a0 += b*row[t];
    a1 += b*row[t+256];
  }
  part[(lq*8+kt)*512 + t]       = a0;
  part[(lq*8+kt)*512 + t + 256] = a1;
}

// ---------- weight transposes (LDS-tiled) + bqkv assembly ----------
__global__ __launch_bounds__(256) void wtrans_kernel(
    const float* __restrict__ wv, const float* __restrict__ out_w,
    const float* __restrict__ ffn_w,
    const float* __restrict__ inproj_b, const float* __restrict__ bvv,
    const float* __restrict__ part,
    unsigned short* __restrict__ wqkvT, unsigned short* __restrict__ outT,
    unsigned short* __restrict__ ffnT, float* __restrict__ bqkv) {
  const int blk = blockIdx.x;   // 0..125
  const int t = threadIdx.x;
  if (blk < 108) {
    __shared__ float tile[64][65];
    const float* src; unsigned short* dst; int srcld, dstld;
    if (blk < 48) {              // wv [3][128][512] -> wqkvT v-part [n][k]
      int lay = blk/16, rem = blk%16, kt = rem>>3, nt = rem&7;
      src = wv + ((size_t)lay*128 + kt*64)*512 + nt*64; srcld = 512;
      dst = wqkvT + ((size_t)lay*1536 + 1024 + nt*64)*128 + kt*64; dstld = 128;
    } else if (blk < 96) {       // out_w [3][512][128] -> outT [n][k]
      int b2 = blk-48; int lay = b2/16, rem = b2%16, kt = rem>>1, nt = rem&1;
      src = out_w + ((size_t)lay*512 + kt*64)*128 + nt*64; srcld = 128;
      dst = outT + ((size_t)lay*128 + nt*64)*512 + kt*64; dstld = 512;
    } else {                     // ffn_w [3][128][128] -> ffnT [n][k]
      int b3 = blk-96; int lay = b3/4, rem = b3%4, kt = rem>>1, nt = rem&1;
      src = ffn_w + ((size_t)lay*128 + kt*64)*128 + nt*64; srcld = 128;
      dst = ffnT + ((size_t)lay*128 + nt*64)*128 + kt*64; dstld = 128;
    }
    #pragma unroll
    for (int rp=0; rp<4; ++rp){
      int r = rp*16 + (t>>4), c = (t&15)*4;
      float4 v = *(const float4*)(src + (size_t)r*srcld + c);
      tile[r][c+0]=v.x; tile[r][c+1]=v.y; tile[r][c+2]=v.z; tile[r][c+3]=v.w;
    }
    __syncthreads();
    #pragma unroll
    for (int wp=0; wp<2; ++wp){
      int n = wp*32 + (t>>3), kk = (t&7)*8;
      us8v pk;
      #pragma unroll
      for (int e=0;e<8;++e) pk[e] = f2bf(tile[kk+e][n]);
      *(us8v*)(dst + (size_t)n*dstld + kk) = pk;
    }
  } else {
    int idx = (blk-108)*256 + t;          // 0..4607
    int l = idx/1536, n = idx - l*1536;
    float v;
    if (n < 1024) {
      int qk = n>>9, c = n&511;
      v = inproj_b[(size_t)l*1536 + n];
      #pragma unroll
      for (int kt=0;kt<8;++kt) v += part[((l*2+qk)*8+kt)*512 + c];
    } else {
      v = bvv[(size_t)l*512 + (n-1024)];
    }
    bqkv[idx] = v;
  }
}

// ---------- embed weight prep ----------
__global__ __launch_bounds__(128) void embW1_kernel(
    const float* __restrict__ emb_w, const float* __restrict__ comp_w,
    unsigned short* __restrict__ WHi, unsigned short* __restrict__ WLo,
    float* __restrict__ Cpart) {
  int p = blockIdx.x, e = threadIdx.x;
  if (p < 10) {
    float Cp = 0.f;
    for (int ff=0; ff<10; ++ff){
      int f = p*10+ff;
      float A=0.f, Bv=0.f;
      #pragma unroll
      for (int s=0;s<10;++s){
        float wv = emb_w[(size_t)(f*10+s)*128 + e];
        A += wv; Bv += 0.2f*s*wv; Cp += 0.01f*(s*s)*wv;
      }
      int kA = 92+f, kB = 192+f;
      unsigned short hA = f2bf(A);
      WHi[e*320+kA]=hA; WLo[e*320+kA]=f2bf(A - bf2f(hA));
      unsigned short hB = f2bf(Bv);
      WHi[e*320+kB]=hB; WLo[e*320+kB]=f2bf(Bv - bf2f(hB));
    }
    Cpart[p*128+e] = Cp;
  } else if (p == 10) {
    for (int kk=0;kk<92;++kk){
      float v = comp_w[(size_t)kk*128 + e];
      unsigned short h = f2bf(v);
      WHi[e*320+kk]=h; WLo[e*320+kk]=f2bf(v - bf2f(h));
    }
  } else {
    for (int kk=292;kk<320;++kk){ WHi[e*320+kk]=0; WLo[e*320+kk]=0; }
  }
}

__global__ __launch_bounds__(128) void embBias_kernel(
    const float* __restrict__ Cpart, const float* __restrict__ comp_b,
    const float* __restrict__ emb_b, float* __restrict__ biasE){
  int e = threadIdx.x; float c=0.f;
  for (int p=0;p<10;++p) c += Cpart[p*128+e];
  biasE[e] = comp_b[e] + emb_b[e] + c;
}

// ---------- feature builder (coalesced) ----------
__global__ __launch_bounds__(256) void feat_kernel(
    const float* __restrict__ str_fea, const int* __restrict__ comp_fea,
    const float* __restrict__ af_table,
    unsigned short* __restrict__ FHi, unsigned short* __restrict__ FLo,
    float* __restrict__ w_row) {
  int g = blockIdx.x*256 + threadIdx.x;      // M*40 = 655360
  int row = g / 40, seg = g - row*40;
  const float* sr = str_fea + (size_t)row*F_;
  if (seg == 0) w_row[row] = sr[0];
  const float* af = af_table + (size_t)comp_fea[row]*92;
  const int c0 = seg*8;
  us8v hi, lo;
  #pragma unroll
  for (int e=0;e<8;++e){
    int kk = c0+e; float v;
    if (kk < 92) v = af[kk];
    else if (kk < 192) { float u = 1.f - sr[1+kk-92]; v = u*u; }
    else if (kk < 292) v = 1.f - sr[1+kk-192];
    else v = 0.f;
    unsigned short h = f2bf(v);
    hi[e] = h; lo[e] = f2bf(v - bf2f(h));
  }
  *(us8v*)(FHi + (size_t)row*320 + c0) = hi;
  *(us8v*)(FLo + (size_t)row*320 + c0) = lo;
}

// ---------- embed GEMM (split bf16, 3-MFMA) + LN0 epilogue ----------
__global__ __launch_bounds__(256) void embgemm_kernel(
    const unsigned short* __restrict__ FHi, const unsigned short* __restrict__ FLo,
    const unsigned short* __restrict__ WHi, const unsigned short* __restrict__ WLo,
    const float* __restrict__ biasE,
    const float* __restrict__ g0, const float* __restrict__ b0,
    float* __restrict__ x, float* __restrict__ x_init,
    unsigned short* __restrict__ xnb) {
  __shared__ unsigned short lds[24576];    // 48 KB
  unsigned short* AHi = lds;
  unsigned short* ALo = lds + 4096;
  unsigned short* BHi = lds + 8192;
  unsigned short* BLo = lds + 16384;
  const int bm = blockIdx.x*64;
  const int t = threadIdx.x, w = t>>6, l = t&63;
  f4v acc[8];
  #pragma unroll
  for (int i=0;i<8;++i) acc[i] = (f4v){0.f,0.f,0.f,0.f};
  const int srow = t>>3, sseg = t&7;
  for (int k0=0;k0<320;k0+=64){
    #pragma unroll
    for (int c=0;c<2;++c){
      int row = c*32+srow;
      GLOAD16(FHi + (size_t)(bm+row)*320 + k0 + ((sseg^(row&7))<<3), (char*)AHi + c*4096 + w*1024);
      GLOAD16(FLo + (size_t)(bm+row)*320 + k0 + ((sseg^(row&7))<<3), (char*)ALo + c*4096 + w*1024);
    }
    #pragma unroll
    for (int c=0;c<4;++c){
      int row = c*32+srow;
      GLOAD16(WHi + (size_t)row*320 + k0 + ((sseg^(row&7))<<3), (char*)BHi + c*4096 + w*1024);
      GLOAD16(WLo + (size_t)row*320 + k0 + ((sseg^(row&7))<<3), (char*)BLo + c*4096 + w*1024);
    }
    __syncthreads();
    #pragma unroll
    for (int ks=0;ks<2;++ks){
      int arow = w*16 + (l&15);
      int aswz = ((((l>>4)+ks*4) ^ (arow&7))<<4);
      s8v ah = *(const s8v*)((const char*)AHi + arow*128 + aswz);
      s8v al = *(const s8v*)((const char*)ALo + arow*128 + aswz);
      #pragma unroll
      for (int ct=0;ct<8;++ct){
        int col = ct*16 + (l&15);
        int bswz = ((((l>>4)+ks*4) ^ (col&7))<<4);
        s8v bh = *(const s8v*)((const char*)BHi + col*128 + bswz);
        s8v bl = *(const s8v*)((const char*)BLo + col*128 + bswz);
        acc[ct] = MFMA16(ah, bh, acc[ct]);
        acc[ct] = MFMA16(ah, bl, acc[ct]);
        acc[ct] = MFMA16(al, bh, acc[ct]);
      }
    }
    __syncthreads();
  }
  float vv[8][4], gc[8], bc[8];
  #pragma unroll
  for (int ct=0;ct<8;++ct){
    int c = ct*16 + (l&15);
    float be = biasE[c]; gc[ct] = g0[c]; bc[ct] = b0[c];
    #pragma unroll
    for (int r=0;r<4;++r) vv[ct][r] = acc[ct][r] + be;
  }
  #pragma unroll
  for (int r=0;r<4;++r){
    float s=0.f, sq=0.f;
    #pragma unroll
    for (int ct=0;ct<8;++ct){ s += vv[ct][r]; sq += vv[ct][r]*vv[ct][r]; }
    #pragma unroll
    for (int m=1;m<16;m<<=1){ s += __shfl_xor(s,m,64); sq += __shfl_xor(sq,m,64); }
    float mean = s*(1.f/128.f);
    float rstd = rsqrtf(sq*(1.f/128.f) - mean*mean + 1e-5f);
    int row = bm + w*16 + (l>>4)*4 + r;
    #pragma unroll
    for (int ct=0;ct<8;++ct){
      int c = ct*16 + (l&15);
      float v = vv[ct][r];
      x[(size_t)row*128 + c] = v;
      x_init[(size_t)row*128 + c] = v;
      xnb[(size_t)row*128 + c] = f2bf((v-mean)*rstd*gc[ct] + bc[ct]);
    }
  }
}

// ---------- bf16 MFMA GEMM (qkv): bf16 out -> qkb (n<1024) or transposed vT ----------
template<int RT>
__global__ __launch_bounds__(256) void mgemm_kernel(
    const unsigned short* __restrict__ A,
    const unsigned short* __restrict__ Bt,
    const float* __restrict__ bias,
    unsigned short* __restrict__ Cb,
    unsigned short* __restrict__ vT,
    int K) {
  constexpr int BM = RT*32;
  __shared__ float smem[8192];   // 32 KB
  unsigned short* Al = (unsigned short*)smem;
  unsigned short* Bl = Al + BM*64;
  const int bm = blockIdx.x*BM;
  const int bn = blockIdx.y*128;
  const int t = threadIdx.x;
  const int w = t>>6, l = t&63;
  const int wr = w>>1, wc = w&1;
  f4v acc[RT][4];
  #pragma unroll
  for (int i=0;i<RT;++i)
    #pragma unroll
    for (int j=0;j<4;++j) acc[i][j] = (f4v){0.f,0.f,0.f,0.f};
  const int srow = t>>3, sseg = t&7;
  for (int k0 = 0; k0 < K; k0 += 64) {
    #pragma unroll
    for (int c=0;c<BM/32;++c){
      int row = c*32 + srow;
      GLOAD16(A + (size_t)(bm+row)*K + k0 + ((sseg ^ (row&7))<<3),
              (char*)Al + c*4096 + w*1024);
    }
    #pragma unroll
    for (int c=0;c<4;++c){
      int row = c*32 + srow;
      GLOAD16(Bt + (size_t)(bn+row)*K + k0 + ((sseg ^ (row&7))<<3),
              (char*)Bl + c*4096 + w*1024);
    }
    __syncthreads();
    #pragma unroll
    for (int ks=0;ks<2;++ks){
      s8v bf[4];
      #pragma unroll
      for (int ct=0;ct<4;++ct){
        int col = wc*64 + ct*16 + (l&15);
        bf[ct] = *(const s8v*)((const char*)Bl + col*128 + ((((l>>4)+ks*4) ^ (col&7))<<4));
      }
      #pragma unroll
      for (int rt=0;rt<RT;++rt){
        int arow = wr*(RT*16) + rt*16 + (l&15);
        s8v af = *(const s8v*)((const char*)Al + arow*128 + ((((l>>4)+ks*4) ^ (arow&7))<<4));
        #pragma unroll
        for (int ct=0;ct<4;++ct)
          acc[rt][ct] = MFMA16(af, bf[ct], acc[rt][ct]);
      }
    }
    __syncthreads();
  }
  float bia[4];
  #pragma unroll
  for (int ct=0;ct<4;++ct) bia[ct] = bias[bn + wc*64 + ct*16 + (l&15)];
  unsigned short* lds16 = (unsigned short*)smem;
  if (bn < 1024) {
    #pragma unroll
    for (int rt=0;rt<RT;++rt)
      #pragma unroll
      for (int ct=0;ct<4;++ct)
        #pragma unroll
        for (int r=0;r<4;++r){
          int rr = wr*(RT*16) + rt*16 + (l>>4)*4 + r;
          int cc = wc*64 + ct*16 + (l&15);
          lds16[rr*128 + cc] = f2bf(acc[rt][ct][r] + bia[ct]);
        }
    __syncthreads();
    #pragma unroll
    for (int it=0; it<BM/16; ++it){
      int row = it*16 + (t>>4), seg = t&15;
      u4v v = *(const u4v*)(lds16 + row*128 + seg*8);
      *(u4v*)(Cb + (size_t)(bm+row)*1024 + bn + seg*8) = v;
    }
  } else {
    #pragma unroll
    for (int rt=0;rt<RT;++rt)
      #pragma unroll
      for (int ct=0;ct<4;++ct){
        int rbase = bm + wr*(RT*16) + rt*16 + (l>>4)*4;
        int bb = rbase >> 9, nn = rbase & 511;
        int d = bn - 1024 + wc*64 + ct*16 + (l&15);
        unsigned int lo = (unsigned int)f2bf(acc[rt][ct][0] + bia[ct])
                        | ((unsigned int)f2bf(acc[rt][ct][1] + bia[ct])<<16);
        unsigned int hi = (unsigned int)f2bf(acc[rt][ct][2] + bia[ct])
                        | ((unsigned int)f2bf(acc[rt][ct][3] + bia[ct])<<16);
        uint2 pk; pk.x = lo; pk.y = hi;
        *(uint2*)(vT + ((size_t)(bb*512 + d))*512 + nn) = pk;
      }
  }
}

// ---------- fused attention: no P materialization (recompute QK in pass 2) ----------
// grid 256 (flat, XCD-mapped), 512 threads (8 waves: wi = w&3 i-group, wd = w>>2)
__global__ __launch_bounds__(512, 2) void attnF_kernel(
    const unsigned short* __restrict__ qkb, const unsigned short* __restrict__ vT,
    const float* __restrict__ w_row, unsigned short* __restrict__ att) {
  __shared__ char smem[147712];
  char* KV4   = smem;                         // 64 KB: K-tile [64j][512] (4 heads)
  char* Vl    = smem + 65536;                 // 64 KB: V-tile [512d][64j] / att staging
  char* cA    = smem + 131072;                // 8 KB: c-tile [64i][64j] bf16 swizzled
  float* w_s  = (float*)(smem + 139264);      // 512
  float* Spart= (float*)(smem + 141312);      // [2][4][64]
  float* Rpart= (float*)(smem + 143360);      // [2][4][64]
  float* sinv_l=(float*)(smem + 145408);      // [4][64]
  float* rho_l= (float*)(smem + 146432);      // [4][64]
  float* zinv_l=(float*)(smem + 147456);      // [64]

  const int id = blockIdx.x;
  const int b  = (id & 7) | ((id >> 6) << 3);
  const int i0 = ((id >> 3) & 7) * 64;
  const int t = threadIdx.x, w = t>>6, l = t&63;
  const int wi = w & 3, wd = w >> 2;
  const float SC = 0.088388347648318447f;   // 1/sqrt(128)

  for (int j=t; j<512; j+=512) w_s[j] = w_row[b*512+j];

  // Q fragments for all 4 heads (A-operand), rows i = i0 + wi*16 + (l&15)
  s8v qf[4][4];
  {
    const unsigned short* qbase = qkb + ((size_t)(b*512 + i0 + wi*16 + (l&15)))*1024;
    #pragma unroll
    for (int h=0;h<4;++h)
      #pragma unroll
      for (int ks=0;ks<4;++ks)
        qf[h][ks] = *(const s8v*)(qbase + h*128 + ks*32 + (l>>4)*8);
  }

  // ---- pass 1: S_h and rho_h ----
  float sp[4][4], rp[4][4];
  #pragma unroll
  for (int h=0;h<4;++h)
    #pragma unroll
    for (int r=0;r<4;++r){ sp[h][r]=0.f; rp[h][r]=0.f; }
  __syncthreads();
  #pragma unroll 1
  for (int j0=0;j0<512;j0+=64){
    #pragma unroll
    for (int c=0;c<8;++c){
      int row = c*8 + w;
      GLOAD16(qkb + (size_t)(b*512 + j0 + row)*1024 + 512 + ((l ^ (row&7))<<3),
              KV4 + c*8192 + w*1024);
    }
    __syncthreads();
    #pragma unroll
    for (int h=0;h<4;++h){
      #pragma unroll
      for (int jt=0;jt<2;++jt){
        int jcol = wd*32 + jt*16 + (l&15);
        f4v a = (f4v){0.f,0.f,0.f,0.f};
        #pragma unroll
        for (int ks=0;ks<4;++ks){
          int g = h*16 + ks*4 + (l>>4);
          s8v kf = *(const s8v*)(KV4 + jcol*1024 + ((g ^ (jcol&7))<<4));
          a = MFMA16(qf[h][ks], kf, a);
        }
        float wv = w_s[j0 + jcol];
        float mw = (wv != 0.f) ? 1.f : 0.f;
        #pragma unroll
        for (int r=0;r<4;++r){
          float e = __expf(a[r]*SC);
          sp[h][r] += e*mw;
          rp[h][r] += e*wv;
        }
      }
    }
    __syncthreads();
  }
  // reduce S,rho within 16-lane groups, combine wd halves via LDS
  #pragma unroll
  for (int h=0;h<4;++h)
    #pragma unroll
    for (int r=0;r<4;++r){
      float s = sp[h][r], rv = rp[h][r];
      s += __shfl_xor(s,1,64); rv += __shfl_xor(rv,1,64);
      s += __shfl_xor(s,2,64); rv += __shfl_xor(rv,2,64);
      s += __shfl_xor(s,4,64); rv += __shfl_xor(rv,4,64);
      s += __shfl_xor(s,8,64); rv += __shfl_xor(rv,8,64);
      sp[h][r] = s; rp[h][r] = rv;
    }
  if ((l&15)==0){
    int i = wi*16 + (l>>4)*4;
    #pragma unroll
    for (int h=0;h<4;++h)
      #pragma unroll
      for (int r=0;r<4;++r){
        Spart[(wd*4+h)*64 + i + r] = sp[h][r];
        Rpart[(wd*4+h)*64 + i + r] = rp[h][r];
      }
  }
  __syncthreads();
  if (t < 256){
    int h = t>>6, i = t&63;
    float S = Spart[h*64+i] + Spart[(4+h)*64+i];
    float R = Rpart[h*64+i] + Rpart[(4+h)*64+i];
    float si = 1.f/S;
    sinv_l[h*64+i] = si;
    rho_l[h*64+i]  = R*si;
  }
  __syncthreads();
  if (t < 64)
    zinv_l[t] = 1.f/(rho_l[t] + rho_l[64+t] + rho_l[128+t] + rho_l[192+t]);
  __syncthreads();

  float siv[4][4], zv[4];
  {
    int ib = wi*16 + (l>>4)*4;
    #pragma unroll
    for (int h=0;h<4;++h)
      #pragma unroll
      for (int r=0;r<4;++r) siv[h][r] = sinv_l[h*64 + ib + r];
    #pragma unroll
    for (int r=0;r<4;++r) zv[r] = zinv_l[ib + r];
  }

  // ---- pass 2: recompute QK, combine, PV ----
  f4v pacc[16];
  #pragma unroll
  for (int ct=0;ct<16;++ct) pacc[ct] = (f4v){0.f,0.f,0.f,0.f};
  #pragma unroll 1
  for (int j0=0;j0<512;j0+=64){
    #pragma unroll
    for (int c=0;c<8;++c){
      int row = c*8 + w;
      GLOAD16(qkb + (size_t)(b*512 + j0 + row)*1024 + 512 + ((l ^ (row&7))<<3),
              KV4 + c*8192 + w*1024);
    }
    #pragma unroll
    for (int c=0;c<8;++c){
      int d = c*64 + (t>>3);
      GLOAD16(vT + ((size_t)(b*512 + d))*512 + j0 + (((t&7) ^ (d&7))<<3),
              Vl + c*8192 + w*1024);
    }
    __syncthreads();
    float cacc[2][4];
    #pragma unroll
    for (int jt=0;jt<2;++jt)
      #pragma unroll
      for (int r=0;r<4;++r) cacc[jt][r] = 0.f;
    #pragma unroll
    for (int h=0;h<4;++h){
      #pragma unroll
      for (int jt=0;jt<2;++jt){
        int jcol = wd*32 + jt*16 + (l&15);
        f4v a = (f4v){0.f,0.f,0.f,0.f};
        #pragma unroll
        for (int ks=0;ks<4;++ks){
          int g = h*16 + ks*4 + (l>>4);
          s8v kf = *(const s8v*)(KV4 + jcol*1024 + ((g ^ (jcol&7))<<4));
          a = MFMA16(qf[h][ks], kf, a);
        }
        #pragma unroll
        for (int r=0;r<4;++r)
          cacc[jt][r] += __expf(a[r]*SC) * siv[h][r];
      }
    }
    #pragma unroll
    for (int jt=0;jt<2;++jt){
      int jcol = wd*32 + jt*16 + (l&15);
      float wv = w_s[j0 + jcol];
      #pragma unroll
      for (int r=0;r<4;++r){
        int i = wi*16 + (l>>4)*4 + r;
        int byte = i*128 + (((jcol>>3) ^ (i&7))<<4) + ((jcol&7)<<1);
        *(unsigned short*)(cA + byte) = f2bf(cacc[jt][r]*wv);
      }
    }
    __syncthreads();
    #pragma unroll
    for (int ks=0;ks<2;++ks){
      int kidx = (l>>4) + ks*4;
      int arow = wi*16 + (l&15);
      s8v af = *(const s8v*)(cA + arow*128 + ((kidx ^ (arow&7))<<4));
      #pragma unroll
      for (int ct=0;ct<16;++ct){
        int d = wd*256 + ct*16 + (l&15);
        s8v vf = *(const s8v*)(Vl + d*128 + ((kidx ^ (d&7))<<4));
        pacc[ct] = MFMA16(af, vf, pacc[ct]);
      }
    }
    __syncthreads();
  }

  // epilogue: scale by 1/Z, stage to LDS, coalesced store
  unsigned short* outL = (unsigned short*)Vl;
  #pragma unroll
  for (int ct=0;ct<16;++ct){
    int d = wd*256 + ct*16 + (l&15);
    #pragma unroll
    for (int r=0;r<4;++r){
      int i = wi*16 + (l>>4)*4 + r;
      outL[i*512 + d] = f2bf(pacc[ct][r]*zv[r]);
    }
  }
  __syncthreads();
  #pragma unroll
  for (int c=0;c<8;++c){
    int idx = c*512 + t;
    int row = idx>>6, seg = idx&63;
    u4v v = *(const u4v*)(outL + row*512 + seg*8);
    *(u4v*)(att + ((size_t)(b*512 + i0 + row))*512 + seg*8) = v;
  }
}

// ---------- fused tail: out-proj + LN + ffn + softplus + add + LN (+ next LN) ----------
__global__ __launch_bounds__(256) void tail_kernel(
    const unsigned short* __restrict__ attb, const unsigned short* __restrict__ outT,
    const float* __restrict__ out_b,
    const unsigned short* __restrict__ ffnT, const float* __restrict__ ffn_b,
    float* __restrict__ x, unsigned short* __restrict__ xnb,
    const float* __restrict__ g1, const float* __restrict__ b1,
    const float* __restrict__ g2, const float* __restrict__ b2) {
  __shared__ char smem[81920];                            // 80 KB
  unsigned short* Al   = (unsigned short*)smem;           // [0,8K) gemm1 A
  unsigned short* Bl   = (unsigned short*)(smem+8192);    // [8K,24K) gemm1 B
  char* xnl  = smem;                                      // [0,16K) after gemm1
  char* ffnB = smem + 16384;                              // [16K,48K)
  float* vst = (float*)(smem + 49152);                    // [48K,80K) 64x128 f32
  const int bm = blockIdx.x*64;
  const int t = threadIdx.x, w = t>>6, l = t&63;
  const int wr = w>>1, wc = w&1;
  f4v acc[2][4];
  #pragma unroll
  for (int i=0;i<2;++i)
    #pragma unroll
    for (int j=0;j<4;++j) acc[i][j] = (f4v){0.f,0.f,0.f,0.f};
  const int srow = t>>3, sseg = t&7;
  for (int k0 = 0; k0 < 512; k0 += 64) {
    #pragma unroll
    for (int c=0;c<2;++c){
      int row = c*32 + srow;
      GLOAD16(attb + (size_t)(bm+row)*512 + k0 + ((sseg ^ (row&7))<<3),
              (char*)Al + c*4096 + w*1024);
    }
    #pragma unroll
    for (int c=0;c<4;++c){
      int row = c*32 + srow;
      GLOAD16(outT + (size_t)row*512 + k0 + ((sseg ^ (row&7))<<3),
              (char*)Bl + c*4096 + w*1024);
    }
    __syncthreads();
    #pragma unroll
    for (int ks=0;ks<2;++ks){
      s8v bf[4];
      #pragma unroll
      for (int ct=0;ct<4;++ct){
        int col = wc*64 + ct*16 + (l&15);
        bf[ct] = *(const s8v*)((const char*)Bl + col*128 + ((((l>>4)+ks*4) ^ (col&7))<<4));
      }
      #pragma unroll
      for (int rt=0;rt<2;++rt){
        int arow = wr*32 + rt*16 + (l&15);
        s8v af = *(const s8v*)((const char*)Al + arow*128 + ((((l>>4)+ks*4) ^ (arow&7))<<4));
        #pragma unroll
        for (int ct=0;ct<4;++ct)
          acc[rt][ct] = MFMA16(af, bf[ct], acc[rt][ct]);
      }
    }
    __syncthreads();
  }
  #pragma unroll
  for (int kh=0;kh<2;++kh)
    #pragma unroll
    for (int c=0;c<4;++c){
      int row = c*32 + srow;
      GLOAD16(ffnT + (size_t)row*128 + kh*64 + ((sseg ^ (row&7))<<3),
              ffnB + kh*16384 + c*4096 + w*1024);
    }
  {
    float bia[4];
    #pragma unroll
    for (int ct=0;ct<4;++ct) bia[ct] = out_b[wc*64 + ct*16 + (l&15)];
    #pragma unroll
    for (int rt=0;rt<2;++rt)
      #pragma unroll
      for (int ct=0;ct<4;++ct)
        #pragma unroll
        for (int r=0;r<4;++r){
          int rr = wr*32 + rt*16 + (l>>4)*4 + r;
          int cc = wc*64 + ct*16 + (l&15);
          vst[rr*128 + cc] = acc[rt][ct][r] + bia[ct] + x[(size_t)(bm+rr)*128 + cc];
        }
  }
  __syncthreads();
  {
    const float2 g1v = *(const float2*)(g1 + l*2);
    const float2 b1v = *(const float2*)(b1 + l*2);
    for (int rr=0; rr<16; ++rr){
      int row = w*16 + rr;
      float2 vv = *(const float2*)&vst[row*128 + l*2];
      float s = vv.x+vv.y, sq = vv.x*vv.x + vv.y*vv.y;
      #pragma unroll
      for (int m=1;m<64;m<<=1){ s += __shfl_xor(s,m,64); sq += __shfl_xor(sq,m,64); }
      float mean = s*(1.f/128.f);
      float rstd = rsqrtf(sq*(1.f/128.f) - mean*mean + 1e-5f);
      float xa = (vv.x-mean)*rstd*g1v.x + b1v.x;
      float xb = (vv.y-mean)*rstd*g1v.y + b1v.y;
      int col = l*2;
      int byte = row*256 + (((col>>3) ^ (row&7))<<4) + ((col&7)<<1);
      unsigned int pk = (unsigned int)f2bf(xa) | ((unsigned int)f2bf(xb)<<16);
      *(unsigned int*)(xnl + byte) = pk;
    }
  }
  __syncthreads();
  f4v acc2[2][4];
  #pragma unroll
  for (int i=0;i<2;++i)
    #pragma unroll
    for (int j=0;j<4;++j) acc2[i][j] = (f4v){0.f,0.f,0.f,0.f};
  #pragma unroll
  for (int ks2=0;ks2<4;++ks2){
    int kh = ks2>>1, ks = ks2&1;
    s8v bf[4];
    #pragma unroll
    for (int ct=0;ct<4;++ct){
      int col = wc*64 + ct*16 + (l&15);
      bf[ct] = *(const s8v*)(ffnB + kh*16384 + col*128 + ((((l>>4)+ks*4) ^ (col&7))<<4));
    }
    #pragma unroll
    for (int rt=0;rt<2;++rt){
      int arow = wr*32 + rt*16 + (l&15);
      s8v af = *(const s8v*)(xnl + arow*256 + ((((l>>4)+ks2*4) ^ (arow&7))<<4));
      #pragma unroll
      for (int ct=0;ct<4;++ct)
        acc2[rt][ct] = MFMA16(af, bf[ct], acc2[rt][ct]);
    }
  }
  {
    float fb[4];
    #pragma unroll
    for (int ct=0;ct<4;++ct) fb[ct] = ffn_b[wc*64 + ct*16 + (l&15)];
    #pragma unroll
    for (int rt=0;rt<2;++rt)
      #pragma unroll
      for (int ct=0;ct<4;++ct)
        #pragma unroll
        for (int r=0;r<4;++r){
          int rr = wr*32 + rt*16 + (l>>4)*4 + r;
          int cc = wc*64 + ct*16 + (l&15);
          vst[rr*128 + cc] += softplus_f(acc2[rt][ct][r] + fb[ct]);
        }
  }
  __syncthreads();
  {
    const float2 g1v = *(const float2*)(g1 + l*2);
    const float2 b1v = *(const float2*)(b1 + l*2);
    for (int rr=0; rr<16; ++rr){
      int row = w*16 + rr;
      float2 vv = *(const float2*)&vst[row*128 + l*2];
      float s = vv.x+vv.y, sq = vv.x*vv.x + vv.y*vv.y;
      #pragma unroll
      for (int m=1;m<64;m<<=1){ s += __shfl_xor(s,m,64); sq += __shfl_xor(sq,m,64); }
      float mean = s*(1.f/128.f);
      float rstd = rsqrtf(sq*(1.f/128.f) - mean*mean + 1e-5f);
      float xa = (vv.x-mean)*rstd*g1v.x + b1v.x;
      float xb = (vv.y-mean)*rstd*g1v.y + b1v.y;
      float2 xo; xo.x = xa; xo.y = xb;
      *(float2*)(x + (size_t)(bm+row)*128 + l*2) = xo;
      if (g2) {
        float s2 = xa+xb, sq2 = xa*xa + xb*xb;
        #pragma unroll
        for (int m=1;m<64;m<<=1){ s2 += __shfl_xor(s2,m,64); sq2 += __shfl_xor(sq2,m,64); }
        float mean2 = s2*(1.f/128.f);
        float rstd2 = rsqrtf(sq2*(1.f/128.f) - mean2*mean2 + 1e-5f);
        const float2 g2v = *(const float2*)(g2 + l*2);
        const float2 b2v = *(const float2*)(b2 + l*2);
        float ya = (xa-mean2)*rstd2*g2v.x + b2v.x;
        float yb = (xb-mean2)*rstd2*g2v.y + b2v.y;
        unsigned int pk = (unsigned int)f2bf(ya) | ((unsigned int)f2bf(yb)<<16);
        *(unsigned int*)(xnb + (size_t)(bm+row)*128 + l*2) = pk;
      }
    }
  }
}

// ---------- pooling (parallel partials) + final ----------
__global__ __launch_bounds__(128) void pool_part_kernel(const float* __restrict__ x,
    const float* __restrict__ x_init,
    const float* __restrict__ w_row, float* __restrict__ partial) {
  int b = blockIdx.x, p = blockIdx.y, e = threadIdx.x;
  float acc = 0.f;
  for (int n = p*64; n < p*64+64; ++n) {
    float w = w_row[(size_t)b*N_ + n];
    size_t o = ((size_t)b*N_ + n)*E_ + e;
    acc += w * (x[o] + x_init[o]);
  }
  partial[((size_t)b*8 + p)*E_ + e] = acc;
}

__global__ __launch_bounds__(128) void final_kernel(const float* __restrict__ partial,
    const float* __restrict__ g, const float* __restrict__ bt,
    const float* __restrict__ fw, const float* __restrict__ fb, float* __restrict__ out) {
  int b = blockIdx.x, t = threadIdx.x;
  float v = 0.f;
  for (int p=0;p<8;++p) v += partial[((size_t)b*8+p)*E_ + t];
  float s = v, sq = v*v;
  #pragma unroll
  for (int m = 1; m < 64; m <<= 1) { s += __shfl_xor(s, m, 64); sq += __shfl_xor(sq, m, 64); }
  __shared__ float red[4];
  int wv = t >> 6, ln = t & 63;
  if (ln == 0) { red[wv*2] = s; red[wv*2+1] = sq; }
  __syncthreads();
  s = red[0] + red[2]; sq = red[1] + red[3];
  float mean = s*(1.f/E_), var = sq*(1.f/E_) - mean*mean;
  float rstd = rsqrtf(var + 1e-5f);
  float xl = (v - mean)*rstd*g[t] + bt[t];
  float p = xl * fw[t];
  #pragma unroll
  for (int m = 1; m < 64; m <<= 1) p += __shfl_xor(p, m, 64);
  __shared__ float red2[2];
  if (ln == 0) red2[wv] = p;
  __syncthreads();
  if (t == 0) out[b] = red2[0] + red2[1] + fb[0];
}

extern "C" void kernel_launch(void* const* d_in, const int* in_sizes, int n_in,
                              void* d_out, int out_size, void* d_ws, size_t ws_size,
                              hipStream_t stream) {
  (void)in_sizes; (void)n_in; (void)out_size; (void)ws_size;
  const float* str_fea  = (const float*)d_in[0];
  const int*   comp_fea = (const int*)  d_in[1];
  const float* af_table = (const float*)d_in[3];
  const float* comp_w   = (const float*)d_in[4];
  const float* comp_b   = (const float*)d_in[5];
  const float* emb_w    = (const float*)d_in[6];
  const float* emb_b    = (const float*)d_in[7];
  const float* ln_g     = (const float*)d_in[8];
  const float* ln_b     = (const float*)d_in[9];
  const float* wq       = (const float*)d_in[10];
  const float* bq       = (const float*)d_in[11];
  const float* wk       = (const float*)d_in[12];
  const float* bk       = (const float*)d_in[13];
  const float* wv       = (const float*)d_in[14];
  const float* bv       = (const float*)d_in[15];
  const float* inproj_w = (const float*)d_in[16];
  const float* inproj_b = (const float*)d_in[17];
  const float* out_w    = (const float*)d_in[18];
  const float* out_b    = (const float*)d_in[19];
  const float* ffn_w    = (const float*)d_in[20];
  const float* ffn_b    = (const float*)d_in[21];
  const float* ln2_g    = (const float*)d_in[22];
  const float* ln2_b    = (const float*)d_in[23];
  const float* final_w  = (const float*)d_in[24];
  const float* final_b  = (const float*)d_in[25];
  float* out = (float*)d_out;

  float* ws = (float*)d_ws;
  size_t off = 0;
  float* x      = ws + off; off += 2097152;
  float* x_init = ws + off; off += 2097152;
  float* w_row  = ws + off; off += 16384;
  unsigned short* xnb  = (unsigned short*)(ws + off); off += 1048576;   // [M][128]
  unsigned short* qkb  = (unsigned short*)(ws + off); off += 8388608;   // [M][1024]
  unsigned short* vTb  = (unsigned short*)(ws + off); off += 4194304;   // [B][512][512]
  unsigned short* attb = (unsigned short*)(ws + off); off += 4194304;   // [M][512]
  float* part   = ws + off; off += 24576;    // [6][8][512]
  float* effpart= ws + off; off += 3145728;  // [8][6][8][64][128] f32
  float* bqkv   = ws + off; off += 4608;
  unsigned short* wqkvT = (unsigned short*)(ws + off); off += 294912;   // [3][1536][128]
  unsigned short* outT  = (unsigned short*)(ws + off); off += 98304;    // [3][128][512]
  unsigned short* ffnT  = (unsigned short*)(ws + off); off += 24576;    // [3][128][128]
  unsigned short* FHi   = (unsigned short*)(ws + off); off += 2621440;  // [M][320]
  unsigned short* FLo   = (unsigned short*)(ws + off); off += 2621440;
  unsigned short* WHi   = (unsigned short*)(ws + off); off += 20480;    // [128][320]
  unsigned short* WLo   = (unsigned short*)(ws + off); off += 20480;
  float* biasE  = ws + off; off += 128;
  float* Cpart  = ws + off; off += 1280;
  float* partial= ws + off; off += 32768;

  effb_part_kernel<<<dim3(6,8), 256, 0, stream>>>(bq, bk, inproj_w, part);
  effp_kernel<<<dim3(48,8), 256, 0, stream>>>(wq, wk, inproj_w, effpart);
  effred_kernel<<<1536, 256, 0, stream>>>(effpart, wqkvT);
  wtrans_kernel<<<126, 256, 0, stream>>>(wv, out_w, ffn_w, inproj_b, bv, part,
                                         wqkvT, outT, ffnT, bqkv);
  embW1_kernel<<<12, 128, 0, stream>>>(emb_w, comp_w, WHi, WLo, Cpart);
  embBias_kernel<<<1, 128, 0, stream>>>(Cpart, comp_b, emb_b, biasE);
  feat_kernel<<<M_*40/256, 256, 0, stream>>>(str_fea, comp_fea, af_table, FHi, FLo, w_row);
  embgemm_kernel<<<M_/64, 256, 0, stream>>>(FHi, FLo, WHi, WLo, biasE,
                                            ln_g, ln_b, x, x_init, xnb);

  for (int l = 0; l < L_; ++l) {
    mgemm_kernel<4><<<dim3(M_/128, 12), 256, 0, stream>>>(
        xnb, wqkvT + (size_t)l*196608, bqkv + l*1536, qkb, vTb, 128);
    attnF_kernel<<<256, 512, 0, stream>>>(qkb, vTb, w_row, attb);
    tail_kernel<<<M_/64, 256, 0, stream>>>(
        attb, outT + (size_t)l*65536, out_b + (size_t)l*E_,
        ffnT + (size_t)l*16384, ffn_b + (size_t)l*E_,
        x, xnb, ln_g + l*E_, ln_b + l*E_,
        (l < 2) ? (ln_g + (l+1)*E_) : nullptr,
        (l < 2) ? (ln_b + (l+1)*E_) : nullptr);
  }

  pool_part_kernel<<<dim3(B_, 8), 128, 0, stream>>>(x, x_init, w_row, partial);
  final_kernel<<<B_, 128, 0, stream>>>(partial, ln2_g, ln2_b, final_w, final_b, out);
}